// Round 9
// baseline (2320.106 us; speedup 1.0000x reference)
//
#include <hip/hip_runtime.h>

// SizeInvariantTimeSformer forward on MI355X (gfx950).
// fp32 residual stream; big GEMMs: bf16 MFMA 128x128x64 tiles, 2-phase double-buffered
// global_load_lds pipeline, row-parity bit-6 LDS swizzle (full 32-bank spread);
// attn_space MFMA; attn_cls split-K flash.

typedef unsigned short u16;
typedef __bf16 bf16x8 __attribute__((ext_vector_type(8)));
typedef float f32x4 __attribute__((ext_vector_type(4)));
typedef u16 u16x8 __attribute__((ext_vector_type(8)));

#define SEQ   3137
#define ROWS  12548   // B * SEQ
#define MPAD  12672   // 99 * 128
#define NTOK  12544   // B * F * 196
#define NCC   16      // cls split-K chunks
#define CHK   197     // ceil(SEQ/NCC)

__device__ __forceinline__ u16 f2b(float f) {
  union { float f; unsigned u; } v; v.f = f;
  unsigned r = v.u + 0x7FFFu + ((v.u >> 16) & 1u);   // RNE
  return (u16)(r >> 16);
}
__device__ __forceinline__ float b2f(u16 u) {
  union { unsigned u; float f; } v; v.u = ((unsigned)u) << 16;
  return v.f;
}
__device__ __forceinline__ float gelu_f(float g) {
  return 0.5f * g * (1.0f + erff(g * 0.70710678118654752f));
}
// bool inputs may arrive as uint8 bytes, int32 words, or float32 words.
__device__ __forceinline__ bool read_bool(const void* p, int idx) {
  const unsigned* w = (const unsigned*)p;
  unsigned w0 = w[0];
  if (w0 == 1u || w0 == 0u) return ((const int*)p)[idx] != 0;   // int32-encoded
  if (w0 == 0x3F800000u) return w[idx] != 0;                    // float32-encoded
  return ((const unsigned char*)p)[idx] != 0;                   // uint8-encoded
}

typedef const __attribute__((address_space(1))) void GVOID;
typedef __attribute__((address_space(3))) void LVOID;
__device__ __forceinline__ void gload_lds16(const void* g, void* l) {
  __builtin_amdgcn_global_load_lds((GVOID*)g, (LVOID*)l, 16, 0, 0);
}

// ---------------- GEMM: C[M,N] = A[M,K](bf16) * Bt[N,K](bf16)^T (+bias) ----------------
// 2-phase double-buffered staging. Per-buf layout: A [128][64]bf16, B [128][64]bf16.
// Row-parity swizzle: data for logical (row,colb) stored at colb ^ ((row&1)<<6) —
// one ds_read_b128 wave then touches all 32 banks at exactly 8 dwords/bank (no conflict).
// MODE 0: Cf = acc+bias (f32)   MODE 1: Cf += acc+bias (f32)   MODE 2: Cb = bf16(acc+bias)
template<int MODE>
__global__ __launch_bounds__(256) void gemm_bt(
    const u16* __restrict__ A, const u16* __restrict__ Bt,
    const float* __restrict__ bias,
    float* __restrict__ Cf, u16* __restrict__ Cb,
    int Mact, int N, int K)
{
  __shared__ char smem[65536];            // 2 bufs x (16KB A + 16KB B)
  const int tid  = threadIdx.x;
  const int lane = tid & 63, wid = tid >> 6;
  const int wm = wid >> 1, wn = wid & 1;
  const long arow0 = (long)blockIdx.y * 128;
  const long brow0 = (long)blockIdx.x * 128;

  // staging: linear LDS dest; global source col pre-swizzled (row-parity bit 6)
  const int  s_row = tid >> 3;                                   // 0..31
  const int  s_swz = ((tid & 7) << 4) ^ ((s_row & 1) << 6);      // byte col in row
  const char* Ag = (const char*)A + (arow0 + s_row) * (long)K * 2 + s_swz;
  const char* Bg = (const char*)Bt + (brow0 + s_row) * (long)K * 2 + s_swz;

  f32x4 acc[4][4] = {};
  const int rd_row_a = wm * 64 + (lane & 15);
  const int rd_row_b = wn * 64 + (lane & 15);
  const int rd_kb    = (lane >> 4) << 4;
  const int swzr     = (lane & 1) << 6;    // row parity (rows = base + lane&15, bases even)

  const int NT = K >> 6;
  // prologue: stage tile 0 -> buf 0
#pragma unroll
  for (int i = 0; i < 4; ++i) {
    gload_lds16(Ag + (long)i * 32 * K * 2, smem + wid * 1024 + i * 4096);
    gload_lds16(Bg + (long)i * 32 * K * 2, smem + 16384 + wid * 1024 + i * 4096);
  }
  __syncthreads();

  for (int t = 0; t < NT; ++t) {
    const int cur = t & 1;
    if (t + 1 < NT) {                      // issue next-tile loads first
      const long kb = (long)(t + 1) * 128;
      char* dst = smem + (cur ^ 1) * 32768 + wid * 1024;
#pragma unroll
      for (int i = 0; i < 4; ++i) {
        gload_lds16(Ag + kb + (long)i * 32 * K * 2, dst + i * 4096);
        gload_lds16(Bg + kb + (long)i * 32 * K * 2, dst + 16384 + i * 4096);
      }
    }
    const char* Ab = smem + cur * 32768;
    const char* Bb = Ab + 16384;
#pragma unroll
    for (int ks = 0; ks < 2; ++ks) {
      bf16x8 af[4], bfr[4];
#pragma unroll
      for (int mi = 0; mi < 4; ++mi)
        af[mi] = *(const bf16x8*)(Ab + (rd_row_a + mi * 16) * 128 + ((ks * 64 + rd_kb) ^ swzr));
#pragma unroll
      for (int ni = 0; ni < 4; ++ni)
        bfr[ni] = *(const bf16x8*)(Bb + (rd_row_b + ni * 16) * 128 + ((ks * 64 + rd_kb) ^ swzr));
#pragma unroll
      for (int mi = 0; mi < 4; ++mi)
#pragma unroll
        for (int ni = 0; ni < 4; ++ni)
          acc[mi][ni] = __builtin_amdgcn_mfma_f32_16x16x32_bf16(af[mi], bfr[ni], acc[mi][ni], 0, 0, 0);
    }
    __syncthreads();                       // drains vmcnt(0): buf cur^1 ready
  }

  // epilogue: C/D layout col=lane&15, row=(lane>>4)*4+reg
  const int ccol0 = (int)brow0 + wn * 64 + (lane & 15);
  const int rsub  = (lane >> 4) * 4;
  float bv[4];
#pragma unroll
  for (int ni = 0; ni < 4; ++ni) bv[ni] = bias ? bias[ccol0 + ni * 16] : 0.0f;
#pragma unroll
  for (int mi = 0; mi < 4; ++mi) {
#pragma unroll
    for (int r = 0; r < 4; ++r) {
      long row = arow0 + wm * 64 + mi * 16 + rsub + r;
      if (row < Mact) {
#pragma unroll
        for (int ni = 0; ni < 4; ++ni) {
          float v = acc[mi][ni][r] + bv[ni];
          long idx = row * (long)N + ccol0 + ni * 16;
          if (MODE == 0)      Cf[idx] = v;
          else if (MODE == 1) Cf[idx] += v;
          else                Cb[idx] = f2b(v);
        }
      }
    }
  }
}

// ---------------- FFN1 fused: H = XN @ PW1^T + b1 (permuted), HACT = a * gelu(g) --------
// Same pipeline + row-parity swizzle; epilogue g-exchange via LDS (stride 68 = 2-way free).
__global__ __launch_bounds__(256) void gemm_w1_fused(
    const u16* __restrict__ A, const u16* __restrict__ Bt,
    const float* __restrict__ bias, u16* __restrict__ HACT, int Mact)
{
  __shared__ char smem[65536];
  const int K = 1024;
  const int tid  = threadIdx.x;
  const int lane = tid & 63, wid = tid >> 6;
  const int wm = wid >> 1, wn = wid & 1;
  const long arow0 = (long)blockIdx.y * 128;
  const long brow0 = (long)blockIdx.x * 128;

  const int  s_row = tid >> 3;
  const int  s_swz = ((tid & 7) << 4) ^ ((s_row & 1) << 6);
  const char* Ag = (const char*)A + (arow0 + s_row) * (long)K * 2 + s_swz;
  const char* Bg = (const char*)Bt + (brow0 + s_row) * (long)K * 2 + s_swz;

  f32x4 acc[4][4] = {};
  const int rd_row_a = wm * 64 + (lane & 15);
  const int rd_row_b = wn * 64 + (lane & 15);
  const int rd_kb    = (lane >> 4) << 4;
  const int swzr     = (lane & 1) << 6;

  const int NT = K >> 6;
#pragma unroll
  for (int i = 0; i < 4; ++i) {
    gload_lds16(Ag + (long)i * 32 * K * 2, smem + wid * 1024 + i * 4096);
    gload_lds16(Bg + (long)i * 32 * K * 2, smem + 16384 + wid * 1024 + i * 4096);
  }
  __syncthreads();

  for (int t = 0; t < NT; ++t) {
    const int cur = t & 1;
    if (t + 1 < NT) {
      const long kb = (long)(t + 1) * 128;
      char* dst = smem + (cur ^ 1) * 32768 + wid * 1024;
#pragma unroll
      for (int i = 0; i < 4; ++i) {
        gload_lds16(Ag + kb + (long)i * 32 * K * 2, dst + i * 4096);
        gload_lds16(Bg + kb + (long)i * 32 * K * 2, dst + 16384 + i * 4096);
      }
    }
    const char* Ab = smem + cur * 32768;
    const char* Bb = Ab + 16384;
#pragma unroll
    for (int ks = 0; ks < 2; ++ks) {
      bf16x8 af[4], bfr[4];
#pragma unroll
      for (int mi = 0; mi < 4; ++mi)
        af[mi] = *(const bf16x8*)(Ab + (rd_row_a + mi * 16) * 128 + ((ks * 64 + rd_kb) ^ swzr));
#pragma unroll
      for (int ni = 0; ni < 4; ++ni)
        bfr[ni] = *(const bf16x8*)(Bb + (rd_row_b + ni * 16) * 128 + ((ks * 64 + rd_kb) ^ swzr));
#pragma unroll
      for (int mi = 0; mi < 4; ++mi)
#pragma unroll
        for (int ni = 0; ni < 4; ++ni)
          acc[mi][ni] = __builtin_amdgcn_mfma_f32_16x16x32_bf16(af[mi], bfr[ni], acc[mi][ni], 0, 0, 0);
    }
    __syncthreads();
  }

  // epilogue: staging LDS dead; reuse as gx[2][64][68] f32
  float* gx = (float*)smem;
  const int colb  = lane & 15;
  const int rsub  = (lane >> 4) * 4;
  const int cbase = blockIdx.x * 64;
  float bv[4];
#pragma unroll
  for (int ni = 0; ni < 4; ++ni)
    bv[ni] = bias[(wn ? 4096 : 0) + cbase + ni * 16 + colb];

  if (wn == 1) {
#pragma unroll
    for (int mi = 0; mi < 4; ++mi)
#pragma unroll
      for (int r = 0; r < 4; ++r) {
        int rl = mi * 16 + rsub + r;
#pragma unroll
        for (int ni = 0; ni < 4; ++ni)
          gx[(wm * 64 + rl) * 68 + ni * 16 + colb] = acc[mi][ni][r] + bv[ni];
      }
  }
  __syncthreads();
  if (wn == 0) {
#pragma unroll
    for (int mi = 0; mi < 4; ++mi)
#pragma unroll
      for (int r = 0; r < 4; ++r) {
        int rl = mi * 16 + rsub + r;
        long row = arow0 + wm * 64 + rl;
        if (row < Mact) {
#pragma unroll
          for (int ni = 0; ni < 4; ++ni) {
            float a = acc[mi][ni][r] + bv[ni];
            float g = gx[(wm * 64 + rl) * 68 + ni * 16 + colb];
            HACT[row * 4096L + cbase + ni * 16 + colb] = f2b(a * gelu_f(g));
          }
        }
      }
  }
}

// ---------------- transpose + f32->bf16 convert ----------------
__global__ __launch_bounds__(256) void transpose_cvt(
    const float* __restrict__ src, u16* __restrict__ dst,
    int R, int C, long sstride, long dstride)
{
  src += (long)blockIdx.z * sstride;
  dst += (long)blockIdx.z * dstride;
  __shared__ float tile[32][33];
  const int r0 = blockIdx.y * 32, c0 = blockIdx.x * 32;
  const int tx = threadIdx.x & 31, ty = threadIdx.x >> 5;
#pragma unroll
  for (int i = 0; i < 32; i += 8) {
    int r = r0 + ty + i, c = c0 + tx;
    if (r < R && c < C) tile[ty + i][tx] = src[(long)r * C + c];
  }
  __syncthreads();
#pragma unroll
  for (int i = 0; i < 32; i += 8) {
    int c = c0 + ty + i, r = r0 + tx;
    if (c < C && r < R) dst[(long)c * R + r] = f2b(tile[tx][ty + i]);
  }
}

// ---------------- w1 permuted transpose ----------------
__global__ __launch_bounds__(256) void transpose_w1(
    const float* __restrict__ src, u16* __restrict__ dst)
{
  __shared__ float tile[32][33];
  const int r0 = blockIdx.y * 32, c0 = blockIdx.x * 32;
  const int tx = threadIdx.x & 31, ty = threadIdx.x >> 5;
#pragma unroll
  for (int i = 0; i < 32; i += 8)
    tile[ty + i][tx] = src[(long)(r0 + ty + i) * 8192 + c0 + tx];
  __syncthreads();
#pragma unroll
  for (int i = 0; i < 32; i += 8) {
    int n = c0 + ty + i;
    int np = (n < 4096) ? ((n >> 6) * 128 + (n & 63))
                        : (((n - 4096) >> 6) * 128 + 64 + ((n - 4096) & 63));
    dst[(long)np * 1024 + r0 + tx] = f2b(tile[tx][ty + i]);
  }
}

// ---------------- build XT = concat(cls, tokens) + pos ----------------
__global__ __launch_bounds__(256) void build_xt(
    const float* __restrict__ TOK, const float* __restrict__ cls,
    const float* __restrict__ pos, float* __restrict__ XT)
{
  const int row = blockIdx.x, tid = threadIdx.x;
  const int b = row / SEQ, s = row % SEQ;
  float4 p = ((const float4*)(pos + (long)s * 1024))[tid];
  float4 t;
  if (s == 0) t = ((const float4*)cls)[tid];
  else        t = ((const float4*)(TOK + ((long)b * 3136 + (s - 1)) * 1024))[tid];
  float4 r; r.x = t.x + p.x; r.y = t.y + p.y; r.z = t.z + p.z; r.w = t.w + p.w;
  ((float4*)(XT + (long)row * 1024))[tid] = r;
}

// ---------------- LayerNorm (f32 in) -> bf16 out ----------------
__global__ __launch_bounds__(256) void ln_rows(
    const float* __restrict__ X, const float* __restrict__ g,
    const float* __restrict__ b, u16* __restrict__ Y)
{
  const int row = blockIdx.x, tid = threadIdx.x;
  const int lane = tid & 63, wid = tid >> 6;
  float4 x = ((const float4*)(X + (long)row * 1024))[tid];
  float s = x.x + x.y + x.z + x.w;
  float q = x.x * x.x + x.y * x.y + x.z * x.z + x.w * x.w;
#pragma unroll
  for (int o = 32; o; o >>= 1) { s += __shfl_xor(s, o); q += __shfl_xor(q, o); }
  __shared__ float ls[4], lq[4];
  if (lane == 0) { ls[wid] = s; lq[wid] = q; }
  __syncthreads();
  s = ls[0] + ls[1] + ls[2] + ls[3];
  q = lq[0] + lq[1] + lq[2] + lq[3];
  const float mean = s * (1.0f / 1024.0f);
  const float rstd = rsqrtf(q * (1.0f / 1024.0f) - mean * mean + 1e-5f);
  float4 gg = ((const float4*)g)[tid];
  float4 bb = ((const float4*)b)[tid];
  ushort4 o4;
  o4.x = f2b((x.x - mean) * rstd * gg.x + bb.x);
  o4.y = f2b((x.y - mean) * rstd * gg.y + bb.y);
  o4.z = f2b((x.z - mean) * rstd * gg.z + bb.z);
  o4.w = f2b((x.w - mean) * rstd * gg.w + bb.w);
  ((ushort4*)(Y + (long)row * 1024))[tid] = o4;
}

// ---------------- cls attention, split-K partial ----------------
__global__ __launch_bounds__(256) void attn_cls_part(
    const u16* __restrict__ QKV, float* __restrict__ PART, const void* __restrict__ maskp)
{
  const int c = blockIdx.x, bh = blockIdx.y;
  const int b = bh >> 4, h = bh & 15;
  const long rowbase = (long)b * SEQ;
  const int tid = threadIdx.x, lane = tid & 63, w = tid >> 6;
  const int rs = lane >> 3, c8 = lane & 7;
  const int start = c * CHK;
  const int end = (start + CHK < SEQ) ? start + CHK : SEQ;

  float qf[8];
  {
    u16x8 qv = *(const u16x8*)(QKV + rowbase * 3072 + h * 64 + c8 * 8);
#pragma unroll
    for (int i = 0; i < 8; ++i) qf[i] = b2f(qv[i]) * 0.125f;
  }

  float m_run = -3.4e38f, s_run = 0.f;
  float acc[8] = {};

  for (int j8 = start + w * 8; j8 < end; j8 += 32) {
    int j = j8 + rs;
    bool valid = (j < end);
    int jc = valid ? j : (end - 1);
    const u16* kp = QKV + (rowbase + jc) * 3072 + 1024 + h * 64 + c8 * 8;
    u16x8 kv = *(const u16x8*)kp;
    u16x8 vv = *(const u16x8*)(kp + 1024);
    float sim = 0.f;
#pragma unroll
    for (int i = 0; i < 8; ++i) sim += b2f(kv[i]) * qf[i];
    sim += __shfl_xor(sim, 1); sim += __shfl_xor(sim, 2); sim += __shfl_xor(sim, 4);
    bool ok = valid && ((jc == 0) || read_bool(maskp, b * 16 + (jc - 1) / 196));
    float simv = ok ? sim : -3.4e38f;
    float mx = simv;
    mx = fmaxf(mx, __shfl_xor(mx, 8));
    mx = fmaxf(mx, __shfl_xor(mx, 16));
    mx = fmaxf(mx, __shfl_xor(mx, 32));
    float new_m = fmaxf(m_run, mx);
    float scale = __expf(m_run - new_m);
    float p = ok ? __expf(simv - new_m) : 0.f;
    m_run = new_m;
    s_run = s_run * scale + p;
#pragma unroll
    for (int i = 0; i < 8; ++i) acc[i] = acc[i] * scale + p * b2f(vv[i]);
  }
#pragma unroll
  for (int o = 8; o <= 32; o <<= 1) {
    s_run += __shfl_xor(s_run, o);
#pragma unroll
    for (int i = 0; i < 8; ++i) acc[i] += __shfl_xor(acc[i], o);
  }

  __shared__ float sm_m[4], sm_s[4], sm_a[4][64];
  if (lane == 0) { sm_m[w] = m_run; sm_s[w] = s_run; }
  if (rs == 0) {
#pragma unroll
    for (int i = 0; i < 8; ++i) sm_a[w][c8 * 8 + i] = acc[i];
  }
  __syncthreads();
  if (tid < 64) {
    float M = fmaxf(fmaxf(sm_m[0], sm_m[1]), fmaxf(sm_m[2], sm_m[3]));
    float S = 0.f, A = 0.f;
#pragma unroll
    for (int ww = 0; ww < 4; ++ww) {
      float e = __expf(sm_m[ww] - M);
      S += sm_s[ww] * e;
      A += sm_a[ww][tid] * e;
    }
    float* outp = PART + ((long)bh * NCC + c) * 72;
    outp[tid] = A;
    if (tid == 0) { outp[64] = M; outp[65] = S; }
  }
}

// ---------------- cls attention combine ----------------
__global__ __launch_bounds__(64) void attn_cls_comb(
    const float* __restrict__ PART, u16* __restrict__ ATT)
{
  const int bh = blockIdx.x, b = bh >> 4, h = bh & 15;
  const int d = threadIdx.x;
  float M = -3.4e38f;
#pragma unroll
  for (int c = 0; c < NCC; ++c) M = fmaxf(M, PART[((long)bh * NCC + c) * 72 + 64]);
  float S = 0.f, A = 0.f;
#pragma unroll
  for (int c = 0; c < NCC; ++c) {
    const float* p = PART + ((long)bh * NCC + c) * 72;
    float e = __expf(p[64] - M);
    S += p[65] * e;
    A += p[d] * e;
  }
  ATT[((long)b * SEQ) * 1024 + h * 64 + d] = f2b(A / S);
}

// ---------------- time attention: groups (b,h,n), 16 queries x 17 keys ----------------
__global__ __launch_bounds__(256) void attn_time(
    const u16* __restrict__ QKV, u16* __restrict__ ATT,
    const void* __restrict__ maskp, const void* __restrict__ idmp)
{
  const int g = blockIdx.x;
  const int n = g % 196;
  const int bh = g / 196;
  const int h = bh & 15, b = bh >> 4;
  const long rowbase = (long)b * SEQ;
  const int tid = threadIdx.x;
  __shared__ float q_s[16][65], k_s[17][65], v_s[17][65], p_s[16][18];
  for (int idx = tid; idx < 16 * 64; idx += 256) {
    int i = idx >> 6, d = idx & 63;
    q_s[i][d] = b2f(QKV[(rowbase + 1 + i * 196 + n) * 3072 + h * 64 + d]) * 0.125f;
  }
  for (int idx = tid; idx < 17 * 64; idx += 256) {
    int j = idx >> 6, d = idx & 63;
    long kr = (j == 0) ? rowbase : (rowbase + 1 + (long)(j - 1) * 196 + n);
    k_s[j][d] = b2f(QKV[kr * 3072 + 1024 + h * 64 + d]);
    v_s[j][d] = b2f(QKV[kr * 3072 + 2048 + h * 64 + d]);
  }
  __syncthreads();
#pragma unroll
  for (int pp = 0; pp < 2; ++pp) {
    int idx = tid + pp * 256;
    if (idx < 272) {
      int i = idx / 17, j = idx % 17;
      float s = 0.f;
      for (int d = 0; d < 64; ++d) s += q_s[i][d] * k_s[j][d];
      bool ok = (j == 0) ||
                (read_bool(maskp, b * 16 + (j - 1)) && read_bool(idmp, (b * 16 + i) * 16 + (j - 1)));
      p_s[i][j] = ok ? s : -3.4e38f;
    }
  }
  __syncthreads();
  if (tid < 16) {
    float m = -3.4e38f;
    for (int j = 0; j < 17; ++j) m = fmaxf(m, p_s[tid][j]);
    float su = 0.f;
    for (int j = 0; j < 17; ++j) { float e = __expf(p_s[tid][j] - m); p_s[tid][j] = e; su += e; }
    float inv = 1.0f / su;
    for (int j = 0; j < 17; ++j) p_s[tid][j] *= inv;
  }
  __syncthreads();
  for (int idx = tid; idx < 1024; idx += 256) {
    int i = idx >> 6, d = idx & 63;
    float o = 0.f;
#pragma unroll
    for (int j = 0; j < 17; ++j) o += p_s[i][j] * v_s[j][d];
    ATT[(rowbase + 1 + i * 196 + n) * 1024 + h * 64 + d] = f2b(o);
  }
}

// ---------------- space attention (MFMA): one block per (b,h,f) ----------------
__global__ __launch_bounds__(256) void attn_space(
    const u16* __restrict__ QKV, u16* __restrict__ ATT)
{
  const int g = blockIdx.x;             // bh*16 + f
  const int fr = g & 15, bh = g >> 4;
  const int h = bh & 15, b = bh >> 4;
  const long rowbase = (long)b * SEQ;
  const long qbase = rowbase + 1 + (long)fr * 196;
  const int tid = threadIdx.x, lane = tid & 63, wid = tid >> 6;

  __shared__ u16 Ks[208][72];
  __shared__ u16 Vt[64][232];
  __shared__ u16 Ps[4][16][232];

  for (int c = tid; c < 197 * 8; c += 256) {
    int row = c >> 3, k8 = c & 7;
    long kr = (row == 0) ? rowbase : (qbase + row - 1);
    *(u16x8*)&Ks[row][k8 * 8] = *(const u16x8*)(QKV + kr * 3072 + 1024 + h * 64 + k8 * 8);
  }
  for (int c = tid; c < 64 * 35; c += 256) {
    int d = c / 35, k = 197 + c % 35;
    Vt[d][k] = 0;
  }
  for (int c = tid; c < 4 * 16 * 24; c += 256) {
    int w = c / (16 * 24), rem = c % (16 * 24);
    Ps[w][rem / 24][208 + rem % 24] = 0;
  }
  for (int c = tid; c < 197 * 64; c += 256) {
    int k = c >> 6, d = c & 63;
    long vr = (k == 0) ? rowbase : (qbase + k - 1);
    Vt[d][k] = QKV[vr * 3072 + 2048 + h * 64 + d];
  }
  __syncthreads();

  const int cl = lane & 15, hi = lane >> 4;
  for (int mt = wid; mt < 13; mt += 4) {
    int qi0 = mt * 16 + cl;
    long qrow = qbase + (qi0 < 196 ? qi0 : 0);
    const u16* qp = QKV + qrow * 3072 + h * 64 + hi * 8;
    bf16x8 af0 = *(const bf16x8*)qp;
    bf16x8 af1 = *(const bf16x8*)(qp + 32);

    f32x4 acc[13];
#pragma unroll
    for (int nt = 0; nt < 13; ++nt) {
      acc[nt] = (f32x4){0.f, 0.f, 0.f, 0.f};
      bf16x8 b0 = *(const bf16x8*)&Ks[nt * 16 + cl][hi * 8];
      acc[nt] = __builtin_amdgcn_mfma_f32_16x16x32_bf16(af0, b0, acc[nt], 0, 0, 0);
      bf16x8 b1 = *(const bf16x8*)&Ks[nt * 16 + cl][32 + hi * 8];
      acc[nt] = __builtin_amdgcn_mfma_f32_16x16x32_bf16(af1, b1, acc[nt], 0, 0, 0);
    }
    float mx[4] = {-3.4e38f, -3.4e38f, -3.4e38f, -3.4e38f};
#pragma unroll
    for (int nt = 0; nt < 13; ++nt) {
      int col = nt * 16 + cl;
#pragma unroll
      for (int r = 0; r < 4; ++r) {
        float s = acc[nt][r] * 0.125f;
        if (col >= 197) s = -3.4e38f;
        acc[nt][r] = s;
        mx[r] = fmaxf(mx[r], s);
      }
    }
#pragma unroll
    for (int r = 0; r < 4; ++r) {
#pragma unroll
      for (int o = 8; o; o >>= 1) mx[r] = fmaxf(mx[r], __shfl_xor(mx[r], o));
    }
    float sum[4] = {0.f, 0.f, 0.f, 0.f};
#pragma unroll
    for (int nt = 0; nt < 13; ++nt) {
      int col = nt * 16 + cl;
#pragma unroll
      for (int r = 0; r < 4; ++r) {
        float p = __expf(acc[nt][r] - mx[r]);
        sum[r] += p;
        Ps[wid][hi * 4 + r][col] = f2b(p);
      }
    }
    float inv[4];
#pragma unroll
    for (int r = 0; r < 4; ++r) {
#pragma unroll
      for (int o = 8; o; o >>= 1) sum[r] += __shfl_xor(sum[r], o);
      inv[r] = 1.0f / sum[r];
    }
    f32x4 ov[4];
#pragma unroll
    for (int dt = 0; dt < 4; ++dt) ov[dt] = (f32x4){0.f, 0.f, 0.f, 0.f};
#pragma unroll
    for (int ks = 0; ks < 7; ++ks) {
      bf16x8 pa = *(const bf16x8*)&Ps[wid][cl][ks * 32 + hi * 8];
#pragma unroll
      for (int dt = 0; dt < 4; ++dt) {
        bf16x8 vb = *(const bf16x8*)&Vt[dt * 16 + cl][ks * 32 + hi * 8];
        ov[dt] = __builtin_amdgcn_mfma_f32_16x16x32_bf16(pa, vb, ov[dt], 0, 0, 0);
      }
    }
#pragma unroll
    for (int r = 0; r < 4; ++r) {
      int qi = mt * 16 + hi * 4 + r;
      if (qi < 196) {
        long orow = (qbase + qi) * 1024 + h * 64;
#pragma unroll
        for (int dt = 0; dt < 4; ++dt)
          ATT[orow + dt * 16 + cl] = f2b(ov[dt][r] * inv[r]);
      }
    }
  }
}

// ---------------- final head: LN(cls) @ o_w + o_b ----------------
__global__ __launch_bounds__(256) void final_head(
    const float* __restrict__ XT, const float* __restrict__ g,
    const float* __restrict__ b, const float* __restrict__ ow,
    const float* __restrict__ ob, float* __restrict__ out)
{
  const int bb = blockIdx.x, tid = threadIdx.x;
  const int lane = tid & 63, wid = tid >> 6;
  float4 x = ((const float4*)(XT + (long)bb * SEQ * 1024))[tid];
  float s = x.x + x.y + x.z + x.w;
  float q = x.x * x.x + x.y * x.y + x.z * x.z + x.w * x.w;
#pragma unroll
  for (int o = 32; o; o >>= 1) { s += __shfl_xor(s, o); q += __shfl_xor(q, o); }
  __shared__ float ls[4], lq[4], lt[4];
  if (lane == 0) { ls[wid] = s; lq[wid] = q; }
  __syncthreads();
  s = ls[0] + ls[1] + ls[2] + ls[3];
  q = lq[0] + lq[1] + lq[2] + lq[3];
  const float mean = s * (1.0f / 1024.0f);
  const float rstd = rsqrtf(q * (1.0f / 1024.0f) - mean * mean + 1e-5f);
  float4 gg = ((const float4*)g)[tid];
  float4 bv = ((const float4*)b)[tid];
  float4 wv = ((const float4*)ow)[tid];
  float t = ((x.x - mean) * rstd * gg.x + bv.x) * wv.x
          + ((x.y - mean) * rstd * gg.y + bv.y) * wv.y
          + ((x.z - mean) * rstd * gg.z + bv.z) * wv.z
          + ((x.w - mean) * rstd * gg.w + bv.w) * wv.w;
#pragma unroll
  for (int o = 32; o; o >>= 1) t += __shfl_xor(t, o);
  if (lane == 0) lt[wid] = t;
  __syncthreads();
  if (tid == 0) out[bb] = lt[0] + lt[1] + lt[2] + lt[3] + ob[0];
}

// ==========================================================================
extern "C" void kernel_launch(void* const* d_in, const int* in_sizes, int n_in,
                              void* d_out, int out_size, void* d_ws, size_t ws_size,
                              hipStream_t stream) {
  const float* x       = (const float*)d_in[0];
  const void*  maskp   = d_in[1];
  const void*  idmp    = d_in[2];
  const float* patch_w = (const float*)d_in[3];
  const float* patch_b = (const float*)d_in[4];
  const float* cls_tok = (const float*)d_in[5];
  const float* pos_emb = (const float*)d_in[6];
  const float* t_ng = (const float*)d_in[7];
  const float* t_nb = (const float*)d_in[8];
  const float* t_qkv = (const float*)d_in[9];
  const float* t_ow = (const float*)d_in[10];
  const float* t_ob = (const float*)d_in[11];
  const float* s_ng = (const float*)d_in[12];
  const float* s_nb = (const float*)d_in[13];
  const float* s_qkv = (const float*)d_in[14];
  const float* s_ow = (const float*)d_in[15];
  const float* s_ob = (const float*)d_in[16];
  const float* f_ng = (const float*)d_in[17];
  const float* f_nb = (const float*)d_in[18];
  const float* f_w1 = (const float*)d_in[19];
  const float* f_b1 = (const float*)d_in[20];
  const float* f_w2 = (const float*)d_in[21];
  const float* f_b2 = (const float*)d_in[22];
  const float* o_ng = (const float*)d_in[23];
  const float* o_nb = (const float*)d_in[24];
  const float* o_w  = (const float*)d_in[25];
  const float* o_b  = (const float*)d_in[26];
  float* out = (float*)d_out;

  // ---- workspace layout (~198 MB) ----
  const size_t szXT   = (size_t)ROWS * 1024 * 4;
  const size_t szXNA  = (size_t)MPAD * 1024 * 2;
  const size_t szBIG  = (size_t)MPAD * 4096 * 2;
  const size_t szWBUF = (size_t)8192 * 1024 * 2;
  size_t off = 0;
  auto take = [&](size_t b) { size_t o = off; off += (b + 255) & ~(size_t)255; return o; };
  char* base = (char*)d_ws;
  float* XT  = (float*)(base + take(szXT));
  u16*  XNA  = (u16*)(base + take(szXNA));
  char* BIG  = base + take(szBIG);
  u16*  WBUF = (u16*)(base + take(szWBUF));
  if (off > ws_size) return;                              // ws too small: fail clean

  u16*   QKV  = (u16*)BIG;
  u16*   HACT = (u16*)BIG;
  u16*   Xtr  = (u16*)BIG;
  float* TOK  = (float*)(BIG + (size_t)40 * 1024 * 1024);
  float* PART = (float*)(BIG + (size_t)MPAD * 3072 * 2);  // after QKV extent

  auto tr = [&](const float* s, u16* d, int R, int C) {
    dim3 gr((C + 31) / 32, (R + 31) / 32, 1);
    transpose_cvt<<<gr, 256, 0, stream>>>(s, d, R, C, 0, 0);
  };

  // ---- patch embedding ----
  {
    dim3 gr((196 + 31) / 32, (1280 + 31) / 32, 64);
    transpose_cvt<<<gr, 256, 0, stream>>>(x, Xtr, 1280, 196, 1280L * 196, 196L * 1280);
  }
  tr(patch_w, WBUF, 1280, 1024);
  gemm_bt<0><<<dim3(8, 98), 256, 0, stream>>>(Xtr, WBUF, patch_b, TOK, nullptr, NTOK, 1024, 1280);
  build_xt<<<ROWS, 256, 0, stream>>>(TOK, cls_tok, pos_emb, XT);

  for (int L = 0; L < 2; ++L) {
    // ---- time attention block ----
    tr(t_qkv + (size_t)L * 1024 * 3072, WBUF, 1024, 3072);
    ln_rows<<<ROWS, 256, 0, stream>>>(XT, t_ng + L * 1024, t_nb + L * 1024, XNA);
    gemm_bt<2><<<dim3(24, 99), 256, 0, stream>>>(XNA, WBUF, nullptr, nullptr, QKV, MPAD, 3072, 1024);
    tr(t_ow + (size_t)L * 1024 * 1024, WBUF, 1024, 1024);
    attn_cls_part<<<dim3(NCC, 64), 256, 0, stream>>>(QKV, PART, maskp);
    attn_cls_comb<<<64, 64, 0, stream>>>(PART, XNA);
    attn_time<<<NTOK, 256, 0, stream>>>(QKV, XNA, maskp, idmp);
    gemm_bt<1><<<dim3(8, 99), 256, 0, stream>>>(XNA, WBUF, t_ob + L * 1024, XT, nullptr, ROWS, 1024, 1024);
    // ---- space attention block ----
    tr(s_qkv + (size_t)L * 1024 * 3072, WBUF, 1024, 3072);
    ln_rows<<<ROWS, 256, 0, stream>>>(XT, s_ng + L * 1024, s_nb + L * 1024, XNA);
    gemm_bt<2><<<dim3(24, 99), 256, 0, stream>>>(XNA, WBUF, nullptr, nullptr, QKV, MPAD, 3072, 1024);
    tr(s_ow + (size_t)L * 1024 * 1024, WBUF, 1024, 1024);
    attn_cls_part<<<dim3(NCC, 64), 256, 0, stream>>>(QKV, PART, maskp);
    attn_cls_comb<<<64, 64, 0, stream>>>(PART, XNA);
    attn_space<<<1024, 256, 0, stream>>>(QKV, XNA);
    gemm_bt<1><<<dim3(8, 99), 256, 0, stream>>>(XNA, WBUF, s_ob + L * 1024, XT, nullptr, ROWS, 1024, 1024);
    // ---- FFN (gate fused into GEMM1 epilogue) ----
    transpose_w1<<<dim3(256, 32), 256, 0, stream>>>(f_w1 + (size_t)L * 1024 * 8192, WBUF);
    ln_rows<<<ROWS, 256, 0, stream>>>(XT, f_ng + L * 1024, f_nb + L * 1024, XNA);
    gemm_w1_fused<<<dim3(64, 99), 256, 0, stream>>>(XNA, WBUF, f_b1 + L * 8192, HACT, ROWS);
    tr(f_w2 + (size_t)L * 4096 * 1024, WBUF, 4096, 1024);
    gemm_bt<1><<<dim3(8, 99), 256, 0, stream>>>(HACT, WBUF, f_b2 + L * 1024, XT, nullptr, ROWS, 1024, 4096);
  }
  final_head<<<4, 256, 0, stream>>>(XT, o_ng, o_nb, o_w, o_b, out);
}

// Round 10
// 2220.960 us; speedup vs baseline: 1.0446x; 1.0446x over previous
//
#include <hip/hip_runtime.h>

// SizeInvariantTimeSformer forward on MI355X (gfx950).
// fp32 residual stream. GEMMs: QKV+FFN1 on a 256^2-tile 8-wave counted-vmcnt pipeline
// (T3/T4 coarse); patch/out-proj/FFN2 on the proven 128^2 2-phase st_16x32 kernel.
// attn_space MFMA; attn_cls split-K flash.

typedef unsigned short u16;
typedef __bf16 bf16x8 __attribute__((ext_vector_type(8)));
typedef float f32x4 __attribute__((ext_vector_type(4)));
typedef u16 u16x8 __attribute__((ext_vector_type(8)));

#define SEQ   3137
#define ROWS  12548   // B * SEQ
#define MPAD  12672   // 99 * 128 (128^2 kernels' M extent)
#define MPADA 12800   // 50 * 256 (256^2 kernels' M extent; XNA rows)
#define NTOK  12544   // B * F * 196
#define NCC   16      // cls split-K chunks
#define CHK   197     // ceil(SEQ/NCC)

__device__ __forceinline__ u16 f2b(float f) {
  union { float f; unsigned u; } v; v.f = f;
  unsigned r = v.u + 0x7FFFu + ((v.u >> 16) & 1u);   // RNE
  return (u16)(r >> 16);
}
__device__ __forceinline__ float b2f(u16 u) {
  union { unsigned u; float f; } v; v.u = ((unsigned)u) << 16;
  return v.f;
}
__device__ __forceinline__ float gelu_f(float g) {
  return 0.5f * g * (1.0f + erff(g * 0.70710678118654752f));
}
// bool inputs may arrive as uint8 bytes, int32 words, or float32 words.
__device__ __forceinline__ bool read_bool(const void* p, int idx) {
  const unsigned* w = (const unsigned*)p;
  unsigned w0 = w[0];
  if (w0 == 1u || w0 == 0u) return ((const int*)p)[idx] != 0;   // int32-encoded
  if (w0 == 0x3F800000u) return w[idx] != 0;                    // float32-encoded
  return ((const unsigned char*)p)[idx] != 0;                   // uint8-encoded
}

typedef const __attribute__((address_space(1))) void GVOID;
typedef __attribute__((address_space(3))) void LVOID;
__device__ __forceinline__ void gload_lds16(const void* g, void* l) {
  __builtin_amdgcn_global_load_lds((GVOID*)g, (LVOID*)l, 16, 0, 0);
}

// ---------------- 128^2 GEMM (r8-proven): C = A * Bt^T (+bias) ----------------
// 2-phase double-buffered staging, st_16x32 swizzle (byte ^= ((byte>>9)&1)<<5).
// MODE 0: Cf = acc+bias   MODE 1: Cf += acc+bias   MODE 2: Cb = bf16(acc+bias)
template<int MODE>
__global__ __launch_bounds__(256) void gemm_bt(
    const u16* __restrict__ A, const u16* __restrict__ Bt,
    const float* __restrict__ bias,
    float* __restrict__ Cf, u16* __restrict__ Cb,
    int Mact, int N, int K)
{
  __shared__ char smem[65536];            // 2 bufs x (16KB A + 16KB B)
  const int tid  = threadIdx.x;
  const int lane = tid & 63, wid = tid >> 6;
  const int wm = wid >> 1, wn = wid & 1;
  const long arow0 = (long)blockIdx.y * 128;
  const long brow0 = (long)blockIdx.x * 128;

  const int  s_row = tid >> 3;                                        // 0..31
  const int  s_swz = ((tid & 7) << 4) ^ (((tid >> 5) & 1) << 5);      // st_16x32 source pre-swz
  const char* Ag = (const char*)A + (arow0 + s_row) * (long)K * 2 + s_swz;
  const char* Bg = (const char*)Bt + (brow0 + s_row) * (long)K * 2 + s_swz;

  f32x4 acc[4][4] = {};
  const int rd_row_a = wm * 64 + (lane & 15);
  const int rd_row_b = wn * 64 + (lane & 15);
  const int rd_kb    = (lane >> 4) << 4;
  const int swzr     = ((lane >> 2) & 1) << 5;   // st_16x32 read xor

  const int NT = K >> 6;
#pragma unroll
  for (int i = 0; i < 4; ++i) {
    gload_lds16(Ag + (long)i * 32 * K * 2, smem + wid * 1024 + i * 4096);
    gload_lds16(Bg + (long)i * 32 * K * 2, smem + 16384 + wid * 1024 + i * 4096);
  }
  __syncthreads();

  for (int t = 0; t < NT; ++t) {
    const int cur = t & 1;
    if (t + 1 < NT) {                      // issue next-tile loads first
      const long kb = (long)(t + 1) * 128;
      char* dst = smem + (cur ^ 1) * 32768 + wid * 1024;
#pragma unroll
      for (int i = 0; i < 4; ++i) {
        gload_lds16(Ag + kb + (long)i * 32 * K * 2, dst + i * 4096);
        gload_lds16(Bg + kb + (long)i * 32 * K * 2, dst + 16384 + i * 4096);
      }
    }
    const char* Ab = smem + cur * 32768;
    const char* Bb = Ab + 16384;
#pragma unroll
    for (int ks = 0; ks < 2; ++ks) {
      bf16x8 af[4], bfr[4];
#pragma unroll
      for (int mi = 0; mi < 4; ++mi)
        af[mi] = *(const bf16x8*)(Ab + (rd_row_a + mi * 16) * 128 + ((ks * 64 + rd_kb) ^ swzr));
#pragma unroll
      for (int ni = 0; ni < 4; ++ni)
        bfr[ni] = *(const bf16x8*)(Bb + (rd_row_b + ni * 16) * 128 + ((ks * 64 + rd_kb) ^ swzr));
#pragma unroll
      for (int mi = 0; mi < 4; ++mi)
#pragma unroll
        for (int ni = 0; ni < 4; ++ni)
          acc[mi][ni] = __builtin_amdgcn_mfma_f32_16x16x32_bf16(af[mi], bfr[ni], acc[mi][ni], 0, 0, 0);
    }
    __syncthreads();                       // drains vmcnt(0): buf cur^1 ready
  }

  const int ccol0 = (int)brow0 + wn * 64 + (lane & 15);
  const int rsub  = (lane >> 4) * 4;
  float bv[4];
#pragma unroll
  for (int ni = 0; ni < 4; ++ni) bv[ni] = bias ? bias[ccol0 + ni * 16] : 0.0f;
#pragma unroll
  for (int mi = 0; mi < 4; ++mi) {
#pragma unroll
    for (int r = 0; r < 4; ++r) {
      long row = arow0 + wm * 64 + mi * 16 + rsub + r;
      if (row < Mact) {
#pragma unroll
        for (int ni = 0; ni < 4; ++ni) {
          float v = acc[mi][ni][r] + bv[ni];
          long idx = row * (long)N + ccol0 + ni * 16;
          if (MODE == 0)      Cf[idx] = v;
          else if (MODE == 1) Cf[idx] += v;
          else                Cb[idx] = f2b(v);
        }
      }
    }
  }
}

// ---------------- 256^2 8-wave counted-vmcnt GEMM core (K=1024 fixed) ----------------
// 512 threads, waves 2M x 4N, per-wave 128x64 out. LDS 128KB: 2 bufs x (A 32KB + B 32KB).
// Schedule per K-step: {vmcnt(8); s_barrier; compute; s_barrier; issue(t+2)} —
// prefetch loads stay in flight across barriers (never drain to 0 in the loop).
#define G256_LOOP                                                                        \
  const int K = 1024, NT = 16;                                                           \
  const int tid = threadIdx.x;                                                           \
  const int lane = tid & 63, wid = tid >> 6;                                             \
  const int wr = wid >> 2, wc = wid & 3;                                                 \
  const long arow0 = (long)blockIdx.y * 256;                                             \
  const long brow0 = (long)blockIdx.x * 256;                                             \
  const int s_row = tid >> 3;                                                            \
  const int s_swz = ((tid & 7) << 4) ^ (((tid >> 5) & 1) << 5);                          \
  const char* Ag = (const char*)A + (arow0 + s_row) * (long)K * 2 + s_swz;               \
  const char* Bg = (const char*)Bt + (brow0 + s_row) * (long)K * 2 + s_swz;              \
  auto issue = [&](int t, int buf) {                                                     \
    const long kb = (long)t * 128;                                                       \
    char* d = smem + buf * 65536 + tid * 16;                                             \
    _Pragma("unroll")                                                                    \
    for (int i = 0; i < 4; ++i) {                                                        \
      gload_lds16(Ag + kb + (long)(i * 64) * K * 2, d + i * 8192);                       \
      gload_lds16(Bg + kb + (long)(i * 64) * K * 2, d + 32768 + i * 8192);               \
    }                                                                                    \
  };                                                                                     \
  f32x4 acc[8][4] = {};                                                                  \
  const int fr = lane & 15;                                                              \
  const int rd_kb = (lane >> 4) << 4;                                                    \
  const int swzr = ((lane >> 2) & 1) << 5;                                               \
  issue(0, 0); issue(1, 1);                                                              \
  for (int t = 0; t < NT; ++t) {                                                         \
    if (t + 1 < NT) asm volatile("s_waitcnt vmcnt(8)" ::: "memory");                     \
    else            asm volatile("s_waitcnt vmcnt(0)" ::: "memory");                     \
    __builtin_amdgcn_sched_barrier(0);                                                   \
    __builtin_amdgcn_s_barrier();                                                        \
    __builtin_amdgcn_sched_barrier(0);                                                   \
    const char* Ab = smem + (t & 1) * 65536;                                             \
    const char* Bb = Ab + 32768;                                                         \
    _Pragma("unroll")                                                                    \
    for (int ks = 0; ks < 2; ++ks) {                                                     \
      bf16x8 af[8], bfr[4];                                                              \
      _Pragma("unroll")                                                                  \
      for (int mi = 0; mi < 8; ++mi)                                                     \
        af[mi] = *(const bf16x8*)(Ab + (wr * 128 + mi * 16 + fr) * 128 +                 \
                                  ((ks * 64 + rd_kb) ^ swzr));                           \
      _Pragma("unroll")                                                                  \
      for (int ni = 0; ni < 4; ++ni)                                                     \
        bfr[ni] = *(const bf16x8*)(Bb + (wc * 64 + ni * 16 + fr) * 128 +                 \
                                   ((ks * 64 + rd_kb) ^ swzr));                          \
      _Pragma("unroll")                                                                  \
      for (int mi = 0; mi < 8; ++mi)                                                     \
        _Pragma("unroll")                                                                \
        for (int ni = 0; ni < 4; ++ni)                                                   \
          acc[mi][ni] = __builtin_amdgcn_mfma_f32_16x16x32_bf16(af[mi], bfr[ni],         \
                                                                acc[mi][ni], 0, 0, 0);   \
    }                                                                                    \
    __builtin_amdgcn_sched_barrier(0);                                                   \
    __builtin_amdgcn_s_barrier();                                                        \
    __builtin_amdgcn_sched_barrier(0);                                                   \
    if (t + 2 < NT) issue(t + 2, t & 1);                                                 \
  }

// QKV: Cb = bf16(A @ Bt^T), no bias.
__global__ __launch_bounds__(512, 2) void gemm256_bt(
    const u16* __restrict__ A, const u16* __restrict__ Bt,
    u16* __restrict__ Cb, int Mact, int N)
{
  __shared__ char smem[131072];
  G256_LOOP
  const int cl = fr, hi = lane >> 4;
#pragma unroll
  for (int mi = 0; mi < 8; ++mi)
#pragma unroll
    for (int r = 0; r < 4; ++r) {
      long row = arow0 + wr * 128 + mi * 16 + hi * 4 + r;
      if (row < Mact) {
#pragma unroll
        for (int ni = 0; ni < 4; ++ni)
          Cb[row * (long)N + brow0 + wc * 64 + ni * 16 + cl] = f2b(acc[mi][ni][r]);
      }
    }
}

// FFN1 fused: permuted PW1 (transpose_w1 layout); block covers np [c*256,c*256+256) =
// [a(2c):64 | g(2c):64 | a(2c+1):64 | g(2c+1):64]. Waves wc even hold a, odd hold g
// (same rows); g exchanged via LDS reuse (4 x 32KB f32 = 128KB exact).
__global__ __launch_bounds__(512, 2) void gemm256_w1(
    const u16* __restrict__ A, const u16* __restrict__ Bt,
    const float* __restrict__ bias, u16* __restrict__ HACT, int Mact)
{
  __shared__ char smem[131072];
  G256_LOOP
  const int cl = fr, hi = lane >> 4;
  const int p = wc >> 1;
  const int cbase = blockIdx.x * 128 + p * 64;        // HACT column base for this pair
  float* gx = (float*)smem + (wr * 2 + p) * 8192;     // 128 rows x 64 cols f32
  if (wc & 1) {                                        // g-wave: write g+bias to LDS
#pragma unroll
    for (int mi = 0; mi < 8; ++mi)
#pragma unroll
      for (int r = 0; r < 4; ++r) {
        int rowl = mi * 16 + hi * 4 + r;
#pragma unroll
        for (int ni = 0; ni < 4; ++ni)
          gx[rowl * 64 + ni * 16 + cl] = acc[mi][ni][r] + bias[4096 + cbase + ni * 16 + cl];
      }
  }
  __syncthreads();
  if (!(wc & 1)) {                                     // a-wave: fuse a*gelu(g), store
    float bv[4];
#pragma unroll
    for (int ni = 0; ni < 4; ++ni) bv[ni] = bias[cbase + ni * 16 + cl];
#pragma unroll
    for (int mi = 0; mi < 8; ++mi)
#pragma unroll
      for (int r = 0; r < 4; ++r) {
        int rowl = mi * 16 + hi * 4 + r;
        long row = arow0 + wr * 128 + rowl;
        if (row < Mact) {
#pragma unroll
          for (int ni = 0; ni < 4; ++ni) {
            float a = acc[mi][ni][r] + bv[ni];
            float g = gx[rowl * 64 + ni * 16 + cl];
            HACT[row * 4096L + cbase + ni * 16 + cl] = f2b(a * gelu_f(g));
          }
        }
      }
  }
}

// ---------------- transpose + f32->bf16 convert ----------------
__global__ __launch_bounds__(256) void transpose_cvt(
    const float* __restrict__ src, u16* __restrict__ dst,
    int R, int C, long sstride, long dstride)
{
  src += (long)blockIdx.z * sstride;
  dst += (long)blockIdx.z * dstride;
  __shared__ float tile[32][33];
  const int r0 = blockIdx.y * 32, c0 = blockIdx.x * 32;
  const int tx = threadIdx.x & 31, ty = threadIdx.x >> 5;
#pragma unroll
  for (int i = 0; i < 32; i += 8) {
    int r = r0 + ty + i, c = c0 + tx;
    if (r < R && c < C) tile[ty + i][tx] = src[(long)r * C + c];
  }
  __syncthreads();
#pragma unroll
  for (int i = 0; i < 32; i += 8) {
    int c = c0 + ty + i, r = r0 + tx;
    if (c < C && r < R) dst[(long)c * R + r] = f2b(tile[tx][ty + i]);
  }
}

// ---------------- w1 permuted transpose ----------------
__global__ __launch_bounds__(256) void transpose_w1(
    const float* __restrict__ src, u16* __restrict__ dst)
{
  __shared__ float tile[32][33];
  const int r0 = blockIdx.y * 32, c0 = blockIdx.x * 32;
  const int tx = threadIdx.x & 31, ty = threadIdx.x >> 5;
#pragma unroll
  for (int i = 0; i < 32; i += 8)
    tile[ty + i][tx] = src[(long)(r0 + ty + i) * 8192 + c0 + tx];
  __syncthreads();
#pragma unroll
  for (int i = 0; i < 32; i += 8) {
    int n = c0 + ty + i;
    int np = (n < 4096) ? ((n >> 6) * 128 + (n & 63))
                        : (((n - 4096) >> 6) * 128 + 64 + ((n - 4096) & 63));
    dst[(long)np * 1024 + r0 + tx] = f2b(tile[tx][ty + i]);
  }
}

// ---------------- build XT = concat(cls, tokens) + pos ----------------
__global__ __launch_bounds__(256) void build_xt(
    const float* __restrict__ TOK, const float* __restrict__ cls,
    const float* __restrict__ pos, float* __restrict__ XT)
{
  const int row = blockIdx.x, tid = threadIdx.x;
  const int b = row / SEQ, s = row % SEQ;
  float4 p = ((const float4*)(pos + (long)s * 1024))[tid];
  float4 t;
  if (s == 0) t = ((const float4*)cls)[tid];
  else        t = ((const float4*)(TOK + ((long)b * 3136 + (s - 1)) * 1024))[tid];
  float4 r; r.x = t.x + p.x; r.y = t.y + p.y; r.z = t.z + p.z; r.w = t.w + p.w;
  ((float4*)(XT + (long)row * 1024))[tid] = r;
}

// ---------------- LayerNorm (f32 in) -> bf16 out ----------------
__global__ __launch_bounds__(256) void ln_rows(
    const float* __restrict__ X, const float* __restrict__ g,
    const float* __restrict__ b, u16* __restrict__ Y)
{
  const int row = blockIdx.x, tid = threadIdx.x;
  const int lane = tid & 63, wid = tid >> 6;
  float4 x = ((const float4*)(X + (long)row * 1024))[tid];
  float s = x.x + x.y + x.z + x.w;
  float q = x.x * x.x + x.y * x.y + x.z * x.z + x.w * x.w;
#pragma unroll
  for (int o = 32; o; o >>= 1) { s += __shfl_xor(s, o); q += __shfl_xor(q, o); }
  __shared__ float ls[4], lq[4];
  if (lane == 0) { ls[wid] = s; lq[wid] = q; }
  __syncthreads();
  s = ls[0] + ls[1] + ls[2] + ls[3];
  q = lq[0] + lq[1] + lq[2] + lq[3];
  const float mean = s * (1.0f / 1024.0f);
  const float rstd = rsqrtf(q * (1.0f / 1024.0f) - mean * mean + 1e-5f);
  float4 gg = ((const float4*)g)[tid];
  float4 bb = ((const float4*)b)[tid];
  ushort4 o4;
  o4.x = f2b((x.x - mean) * rstd * gg.x + bb.x);
  o4.y = f2b((x.y - mean) * rstd * gg.y + bb.y);
  o4.z = f2b((x.z - mean) * rstd * gg.z + bb.z);
  o4.w = f2b((x.w - mean) * rstd * gg.w + bb.w);
  ((ushort4*)(Y + (long)row * 1024))[tid] = o4;
}

// ---------------- cls attention, split-K partial ----------------
__global__ __launch_bounds__(256) void attn_cls_part(
    const u16* __restrict__ QKV, float* __restrict__ PART, const void* __restrict__ maskp)
{
  const int c = blockIdx.x, bh = blockIdx.y;
  const int b = bh >> 4, h = bh & 15;
  const long rowbase = (long)b * SEQ;
  const int tid = threadIdx.x, lane = tid & 63, w = tid >> 6;
  const int rs = lane >> 3, c8 = lane & 7;
  const int start = c * CHK;
  const int end = (start + CHK < SEQ) ? start + CHK : SEQ;

  float qf[8];
  {
    u16x8 qv = *(const u16x8*)(QKV + rowbase * 3072 + h * 64 + c8 * 8);
#pragma unroll
    for (int i = 0; i < 8; ++i) qf[i] = b2f(qv[i]) * 0.125f;
  }

  float m_run = -3.4e38f, s_run = 0.f;
  float acc[8] = {};

  for (int j8 = start + w * 8; j8 < end; j8 += 32) {
    int j = j8 + rs;
    bool valid = (j < end);
    int jc = valid ? j : (end - 1);
    const u16* kp = QKV + (rowbase + jc) * 3072 + 1024 + h * 64 + c8 * 8;
    u16x8 kv = *(const u16x8*)kp;
    u16x8 vv = *(const u16x8*)(kp + 1024);
    float sim = 0.f;
#pragma unroll
    for (int i = 0; i < 8; ++i) sim += b2f(kv[i]) * qf[i];
    sim += __shfl_xor(sim, 1); sim += __shfl_xor(sim, 2); sim += __shfl_xor(sim, 4);
    bool ok = valid && ((jc == 0) || read_bool(maskp, b * 16 + (jc - 1) / 196));
    float simv = ok ? sim : -3.4e38f;
    float mx = simv;
    mx = fmaxf(mx, __shfl_xor(mx, 8));
    mx = fmaxf(mx, __shfl_xor(mx, 16));
    mx = fmaxf(mx, __shfl_xor(mx, 32));
    float new_m = fmaxf(m_run, mx);
    float scale = __expf(m_run - new_m);
    float p = ok ? __expf(simv - new_m) : 0.f;
    m_run = new_m;
    s_run = s_run * scale + p;
#pragma unroll
    for (int i = 0; i < 8; ++i) acc[i] = acc[i] * scale + p * b2f(vv[i]);
  }
#pragma unroll
  for (int o = 8; o <= 32; o <<= 1) {
    s_run += __shfl_xor(s_run, o);
#pragma unroll
    for (int i = 0; i < 8; ++i) acc[i] += __shfl_xor(acc[i], o);
  }

  __shared__ float sm_m[4], sm_s[4], sm_a[4][64];
  if (lane == 0) { sm_m[w] = m_run; sm_s[w] = s_run; }
  if (rs == 0) {
#pragma unroll
    for (int i = 0; i < 8; ++i) sm_a[w][c8 * 8 + i] = acc[i];
  }
  __syncthreads();
  if (tid < 64) {
    float M = fmaxf(fmaxf(sm_m[0], sm_m[1]), fmaxf(sm_m[2], sm_m[3]));
    float S = 0.f, A = 0.f;
#pragma unroll
    for (int ww = 0; ww < 4; ++ww) {
      float e = __expf(sm_m[ww] - M);
      S += sm_s[ww] * e;
      A += sm_a[ww][tid] * e;
    }
    float* outp = PART + ((long)bh * NCC + c) * 72;
    outp[tid] = A;
    if (tid == 0) { outp[64] = M; outp[65] = S; }
  }
}

// ---------------- cls attention combine ----------------
__global__ __launch_bounds__(64) void attn_cls_comb(
    const float* __restrict__ PART, u16* __restrict__ ATT)
{
  const int bh = blockIdx.x, b = bh >> 4, h = bh & 15;
  const int d = threadIdx.x;
  float M = -3.4e38f;
#pragma unroll
  for (int c = 0; c < NCC; ++c) M = fmaxf(M, PART[((long)bh * NCC + c) * 72 + 64]);
  float S = 0.f, A = 0.f;
#pragma unroll
  for (int c = 0; c < NCC; ++c) {
    const float* p = PART + ((long)bh * NCC + c) * 72;
    float e = __expf(p[64] - M);
    S += p[65] * e;
    A += p[d] * e;
  }
  ATT[((long)b * SEQ) * 1024 + h * 64 + d] = f2b(A / S);
}

// ---------------- time attention: groups (b,h,n), 16 queries x 17 keys ----------------
__global__ __launch_bounds__(256) void attn_time(
    const u16* __restrict__ QKV, u16* __restrict__ ATT,
    const void* __restrict__ maskp, const void* __restrict__ idmp)
{
  const int g = blockIdx.x;
  const int n = g % 196;
  const int bh = g / 196;
  const int h = bh & 15, b = bh >> 4;
  const long rowbase = (long)b * SEQ;
  const int tid = threadIdx.x;
  __shared__ float q_s[16][65], k_s[17][65], v_s[17][65], p_s[16][18];
  for (int idx = tid; idx < 16 * 64; idx += 256) {
    int i = idx >> 6, d = idx & 63;
    q_s[i][d] = b2f(QKV[(rowbase + 1 + i * 196 + n) * 3072 + h * 64 + d]) * 0.125f;
  }
  for (int idx = tid; idx < 17 * 64; idx += 256) {
    int j = idx >> 6, d = idx & 63;
    long kr = (j == 0) ? rowbase : (rowbase + 1 + (long)(j - 1) * 196 + n);
    k_s[j][d] = b2f(QKV[kr * 3072 + 1024 + h * 64 + d]);
    v_s[j][d] = b2f(QKV[kr * 3072 + 2048 + h * 64 + d]);
  }
  __syncthreads();
#pragma unroll
  for (int pp = 0; pp < 2; ++pp) {
    int idx = tid + pp * 256;
    if (idx < 272) {
      int i = idx / 17, j = idx % 17;
      float s = 0.f;
      for (int d = 0; d < 64; ++d) s += q_s[i][d] * k_s[j][d];
      bool ok = (j == 0) ||
                (read_bool(maskp, b * 16 + (j - 1)) && read_bool(idmp, (b * 16 + i) * 16 + (j - 1)));
      p_s[i][j] = ok ? s : -3.4e38f;
    }
  }
  __syncthreads();
  if (tid < 16) {
    float m = -3.4e38f;
    for (int j = 0; j < 17; ++j) m = fmaxf(m, p_s[tid][j]);
    float su = 0.f;
    for (int j = 0; j < 17; ++j) { float e = __expf(p_s[tid][j] - m); p_s[tid][j] = e; su += e; }
    float inv = 1.0f / su;
    for (int j = 0; j < 17; ++j) p_s[tid][j] *= inv;
  }
  __syncthreads();
  for (int idx = tid; idx < 1024; idx += 256) {
    int i = idx >> 6, d = idx & 63;
    float o = 0.f;
#pragma unroll
    for (int j = 0; j < 17; ++j) o += p_s[i][j] * v_s[j][d];
    ATT[(rowbase + 1 + i * 196 + n) * 1024 + h * 64 + d] = f2b(o);
  }
}

// ---------------- space attention (MFMA): one block per (b,h,f) ----------------
__global__ __launch_bounds__(256) void attn_space(
    const u16* __restrict__ QKV, u16* __restrict__ ATT)
{
  const int g = blockIdx.x;             // bh*16 + f
  const int fr = g & 15, bh = g >> 4;
  const int h = bh & 15, b = bh >> 4;
  const long rowbase = (long)b * SEQ;
  const long qbase = rowbase + 1 + (long)fr * 196;
  const int tid = threadIdx.x, lane = tid & 63, wid = tid >> 6;

  __shared__ u16 Ks[208][72];
  __shared__ u16 Vt[64][232];
  __shared__ u16 Ps[4][16][232];

  for (int c = tid; c < 197 * 8; c += 256) {
    int row = c >> 3, k8 = c & 7;
    long kr = (row == 0) ? rowbase : (qbase + row - 1);
    *(u16x8*)&Ks[row][k8 * 8] = *(const u16x8*)(QKV + kr * 3072 + 1024 + h * 64 + k8 * 8);
  }
  for (int c = tid; c < 64 * 35; c += 256) {
    int d = c / 35, k = 197 + c % 35;
    Vt[d][k] = 0;
  }
  for (int c = tid; c < 4 * 16 * 24; c += 256) {
    int w = c / (16 * 24), rem = c % (16 * 24);
    Ps[w][rem / 24][208 + rem % 24] = 0;
  }
  for (int c = tid; c < 197 * 64; c += 256) {
    int k = c >> 6, d = c & 63;
    long vr = (k == 0) ? rowbase : (qbase + k - 1);
    Vt[d][k] = QKV[vr * 3072 + 2048 + h * 64 + d];
  }
  __syncthreads();

  const int cl = lane & 15, hi = lane >> 4;
  for (int mt = wid; mt < 13; mt += 4) {
    int qi0 = mt * 16 + cl;
    long qrow = qbase + (qi0 < 196 ? qi0 : 0);
    const u16* qp = QKV + qrow * 3072 + h * 64 + hi * 8;
    bf16x8 af0 = *(const bf16x8*)qp;
    bf16x8 af1 = *(const bf16x8*)(qp + 32);

    f32x4 acc[13];
#pragma unroll
    for (int nt = 0; nt < 13; ++nt) {
      acc[nt] = (f32x4){0.f, 0.f, 0.f, 0.f};
      bf16x8 b0 = *(const bf16x8*)&Ks[nt * 16 + cl][hi * 8];
      acc[nt] = __builtin_amdgcn_mfma_f32_16x16x32_bf16(af0, b0, acc[nt], 0, 0, 0);
      bf16x8 b1 = *(const bf16x8*)&Ks[nt * 16 + cl][32 + hi * 8];
      acc[nt] = __builtin_amdgcn_mfma_f32_16x16x32_bf16(af1, b1, acc[nt], 0, 0, 0);
    }
    float mx[4] = {-3.4e38f, -3.4e38f, -3.4e38f, -3.4e38f};
#pragma unroll
    for (int nt = 0; nt < 13; ++nt) {
      int col = nt * 16 + cl;
#pragma unroll
      for (int r = 0; r < 4; ++r) {
        float s = acc[nt][r] * 0.125f;
        if (col >= 197) s = -3.4e38f;
        acc[nt][r] = s;
        mx[r] = fmaxf(mx[r], s);
      }
    }
#pragma unroll
    for (int r = 0; r < 4; ++r) {
#pragma unroll
      for (int o = 8; o; o >>= 1) mx[r] = fmaxf(mx[r], __shfl_xor(mx[r], o));
    }
    float sum[4] = {0.f, 0.f, 0.f, 0.f};
#pragma unroll
    for (int nt = 0; nt < 13; ++nt) {
      int col = nt * 16 + cl;
#pragma unroll
      for (int r = 0; r < 4; ++r) {
        float p = __expf(acc[nt][r] - mx[r]);
        sum[r] += p;
        Ps[wid][hi * 4 + r][col] = f2b(p);
      }
    }
    float inv[4];
#pragma unroll
    for (int r = 0; r < 4; ++r) {
#pragma unroll
      for (int o = 8; o; o >>= 1) sum[r] += __shfl_xor(sum[r], o);
      inv[r] = 1.0f / sum[r];
    }
    f32x4 ov[4];
#pragma unroll
    for (int dt = 0; dt < 4; ++dt) ov[dt] = (f32x4){0.f, 0.f, 0.f, 0.f};
#pragma unroll
    for (int ks = 0; ks < 7; ++ks) {
      bf16x8 pa = *(const bf16x8*)&Ps[wid][cl][ks * 32 + hi * 8];
#pragma unroll
      for (int dt = 0; dt < 4; ++dt) {
        bf16x8 vb = *(const bf16x8*)&Vt[dt * 16 + cl][ks * 32 + hi * 8];
        ov[dt] = __builtin_amdgcn_mfma_f32_16x16x32_bf16(pa, vb, ov[dt], 0, 0, 0);
      }
    }
#pragma unroll
    for (int r = 0; r < 4; ++r) {
      int qi = mt * 16 + hi * 4 + r;
      if (qi < 196) {
        long orow = (qbase + qi) * 1024 + h * 64;
#pragma unroll
        for (int dt = 0; dt < 4; ++dt)
          ATT[orow + dt * 16 + cl] = f2b(ov[dt][r] * inv[r]);
      }
    }
  }
}

// ---------------- final head: LN(cls) @ o_w + o_b ----------------
__global__ __launch_bounds__(256) void final_head(
    const float* __restrict__ XT, const float* __restrict__ g,
    const float* __restrict__ b, const float* __restrict__ ow,
    const float* __restrict__ ob, float* __restrict__ out)
{
  const int bb = blockIdx.x, tid = threadIdx.x;
  const int lane = tid & 63, wid = tid >> 6;
  float4 x = ((const float4*)(XT + (long)bb * SEQ * 1024))[tid];
  float s = x.x + x.y + x.z + x.w;
  float q = x.x * x.x + x.y * x.y + x.z * x.z + x.w * x.w;
#pragma unroll
  for (int o = 32; o; o >>= 1) { s += __shfl_xor(s, o); q += __shfl_xor(q, o); }
  __shared__ float ls[4], lq[4], lt[4];
  if (lane == 0) { ls[wid] = s; lq[wid] = q; }
  __syncthreads();
  s = ls[0] + ls[1] + ls[2] + ls[3];
  q = lq[0] + lq[1] + lq[2] + lq[3];
  const float mean = s * (1.0f / 1024.0f);
  const float rstd = rsqrtf(q * (1.0f / 1024.0f) - mean * mean + 1e-5f);
  float4 gg = ((const float4*)g)[tid];
  float4 bv = ((const float4*)b)[tid];
  float4 wv = ((const float4*)ow)[tid];
  float t = ((x.x - mean) * rstd * gg.x + bv.x) * wv.x
          + ((x.y - mean) * rstd * gg.y + bv.y) * wv.y
          + ((x.z - mean) * rstd * gg.z + bv.z) * wv.z
          + ((x.w - mean) * rstd * gg.w + bv.w) * wv.w;
#pragma unroll
  for (int o = 32; o; o >>= 1) t += __shfl_xor(t, o);
  if (lane == 0) lt[wid] = t;
  __syncthreads();
  if (tid == 0) out[bb] = lt[0] + lt[1] + lt[2] + lt[3] + ob[0];
}

// ==========================================================================
extern "C" void kernel_launch(void* const* d_in, const int* in_sizes, int n_in,
                              void* d_out, int out_size, void* d_ws, size_t ws_size,
                              hipStream_t stream) {
  const float* x       = (const float*)d_in[0];
  const void*  maskp   = d_in[1];
  const void*  idmp    = d_in[2];
  const float* patch_w = (const float*)d_in[3];
  const float* patch_b = (const float*)d_in[4];
  const float* cls_tok = (const float*)d_in[5];
  const float* pos_emb = (const float*)d_in[6];
  const float* t_ng = (const float*)d_in[7];
  const float* t_nb = (const float*)d_in[8];
  const float* t_qkv = (const float*)d_in[9];
  const float* t_ow = (const float*)d_in[10];
  const float* t_ob = (const float*)d_in[11];
  const float* s_ng = (const float*)d_in[12];
  const float* s_nb = (const float*)d_in[13];
  const float* s_qkv = (const float*)d_in[14];
  const float* s_ow = (const float*)d_in[15];
  const float* s_ob = (const float*)d_in[16];
  const float* f_ng = (const float*)d_in[17];
  const float* f_nb = (const float*)d_in[18];
  const float* f_w1 = (const float*)d_in[19];
  const float* f_b1 = (const float*)d_in[20];
  const float* f_w2 = (const float*)d_in[21];
  const float* f_b2 = (const float*)d_in[22];
  const float* o_ng = (const float*)d_in[23];
  const float* o_nb = (const float*)d_in[24];
  const float* o_w  = (const float*)d_in[25];
  const float* o_b  = (const float*)d_in[26];
  float* out = (float*)d_out;

  // ---- workspace layout (~199 MB) ----
  const size_t szXT   = (size_t)ROWS * 1024 * 4;
  const size_t szXNA  = (size_t)MPADA * 1024 * 2;     // 12800 rows (256-tile M extent)
  const size_t szBIG  = (size_t)MPAD * 4096 * 2;
  const size_t szWBUF = (size_t)8192 * 1024 * 2;
  size_t off = 0;
  auto take = [&](size_t b) { size_t o = off; off += (b + 255) & ~(size_t)255; return o; };
  char* base = (char*)d_ws;
  float* XT  = (float*)(base + take(szXT));
  u16*  XNA  = (u16*)(base + take(szXNA));
  char* BIG  = base + take(szBIG);
  u16*  WBUF = (u16*)(base + take(szWBUF));
  if (off > ws_size) return;                              // ws too small: fail clean

  u16*   QKV  = (u16*)BIG;
  u16*   HACT = (u16*)BIG;
  u16*   Xtr  = (u16*)BIG;
  float* TOK  = (float*)(BIG + (size_t)40 * 1024 * 1024);
  float* PART = (float*)(BIG + (size_t)MPAD * 3072 * 2);  // after QKV extent

  auto tr = [&](const float* s, u16* d, int R, int C) {
    dim3 gr((C + 31) / 32, (R + 31) / 32, 1);
    transpose_cvt<<<gr, 256, 0, stream>>>(s, d, R, C, 0, 0);
  };

  // ---- patch embedding ----
  {
    dim3 gr((196 + 31) / 32, (1280 + 31) / 32, 64);
    transpose_cvt<<<gr, 256, 0, stream>>>(x, Xtr, 1280, 196, 1280L * 196, 196L * 1280);
  }
  tr(patch_w, WBUF, 1280, 1024);
  gemm_bt<0><<<dim3(8, 98), 256, 0, stream>>>(Xtr, WBUF, patch_b, TOK, nullptr, NTOK, 1024, 1280);
  build_xt<<<ROWS, 256, 0, stream>>>(TOK, cls_tok, pos_emb, XT);

  for (int L = 0; L < 2; ++L) {
    // ---- time attention block ----
    tr(t_qkv + (size_t)L * 1024 * 3072, WBUF, 1024, 3072);
    ln_rows<<<ROWS, 256, 0, stream>>>(XT, t_ng + L * 1024, t_nb + L * 1024, XNA);
    gemm256_bt<<<dim3(12, 50), 512, 0, stream>>>(XNA, WBUF, QKV, ROWS, 3072);
    tr(t_ow + (size_t)L * 1024 * 1024, WBUF, 1024, 1024);
    attn_cls_part<<<dim3(NCC, 64), 256, 0, stream>>>(QKV, PART, maskp);
    attn_cls_comb<<<64, 64, 0, stream>>>(PART, XNA);
    attn_time<<<NTOK, 256, 0, stream>>>(QKV, XNA, maskp, idmp);
    gemm_bt<1><<<dim3(8, 99), 256, 0, stream>>>(XNA, WBUF, t_ob + L * 1024, XT, nullptr, ROWS, 1024, 1024);
    // ---- space attention block ----
    tr(s_qkv + (size_t)L * 1024 * 3072, WBUF, 1024, 3072);
    ln_rows<<<ROWS, 256, 0, stream>>>(XT, s_ng + L * 1024, s_nb + L * 1024, XNA);
    gemm256_bt<<<dim3(12, 50), 512, 0, stream>>>(XNA, WBUF, QKV, ROWS, 3072);
    tr(s_ow + (size_t)L * 1024 * 1024, WBUF, 1024, 1024);
    attn_cls_part<<<dim3(NCC, 64), 256, 0, stream>>>(QKV, PART, maskp);
    attn_cls_comb<<<64, 64, 0, stream>>>(PART, XNA);
    attn_space<<<1024, 256, 0, stream>>>(QKV, XNA);
    gemm_bt<1><<<dim3(8, 99), 256, 0, stream>>>(XNA, WBUF, s_ob + L * 1024, XT, nullptr, ROWS, 1024, 1024);
    // ---- FFN (gate fused into GEMM1 epilogue) ----
    transpose_w1<<<dim3(256, 32), 256, 0, stream>>>(f_w1 + (size_t)L * 1024 * 8192, WBUF);
    ln_rows<<<ROWS, 256, 0, stream>>>(XT, f_ng + L * 1024, f_nb + L * 1024, XNA);
    gemm256_w1<<<dim3(32, 50), 512, 0, stream>>>(XNA, WBUF, f_b1 + L * 8192, HACT, ROWS);
    tr(f_w2 + (size_t)L * 4096 * 1024, WBUF, 4096, 1024);
    gemm_bt<1><<<dim3(8, 99), 256, 0, stream>>>(HACT, WBUF, f_b2 + L * 1024, XT, nullptr, ROWS, 1024, 4096);
  }
  final_head<<<4, 256, 0, stream>>>(XT, o_ng, o_nb, o_w, o_b, out);
}

// Round 11
// 2116.079 us; speedup vs baseline: 1.0964x; 1.0496x over previous
//
#include <hip/hip_runtime.h>

// SizeInvariantTimeSformer forward on MI355X (gfx950).
// fp32 residual stream. All big GEMMs: 128x128 tile, BK=32, 3-buffer ring with
// counted vmcnt(4) + one s_barrier per K-tile (loads stay in flight across barriers),
// 48KB LDS -> 3 blocks/CU, 2-bit k-group swizzle (conflict-free), T5 setprio.
// attn_space MFMA; attn_cls split-K flash.

typedef unsigned short u16;
typedef __bf16 bf16x8 __attribute__((ext_vector_type(8)));
typedef float f32x4 __attribute__((ext_vector_type(4)));
typedef u16 u16x8 __attribute__((ext_vector_type(8)));

#define SEQ   3137
#define ROWS  12548   // B * SEQ
#define MPAD  12672   // 99 * 128
#define MPADA 12800   // XNA row allocation (superset)
#define NTOK  12544   // B * F * 196
#define NCC   16      // cls split-K chunks
#define CHK   197     // ceil(SEQ/NCC)

__device__ __forceinline__ u16 f2b(float f) {
  union { float f; unsigned u; } v; v.f = f;
  unsigned r = v.u + 0x7FFFu + ((v.u >> 16) & 1u);   // RNE
  return (u16)(r >> 16);
}
__device__ __forceinline__ float b2f(u16 u) {
  union { unsigned u; float f; } v; v.u = ((unsigned)u) << 16;
  return v.f;
}
__device__ __forceinline__ float gelu_f(float g) {
  return 0.5f * g * (1.0f + erff(g * 0.70710678118654752f));
}
// bool inputs may arrive as uint8 bytes, int32 words, or float32 words.
__device__ __forceinline__ bool read_bool(const void* p, int idx) {
  const unsigned* w = (const unsigned*)p;
  unsigned w0 = w[0];
  if (w0 == 1u || w0 == 0u) return ((const int*)p)[idx] != 0;   // int32-encoded
  if (w0 == 0x3F800000u) return w[idx] != 0;                    // float32-encoded
  return ((const unsigned char*)p)[idx] != 0;                   // uint8-encoded
}

typedef const __attribute__((address_space(1))) void GVOID;
typedef __attribute__((address_space(3))) void LVOID;
__device__ __forceinline__ void gload_lds16(const void* g, void* l) {
  __builtin_amdgcn_global_load_lds((GVOID*)g, (LVOID*)l, 16, 0, 0);
}

// ---- 3-buffer BK=32 pipelined K-loop (shared by gemm_bt and gemm_w1_fused) ----
// LDS: 3 bufs x (A[128][32] 8KB + B[128][32] 8KB) = 48KB.
// Swizzle: logical (row,k16) stored at physical k16 ^ ((row>>1)&3)  (involution).
// Ledger: issue(U+2) after tile-U barrier writes buf((U+2)%3), freed at boundary
// (U-1 -> U); at boundary U -> U+1 outstanding = tile U+2's 4 loads -> vmcnt(4).
#define G128_LOOP(KVAL)                                                                  \
  const int K = (KVAL);                                                                  \
  const int NT = K >> 5;                                                                 \
  const int tid  = threadIdx.x;                                                          \
  const int lane = tid & 63, wid = tid >> 6;                                             \
  const int wm = wid >> 1, wn = wid & 1;                                                 \
  const long arow0 = (long)blockIdx.y * 128;                                             \
  const long brow0 = (long)blockIdx.x * 128;                                             \
  const int  s_row = tid >> 2;                                        /* 0..63 */       \
  const int  s_swz = (((tid & 3) ^ ((tid >> 3) & 3)) << 4);                              \
  const char* Ag = (const char*)A + (arow0 + s_row) * (long)K * 2 + s_swz;               \
  const char* Bg = (const char*)Bt + (brow0 + s_row) * (long)K * 2 + s_swz;              \
  auto issue = [&](int t) {                                                              \
    char* d = smem + (t % 3) * 16384 + tid * 16;                                         \
    const long kb = (long)t * 64;                                                        \
    gload_lds16(Ag + kb,                    d);                                          \
    gload_lds16(Ag + kb + (long)64 * K * 2, d + 4096);                                   \
    gload_lds16(Bg + kb,                    d + 8192);                                   \
    gload_lds16(Bg + kb + (long)64 * K * 2, d + 12288);                                  \
  };                                                                                     \
  f32x4 acc[4][4] = {};                                                                  \
  const int rd_row_a = wm * 64 + (lane & 15);                                            \
  const int rd_row_b = wn * 64 + (lane & 15);                                            \
  const int rd_kb    = (lane >> 4) << 4;                                                 \
  const int rxor     = ((lane >> 1) & 3) << 4;                                           \
  issue(0); issue(1);                                                                    \
  for (int t = 0; t < NT; ++t) {                                                         \
    if (t + 1 < NT) asm volatile("s_waitcnt vmcnt(4)" ::: "memory");                     \
    else            asm volatile("s_waitcnt vmcnt(0)" ::: "memory");                     \
    __builtin_amdgcn_sched_barrier(0);                                                   \
    __builtin_amdgcn_s_barrier();                                                        \
    __builtin_amdgcn_sched_barrier(0);                                                   \
    const char* Ab = smem + (t % 3) * 16384;                                             \
    const char* Bb = Ab + 8192;                                                          \
    bf16x8 af[4], bfr[4];                                                                \
    _Pragma("unroll")                                                                    \
    for (int mi = 0; mi < 4; ++mi)                                                       \
      af[mi] = *(const bf16x8*)(Ab + (rd_row_a + mi * 16) * 64 + (rd_kb ^ rxor));        \
    _Pragma("unroll")                                                                    \
    for (int ni = 0; ni < 4; ++ni)                                                       \
      bfr[ni] = *(const bf16x8*)(Bb + (rd_row_b + ni * 16) * 64 + (rd_kb ^ rxor));       \
    __builtin_amdgcn_s_setprio(1);                                                       \
    _Pragma("unroll")                                                                    \
    for (int mi = 0; mi < 4; ++mi)                                                       \
      _Pragma("unroll")                                                                  \
      for (int ni = 0; ni < 4; ++ni)                                                     \
        acc[mi][ni] = __builtin_amdgcn_mfma_f32_16x16x32_bf16(af[mi], bfr[ni],           \
                                                              acc[mi][ni], 0, 0, 0);     \
    __builtin_amdgcn_s_setprio(0);                                                       \
    if (t + 2 < NT) issue(t + 2);                                                        \
  }

// ---------------- GEMM: C[M,N] = A[M,K](bf16) * Bt[N,K](bf16)^T (+bias) ----------------
// MODE 0: Cf = acc+bias   MODE 1: Cf += acc+bias   MODE 2: Cb = bf16(acc+bias)
template<int MODE>
__global__ __launch_bounds__(256) void gemm_bt(
    const u16* __restrict__ A, const u16* __restrict__ Bt,
    const float* __restrict__ bias,
    float* __restrict__ Cf, u16* __restrict__ Cb,
    int Mact, int N, int Kin)
{
  __shared__ char smem[49152];
  G128_LOOP(Kin)

  const int ccol0 = (int)brow0 + wn * 64 + (lane & 15);
  const int rsub  = (lane >> 4) * 4;
  float bv[4];
#pragma unroll
  for (int ni = 0; ni < 4; ++ni) bv[ni] = bias ? bias[ccol0 + ni * 16] : 0.0f;
#pragma unroll
  for (int mi = 0; mi < 4; ++mi) {
#pragma unroll
    for (int r = 0; r < 4; ++r) {
      long row = arow0 + wm * 64 + mi * 16 + rsub + r;
      if (row < Mact) {
#pragma unroll
        for (int ni = 0; ni < 4; ++ni) {
          float v = acc[mi][ni][r] + bv[ni];
          long idx = row * (long)N + ccol0 + ni * 16;
          if (MODE == 0)      Cf[idx] = v;
          else if (MODE == 1) Cf[idx] += v;
          else                Cb[idx] = f2b(v);
        }
      }
    }
  }
}

// ---------------- FFN1 fused: H = XN @ PW1^T + b1 (permuted), HACT = a * gelu(g) --------
// PW1 rows: block c (128 rows) = [a-cols c*64..+63 | g-cols 4096+c*64..+63].
// Waves wn=0 hold a, wn=1 hold g; g exchanged via LDS reuse (gx stride 68).
__global__ __launch_bounds__(256) void gemm_w1_fused(
    const u16* __restrict__ A, const u16* __restrict__ Bt,
    const float* __restrict__ bias, u16* __restrict__ HACT, int Mact)
{
  __shared__ char smem[49152];
  G128_LOOP(1024)

  float* gx = (float*)smem;          // reuse: 2*64*68*4 = 34.8KB <= 48KB
  const int colb  = lane & 15;
  const int rsub  = (lane >> 4) * 4;
  const int cbase = blockIdx.x * 64;
  float bv[4];
#pragma unroll
  for (int ni = 0; ni < 4; ++ni)
    bv[ni] = bias[(wn ? 4096 : 0) + cbase + ni * 16 + colb];

  __syncthreads();                   // staging LDS dead (vmcnt(0) at last tile)
  if (wn == 1) {
#pragma unroll
    for (int mi = 0; mi < 4; ++mi)
#pragma unroll
      for (int r = 0; r < 4; ++r) {
        int rl = mi * 16 + rsub + r;
#pragma unroll
        for (int ni = 0; ni < 4; ++ni)
          gx[(wm * 64 + rl) * 68 + ni * 16 + colb] = acc[mi][ni][r] + bv[ni];
      }
  }
  __syncthreads();
  if (wn == 0) {
#pragma unroll
    for (int mi = 0; mi < 4; ++mi)
#pragma unroll
      for (int r = 0; r < 4; ++r) {
        int rl = mi * 16 + rsub + r;
        long row = arow0 + wm * 64 + rl;
        if (row < Mact) {
#pragma unroll
          for (int ni = 0; ni < 4; ++ni) {
            float a = acc[mi][ni][r] + bv[ni];
            float g = gx[(wm * 64 + rl) * 68 + ni * 16 + colb];
            HACT[row * 4096L + cbase + ni * 16 + colb] = f2b(a * gelu_f(g));
          }
        }
      }
  }
}

// ---------------- transpose + f32->bf16 convert ----------------
__global__ __launch_bounds__(256) void transpose_cvt(
    const float* __restrict__ src, u16* __restrict__ dst,
    int R, int C, long sstride, long dstride)
{
  src += (long)blockIdx.z * sstride;
  dst += (long)blockIdx.z * dstride;
  __shared__ float tile[32][33];
  const int r0 = blockIdx.y * 32, c0 = blockIdx.x * 32;
  const int tx = threadIdx.x & 31, ty = threadIdx.x >> 5;
#pragma unroll
  for (int i = 0; i < 32; i += 8) {
    int r = r0 + ty + i, c = c0 + tx;
    if (r < R && c < C) tile[ty + i][tx] = src[(long)r * C + c];
  }
  __syncthreads();
#pragma unroll
  for (int i = 0; i < 32; i += 8) {
    int c = c0 + ty + i, r = r0 + tx;
    if (c < C && r < R) dst[(long)c * R + r] = f2b(tile[tx][ty + i]);
  }
}

// ---------------- w1 permuted transpose ----------------
__global__ __launch_bounds__(256) void transpose_w1(
    const float* __restrict__ src, u16* __restrict__ dst)
{
  __shared__ float tile[32][33];
  const int r0 = blockIdx.y * 32, c0 = blockIdx.x * 32;
  const int tx = threadIdx.x & 31, ty = threadIdx.x >> 5;
#pragma unroll
  for (int i = 0; i < 32; i += 8)
    tile[ty + i][tx] = src[(long)(r0 + ty + i) * 8192 + c0 + tx];
  __syncthreads();
#pragma unroll
  for (int i = 0; i < 32; i += 8) {
    int n = c0 + ty + i;
    int np = (n < 4096) ? ((n >> 6) * 128 + (n & 63))
                        : (((n - 4096) >> 6) * 128 + 64 + ((n - 4096) & 63));
    dst[(long)np * 1024 + r0 + tx] = f2b(tile[tx][ty + i]);
  }
}

// ---------------- build XT = concat(cls, tokens) + pos ----------------
__global__ __launch_bounds__(256) void build_xt(
    const float* __restrict__ TOK, const float* __restrict__ cls,
    const float* __restrict__ pos, float* __restrict__ XT)
{
  const int row = blockIdx.x, tid = threadIdx.x;
  const int b = row / SEQ, s = row % SEQ;
  float4 p = ((const float4*)(pos + (long)s * 1024))[tid];
  float4 t;
  if (s == 0) t = ((const float4*)cls)[tid];
  else        t = ((const float4*)(TOK + ((long)b * 3136 + (s - 1)) * 1024))[tid];
  float4 r; r.x = t.x + p.x; r.y = t.y + p.y; r.z = t.z + p.z; r.w = t.w + p.w;
  ((float4*)(XT + (long)row * 1024))[tid] = r;
}

// ---------------- LayerNorm (f32 in) -> bf16 out ----------------
__global__ __launch_bounds__(256) void ln_rows(
    const float* __restrict__ X, const float* __restrict__ g,
    const float* __restrict__ b, u16* __restrict__ Y)
{
  const int row = blockIdx.x, tid = threadIdx.x;
  const int lane = tid & 63, wid = tid >> 6;
  float4 x = ((const float4*)(X + (long)row * 1024))[tid];
  float s = x.x + x.y + x.z + x.w;
  float q = x.x * x.x + x.y * x.y + x.z * x.z + x.w * x.w;
#pragma unroll
  for (int o = 32; o; o >>= 1) { s += __shfl_xor(s, o); q += __shfl_xor(q, o); }
  __shared__ float ls[4], lq[4];
  if (lane == 0) { ls[wid] = s; lq[wid] = q; }
  __syncthreads();
  s = ls[0] + ls[1] + ls[2] + ls[3];
  q = lq[0] + lq[1] + lq[2] + lq[3];
  const float mean = s * (1.0f / 1024.0f);
  const float rstd = rsqrtf(q * (1.0f / 1024.0f) - mean * mean + 1e-5f);
  float4 gg = ((const float4*)g)[tid];
  float4 bb = ((const float4*)b)[tid];
  ushort4 o4;
  o4.x = f2b((x.x - mean) * rstd * gg.x + bb.x);
  o4.y = f2b((x.y - mean) * rstd * gg.y + bb.y);
  o4.z = f2b((x.z - mean) * rstd * gg.z + bb.z);
  o4.w = f2b((x.w - mean) * rstd * gg.w + bb.w);
  ((ushort4*)(Y + (long)row * 1024))[tid] = o4;
}

// ---------------- cls attention, split-K partial ----------------
__global__ __launch_bounds__(256) void attn_cls_part(
    const u16* __restrict__ QKV, float* __restrict__ PART, const void* __restrict__ maskp)
{
  const int c = blockIdx.x, bh = blockIdx.y;
  const int b = bh >> 4, h = bh & 15;
  const long rowbase = (long)b * SEQ;
  const int tid = threadIdx.x, lane = tid & 63, w = tid >> 6;
  const int rs = lane >> 3, c8 = lane & 7;
  const int start = c * CHK;
  const int end = (start + CHK < SEQ) ? start + CHK : SEQ;

  float qf[8];
  {
    u16x8 qv = *(const u16x8*)(QKV + rowbase * 3072 + h * 64 + c8 * 8);
#pragma unroll
    for (int i = 0; i < 8; ++i) qf[i] = b2f(qv[i]) * 0.125f;
  }

  float m_run = -3.4e38f, s_run = 0.f;
  float acc[8] = {};

  for (int j8 = start + w * 8; j8 < end; j8 += 32) {
    int j = j8 + rs;
    bool valid = (j < end);
    int jc = valid ? j : (end - 1);
    const u16* kp = QKV + (rowbase + jc) * 3072 + 1024 + h * 64 + c8 * 8;
    u16x8 kv = *(const u16x8*)kp;
    u16x8 vv = *(const u16x8*)(kp + 1024);
    float sim = 0.f;
#pragma unroll
    for (int i = 0; i < 8; ++i) sim += b2f(kv[i]) * qf[i];
    sim += __shfl_xor(sim, 1); sim += __shfl_xor(sim, 2); sim += __shfl_xor(sim, 4);
    bool ok = valid && ((jc == 0) || read_bool(maskp, b * 16 + (jc - 1) / 196));
    float simv = ok ? sim : -3.4e38f;
    float mx = simv;
    mx = fmaxf(mx, __shfl_xor(mx, 8));
    mx = fmaxf(mx, __shfl_xor(mx, 16));
    mx = fmaxf(mx, __shfl_xor(mx, 32));
    float new_m = fmaxf(m_run, mx);
    float scale = __expf(m_run - new_m);
    float p = ok ? __expf(simv - new_m) : 0.f;
    m_run = new_m;
    s_run = s_run * scale + p;
#pragma unroll
    for (int i = 0; i < 8; ++i) acc[i] = acc[i] * scale + p * b2f(vv[i]);
  }
#pragma unroll
  for (int o = 8; o <= 32; o <<= 1) {
    s_run += __shfl_xor(s_run, o);
#pragma unroll
    for (int i = 0; i < 8; ++i) acc[i] += __shfl_xor(acc[i], o);
  }

  __shared__ float sm_m[4], sm_s[4], sm_a[4][64];
  if (lane == 0) { sm_m[w] = m_run; sm_s[w] = s_run; }
  if (rs == 0) {
#pragma unroll
    for (int i = 0; i < 8; ++i) sm_a[w][c8 * 8 + i] = acc[i];
  }
  __syncthreads();
  if (tid < 64) {
    float M = fmaxf(fmaxf(sm_m[0], sm_m[1]), fmaxf(sm_m[2], sm_m[3]));
    float S = 0.f, A = 0.f;
#pragma unroll
    for (int ww = 0; ww < 4; ++ww) {
      float e = __expf(sm_m[ww] - M);
      S += sm_s[ww] * e;
      A += sm_a[ww][tid] * e;
    }
    float* outp = PART + ((long)bh * NCC + c) * 72;
    outp[tid] = A;
    if (tid == 0) { outp[64] = M; outp[65] = S; }
  }
}

// ---------------- cls attention combine ----------------
__global__ __launch_bounds__(64) void attn_cls_comb(
    const float* __restrict__ PART, u16* __restrict__ ATT)
{
  const int bh = blockIdx.x, b = bh >> 4, h = bh & 15;
  const int d = threadIdx.x;
  float M = -3.4e38f;
#pragma unroll
  for (int c = 0; c < NCC; ++c) M = fmaxf(M, PART[((long)bh * NCC + c) * 72 + 64]);
  float S = 0.f, A = 0.f;
#pragma unroll
  for (int c = 0; c < NCC; ++c) {
    const float* p = PART + ((long)bh * NCC + c) * 72;
    float e = __expf(p[64] - M);
    S += p[65] * e;
    A += p[d] * e;
  }
  ATT[((long)b * SEQ) * 1024 + h * 64 + d] = f2b(A / S);
}

// ---------------- time attention: groups (b,h,n), 16 queries x 17 keys ----------------
__global__ __launch_bounds__(256) void attn_time(
    const u16* __restrict__ QKV, u16* __restrict__ ATT,
    const void* __restrict__ maskp, const void* __restrict__ idmp)
{
  const int g = blockIdx.x;
  const int n = g % 196;
  const int bh = g / 196;
  const int h = bh & 15, b = bh >> 4;
  const long rowbase = (long)b * SEQ;
  const int tid = threadIdx.x;
  __shared__ float q_s[16][65], k_s[17][65], v_s[17][65], p_s[16][18];
  for (int idx = tid; idx < 16 * 64; idx += 256) {
    int i = idx >> 6, d = idx & 63;
    q_s[i][d] = b2f(QKV[(rowbase + 1 + i * 196 + n) * 3072 + h * 64 + d]) * 0.125f;
  }
  for (int idx = tid; idx < 17 * 64; idx += 256) {
    int j = idx >> 6, d = idx & 63;
    long kr = (j == 0) ? rowbase : (rowbase + 1 + (long)(j - 1) * 196 + n);
    k_s[j][d] = b2f(QKV[kr * 3072 + 1024 + h * 64 + d]);
    v_s[j][d] = b2f(QKV[kr * 3072 + 2048 + h * 64 + d]);
  }
  __syncthreads();
#pragma unroll
  for (int pp = 0; pp < 2; ++pp) {
    int idx = tid + pp * 256;
    if (idx < 272) {
      int i = idx / 17, j = idx % 17;
      float s = 0.f;
      for (int d = 0; d < 64; ++d) s += q_s[i][d] * k_s[j][d];
      bool ok = (j == 0) ||
                (read_bool(maskp, b * 16 + (j - 1)) && read_bool(idmp, (b * 16 + i) * 16 + (j - 1)));
      p_s[i][j] = ok ? s : -3.4e38f;
    }
  }
  __syncthreads();
  if (tid < 16) {
    float m = -3.4e38f;
    for (int j = 0; j < 17; ++j) m = fmaxf(m, p_s[tid][j]);
    float su = 0.f;
    for (int j = 0; j < 17; ++j) { float e = __expf(p_s[tid][j] - m); p_s[tid][j] = e; su += e; }
    float inv = 1.0f / su;
    for (int j = 0; j < 17; ++j) p_s[tid][j] *= inv;
  }
  __syncthreads();
  for (int idx = tid; idx < 1024; idx += 256) {
    int i = idx >> 6, d = idx & 63;
    float o = 0.f;
#pragma unroll
    for (int j = 0; j < 17; ++j) o += p_s[i][j] * v_s[j][d];
    ATT[(rowbase + 1 + i * 196 + n) * 1024 + h * 64 + d] = f2b(o);
  }
}

// ---------------- space attention (MFMA): one block per (b,h,f) ----------------
__global__ __launch_bounds__(256) void attn_space(
    const u16* __restrict__ QKV, u16* __restrict__ ATT)
{
  const int g = blockIdx.x;             // bh*16 + f
  const int fr = g & 15, bh = g >> 4;
  const int h = bh & 15, b = bh >> 4;
  const long rowbase = (long)b * SEQ;
  const long qbase = rowbase + 1 + (long)fr * 196;
  const int tid = threadIdx.x, lane = tid & 63, wid = tid >> 6;

  __shared__ u16 Ks[208][72];
  __shared__ u16 Vt[64][232];
  __shared__ u16 Ps[4][16][232];

  for (int c = tid; c < 197 * 8; c += 256) {
    int row = c >> 3, k8 = c & 7;
    long kr = (row == 0) ? rowbase : (qbase + row - 1);
    *(u16x8*)&Ks[row][k8 * 8] = *(const u16x8*)(QKV + kr * 3072 + 1024 + h * 64 + k8 * 8);
  }
  for (int c = tid; c < 64 * 35; c += 256) {
    int d = c / 35, k = 197 + c % 35;
    Vt[d][k] = 0;
  }
  for (int c = tid; c < 4 * 16 * 24; c += 256) {
    int w = c / (16 * 24), rem = c % (16 * 24);
    Ps[w][rem / 24][208 + rem % 24] = 0;
  }
  for (int c = tid; c < 197 * 64; c += 256) {
    int k = c >> 6, d = c & 63;
    long vr = (k == 0) ? rowbase : (qbase + k - 1);
    Vt[d][k] = QKV[vr * 3072 + 2048 + h * 64 + d];
  }
  __syncthreads();

  const int cl = lane & 15, hi = lane >> 4;
  for (int mt = wid; mt < 13; mt += 4) {
    int qi0 = mt * 16 + cl;
    long qrow = qbase + (qi0 < 196 ? qi0 : 0);
    const u16* qp = QKV + qrow * 3072 + h * 64 + hi * 8;
    bf16x8 af0 = *(const bf16x8*)qp;
    bf16x8 af1 = *(const bf16x8*)(qp + 32);

    f32x4 acc[13];
#pragma unroll
    for (int nt = 0; nt < 13; ++nt) {
      acc[nt] = (f32x4){0.f, 0.f, 0.f, 0.f};
      bf16x8 b0 = *(const bf16x8*)&Ks[nt * 16 + cl][hi * 8];
      acc[nt] = __builtin_amdgcn_mfma_f32_16x16x32_bf16(af0, b0, acc[nt], 0, 0, 0);
      bf16x8 b1 = *(const bf16x8*)&Ks[nt * 16 + cl][32 + hi * 8];
      acc[nt] = __builtin_amdgcn_mfma_f32_16x16x32_bf16(af1, b1, acc[nt], 0, 0, 0);
    }
    float mx[4] = {-3.4e38f, -3.4e38f, -3.4e38f, -3.4e38f};
#pragma unroll
    for (int nt = 0; nt < 13; ++nt) {
      int col = nt * 16 + cl;
#pragma unroll
      for (int r = 0; r < 4; ++r) {
        float s = acc[nt][r] * 0.125f;
        if (col >= 197) s = -3.4e38f;
        acc[nt][r] = s;
        mx[r] = fmaxf(mx[r], s);
      }
    }
#pragma unroll
    for (int r = 0; r < 4; ++r) {
#pragma unroll
      for (int o = 8; o; o >>= 1) mx[r] = fmaxf(mx[r], __shfl_xor(mx[r], o));
    }
    float sum[4] = {0.f, 0.f, 0.f, 0.f};
#pragma unroll
    for (int nt = 0; nt < 13; ++nt) {
      int col = nt * 16 + cl;
#pragma unroll
      for (int r = 0; r < 4; ++r) {
        float p = __expf(acc[nt][r] - mx[r]);
        sum[r] += p;
        Ps[wid][hi * 4 + r][col] = f2b(p);
      }
    }
    float inv[4];
#pragma unroll
    for (int r = 0; r < 4; ++r) {
#pragma unroll
      for (int o = 8; o; o >>= 1) sum[r] += __shfl_xor(sum[r], o);
      inv[r] = 1.0f / sum[r];
    }
    f32x4 ov[4];
#pragma unroll
    for (int dt = 0; dt < 4; ++dt) ov[dt] = (f32x4){0.f, 0.f, 0.f, 0.f};
#pragma unroll
    for (int ks = 0; ks < 7; ++ks) {
      bf16x8 pa = *(const bf16x8*)&Ps[wid][cl][ks * 32 + hi * 8];
#pragma unroll
      for (int dt = 0; dt < 4; ++dt) {
        bf16x8 vb = *(const bf16x8*)&Vt[dt * 16 + cl][ks * 32 + hi * 8];
        ov[dt] = __builtin_amdgcn_mfma_f32_16x16x32_bf16(pa, vb, ov[dt], 0, 0, 0);
      }
    }
#pragma unroll
    for (int r = 0; r < 4; ++r) {
      int qi = mt * 16 + hi * 4 + r;
      if (qi < 196) {
        long orow = (qbase + qi) * 1024 + h * 64;
#pragma unroll
        for (int dt = 0; dt < 4; ++dt)
          ATT[orow + dt * 16 + cl] = f2b(ov[dt][r] * inv[r]);
      }
    }
  }
}

// ---------------- final head: LN(cls) @ o_w + o_b ----------------
__global__ __launch_bounds__(256) void final_head(
    const float* __restrict__ XT, const float* __restrict__ g,
    const float* __restrict__ b, const float* __restrict__ ow,
    const float* __restrict__ ob, float* __restrict__ out)
{
  const int bb = blockIdx.x, tid = threadIdx.x;
  const int lane = tid & 63, wid = tid >> 6;
  float4 x = ((const float4*)(XT + (long)bb * SEQ * 1024))[tid];
  float s = x.x + x.y + x.z + x.w;
  float q = x.x * x.x + x.y * x.y + x.z * x.z + x.w * x.w;
#pragma unroll
  for (int o = 32; o; o >>= 1) { s += __shfl_xor(s, o); q += __shfl_xor(q, o); }
  __shared__ float ls[4], lq[4], lt[4];
  if (lane == 0) { ls[wid] = s; lq[wid] = q; }
  __syncthreads();
  s = ls[0] + ls[1] + ls[2] + ls[3];
  q = lq[0] + lq[1] + lq[2] + lq[3];
  const float mean = s * (1.0f / 1024.0f);
  const float rstd = rsqrtf(q * (1.0f / 1024.0f) - mean * mean + 1e-5f);
  float4 gg = ((const float4*)g)[tid];
  float4 bv = ((const float4*)b)[tid];
  float4 wv = ((const float4*)ow)[tid];
  float t = ((x.x - mean) * rstd * gg.x + bv.x) * wv.x
          + ((x.y - mean) * rstd * gg.y + bv.y) * wv.y
          + ((x.z - mean) * rstd * gg.z + bv.z) * wv.z
          + ((x.w - mean) * rstd * gg.w + bv.w) * wv.w;
#pragma unroll
  for (int o = 32; o; o >>= 1) t += __shfl_xor(t, o);
  if (lane == 0) lt[wid] = t;
  __syncthreads();
  if (tid == 0) out[bb] = lt[0] + lt[1] + lt[2] + lt[3] + ob[0];
}

// ==========================================================================
extern "C" void kernel_launch(void* const* d_in, const int* in_sizes, int n_in,
                              void* d_out, int out_size, void* d_ws, size_t ws_size,
                              hipStream_t stream) {
  const float* x       = (const float*)d_in[0];
  const void*  maskp   = d_in[1];
  const void*  idmp    = d_in[2];
  const float* patch_w = (const float*)d_in[3];
  const float* patch_b = (const float*)d_in[4];
  const float* cls_tok = (const float*)d_in[5];
  const float* pos_emb = (const float*)d_in[6];
  const float* t_ng = (const float*)d_in[7];
  const float* t_nb = (const float*)d_in[8];
  const float* t_qkv = (const float*)d_in[9];
  const float* t_ow = (const float*)d_in[10];
  const float* t_ob = (const float*)d_in[11];
  const float* s_ng = (const float*)d_in[12];
  const float* s_nb = (const float*)d_in[13];
  const float* s_qkv = (const float*)d_in[14];
  const float* s_ow = (const float*)d_in[15];
  const float* s_ob = (const float*)d_in[16];
  const float* f_ng = (const float*)d_in[17];
  const float* f_nb = (const float*)d_in[18];
  const float* f_w1 = (const float*)d_in[19];
  const float* f_b1 = (const float*)d_in[20];
  const float* f_w2 = (const float*)d_in[21];
  const float* f_b2 = (const float*)d_in[22];
  const float* o_ng = (const float*)d_in[23];
  const float* o_nb = (const float*)d_in[24];
  const float* o_w  = (const float*)d_in[25];
  const float* o_b  = (const float*)d_in[26];
  float* out = (float*)d_out;

  // ---- workspace layout (~199 MB) ----
  const size_t szXT   = (size_t)ROWS * 1024 * 4;
  const size_t szXNA  = (size_t)MPADA * 1024 * 2;
  const size_t szBIG  = (size_t)MPAD * 4096 * 2;
  const size_t szWBUF = (size_t)8192 * 1024 * 2;
  size_t off = 0;
  auto take = [&](size_t b) { size_t o = off; off += (b + 255) & ~(size_t)255; return o; };
  char* base = (char*)d_ws;
  float* XT  = (float*)(base + take(szXT));
  u16*  XNA  = (u16*)(base + take(szXNA));
  char* BIG  = base + take(szBIG);
  u16*  WBUF = (u16*)(base + take(szWBUF));
  if (off > ws_size) return;                              // ws too small: fail clean

  u16*   QKV  = (u16*)BIG;
  u16*   HACT = (u16*)BIG;
  u16*   Xtr  = (u16*)BIG;
  float* TOK  = (float*)(BIG + (size_t)40 * 1024 * 1024);
  float* PART = (float*)(BIG + (size_t)MPAD * 3072 * 2);  // after QKV extent

  auto tr = [&](const float* s, u16* d, int R, int C) {
    dim3 gr((C + 31) / 32, (R + 31) / 32, 1);
    transpose_cvt<<<gr, 256, 0, stream>>>(s, d, R, C, 0, 0);
  };

  // ---- patch embedding ----
  {
    dim3 gr((196 + 31) / 32, (1280 + 31) / 32, 64);
    transpose_cvt<<<gr, 256, 0, stream>>>(x, Xtr, 1280, 196, 1280L * 196, 196L * 1280);
  }
  tr(patch_w, WBUF, 1280, 1024);
  gemm_bt<0><<<dim3(8, 98), 256, 0, stream>>>(Xtr, WBUF, patch_b, TOK, nullptr, NTOK, 1024, 1280);
  build_xt<<<ROWS, 256, 0, stream>>>(TOK, cls_tok, pos_emb, XT);

  for (int L = 0; L < 2; ++L) {
    // ---- time attention block ----
    tr(t_qkv + (size_t)L * 1024 * 3072, WBUF, 1024, 3072);
    ln_rows<<<ROWS, 256, 0, stream>>>(XT, t_ng + L * 1024, t_nb + L * 1024, XNA);
    gemm_bt<2><<<dim3(24, 99), 256, 0, stream>>>(XNA, WBUF, nullptr, nullptr, QKV, MPAD, 3072, 1024);
    tr(t_ow + (size_t)L * 1024 * 1024, WBUF, 1024, 1024);
    attn_cls_part<<<dim3(NCC, 64), 256, 0, stream>>>(QKV, PART, maskp);
    attn_cls_comb<<<64, 64, 0, stream>>>(PART, XNA);
    attn_time<<<NTOK, 256, 0, stream>>>(QKV, XNA, maskp, idmp);
    gemm_bt<1><<<dim3(8, 99), 256, 0, stream>>>(XNA, WBUF, t_ob + L * 1024, XT, nullptr, ROWS, 1024, 1024);
    // ---- space attention block ----
    tr(s_qkv + (size_t)L * 1024 * 3072, WBUF, 1024, 3072);
    ln_rows<<<ROWS, 256, 0, stream>>>(XT, s_ng + L * 1024, s_nb + L * 1024, XNA);
    gemm_bt<2><<<dim3(24, 99), 256, 0, stream>>>(XNA, WBUF, nullptr, nullptr, QKV, MPAD, 3072, 1024);
    tr(s_ow + (size_t)L * 1024 * 1024, WBUF, 1024, 1024);
    attn_cls_part<<<dim3(NCC, 64), 256, 0, stream>>>(QKV, PART, maskp);
    attn_cls_comb<<<64, 64, 0, stream>>>(PART, XNA);
    attn_space<<<1024, 256, 0, stream>>>(QKV, XNA);
    gemm_bt<1><<<dim3(8, 99), 256, 0, stream>>>(XNA, WBUF, s_ob + L * 1024, XT, nullptr, ROWS, 1024, 1024);
    // ---- FFN (gate fused into GEMM1 epilogue) ----
    transpose_w1<<<dim3(256, 32), 256, 0, stream>>>(f_w1 + (size_t)L * 1024 * 8192, WBUF);
    ln_rows<<<ROWS, 256, 0, stream>>>(XT, f_ng + L * 1024, f_nb + L * 1024, XNA);
    gemm_w1_fused<<<dim3(64, 99), 256, 0, stream>>>(XNA, WBUF, f_b1 + L * 8192, HACT, ROWS);
    tr(f_w2 + (size_t)L * 4096 * 1024, WBUF, 4096, 1024);
    gemm_bt<1><<<dim3(8, 99), 256, 0, stream>>>(HACT, WBUF, f_b2 + L * 1024, XT, nullptr, ROWS, 1024, 4096);
  }
  final_head<<<4, 256, 0, stream>>>(XT, o_ng, o_nb, o_w, o_b, out);
}

// Round 12
// 2079.693 us; speedup vs baseline: 1.1156x; 1.0175x over previous
//
#include <hip/hip_runtime.h>

// SizeInvariantTimeSformer forward on MI355X (gfx950).
// fp32 residual stream. All big GEMMs: 128x256 tile, 4 waves (n-striped, acc[8][4]),
// BK=32, 3-buffer ring with counted vmcnt(6) + one s_barrier per K-tile,
// 72KB LDS -> 2 blocks/CU, 2-bit k-group swizzle (conflict-free), T5 setprio.
// attn_space MFMA; attn_cls split-K flash.

typedef unsigned short u16;
typedef __bf16 bf16x8 __attribute__((ext_vector_type(8)));
typedef float f32x4 __attribute__((ext_vector_type(4)));
typedef u16 u16x8 __attribute__((ext_vector_type(8)));

#define SEQ   3137
#define ROWS  12548   // B * SEQ
#define MPAD  12672   // 99 * 128
#define MPADA 12800   // XNA row allocation (superset)
#define NTOK  12544   // B * F * 196
#define NCC   16      // cls split-K chunks
#define CHK   197     // ceil(SEQ/NCC)

__device__ __forceinline__ u16 f2b(float f) {
  union { float f; unsigned u; } v; v.f = f;
  unsigned r = v.u + 0x7FFFu + ((v.u >> 16) & 1u);   // RNE
  return (u16)(r >> 16);
}
__device__ __forceinline__ float b2f(u16 u) {
  union { unsigned u; float f; } v; v.u = ((unsigned)u) << 16;
  return v.f;
}
__device__ __forceinline__ float gelu_f(float g) {
  return 0.5f * g * (1.0f + erff(g * 0.70710678118654752f));
}
// bool inputs may arrive as uint8 bytes, int32 words, or float32 words.
__device__ __forceinline__ bool read_bool(const void* p, int idx) {
  const unsigned* w = (const unsigned*)p;
  unsigned w0 = w[0];
  if (w0 == 1u || w0 == 0u) return ((const int*)p)[idx] != 0;   // int32-encoded
  if (w0 == 0x3F800000u) return w[idx] != 0;                    // float32-encoded
  return ((const unsigned char*)p)[idx] != 0;                   // uint8-encoded
}

typedef const __attribute__((address_space(1))) void GVOID;
typedef __attribute__((address_space(3))) void LVOID;
__device__ __forceinline__ void gload_lds16(const void* g, void* l) {
  __builtin_amdgcn_global_load_lds((GVOID*)g, (LVOID*)l, 16, 0, 0);
}

// ---- 3-buffer BK=32 pipelined K-loop, 128(M)x256(N) tile, 4 waves ----
// LDS per buffer: A[128][32]bf16 (8KB) + B[256][32]bf16 (16KB) = 24KB; x3 = 72KB.
// Swizzle: logical (row,k16) stored at physical k16 ^ ((row>>1)&3) (involution).
// Ledger: 6 loads/thread/tile; at boundary t->t+1 outstanding = issue(t+1) = 6
// -> vmcnt(6) retires issue(t) exactly; never drains to 0 in the loop.
// Write-after-read: issue(t+2) after the iter-t barrier overwrites buf((t-1)%3),
// whose reads all landed in registers before each wave passed that barrier.
#define G128_LOOP(KVAL)                                                                  \
  const int K = (KVAL);                                                                  \
  const int NT = K >> 5;                                                                 \
  const int tid  = threadIdx.x;                                                          \
  const int lane = tid & 63, wid = tid >> 6;       /* wid = n-stripe 0..3 */             \
  const long arow0 = (long)blockIdx.y * 128;                                             \
  const long brow0 = (long)blockIdx.x * 256;                                             \
  const int  s_row = tid >> 2;                     /* 0..63 */                           \
  const int  s_swz = (((tid & 3) ^ ((tid >> 3) & 3)) << 4);                              \
  const char* Ag = (const char*)A + (arow0 + s_row) * (long)K * 2 + s_swz;               \
  const char* Bg = (const char*)Bt + (brow0 + s_row) * (long)K * 2 + s_swz;              \
  auto issue = [&](int t) {                                                              \
    char* d = smem + (t % 3) * 24576 + tid * 16;                                         \
    const long kb = (long)t * 64;                                                        \
    gload_lds16(Ag + kb,                     d);                                         \
    gload_lds16(Ag + kb + (long)64  * K * 2, d + 4096);                                  \
    gload_lds16(Bg + kb,                     d + 8192);                                  \
    gload_lds16(Bg + kb + (long)64  * K * 2, d + 12288);                                 \
    gload_lds16(Bg + kb + (long)128 * K * 2, d + 16384);                                 \
    gload_lds16(Bg + kb + (long)192 * K * 2, d + 20480);                                 \
  };                                                                                     \
  f32x4 acc[8][4] = {};                                                                  \
  const int frow  = lane & 15;                                                           \
  const int rd_kb = (lane >> 4) << 4;                                                    \
  const int rxor  = ((lane >> 1) & 3) << 4;                                              \
  issue(0); issue(1);                                                                    \
  for (int t = 0; t < NT; ++t) {                                                         \
    if (t + 1 < NT) asm volatile("s_waitcnt vmcnt(6)" ::: "memory");                     \
    else            asm volatile("s_waitcnt vmcnt(0)" ::: "memory");                     \
    __builtin_amdgcn_sched_barrier(0);                                                   \
    __builtin_amdgcn_s_barrier();                                                        \
    __builtin_amdgcn_sched_barrier(0);                                                   \
    const char* Ab = smem + (t % 3) * 24576;                                             \
    const char* Bb = Ab + 8192;                                                          \
    bf16x8 af[8], bfr[4];                                                                \
    _Pragma("unroll")                                                                    \
    for (int mi = 0; mi < 8; ++mi)                                                       \
      af[mi] = *(const bf16x8*)(Ab + (mi * 16 + frow) * 64 + (rd_kb ^ rxor));            \
    _Pragma("unroll")                                                                    \
    for (int ni = 0; ni < 4; ++ni)                                                       \
      bfr[ni] = *(const bf16x8*)(Bb + (wid * 64 + ni * 16 + frow) * 64 + (rd_kb ^ rxor));\
    __builtin_amdgcn_s_setprio(1);                                                       \
    _Pragma("unroll")                                                                    \
    for (int mi = 0; mi < 8; ++mi)                                                       \
      _Pragma("unroll")                                                                  \
      for (int ni = 0; ni < 4; ++ni)                                                     \
        acc[mi][ni] = __builtin_amdgcn_mfma_f32_16x16x32_bf16(af[mi], bfr[ni],           \
                                                              acc[mi][ni], 0, 0, 0);     \
    __builtin_amdgcn_s_setprio(0);                                                       \
    if (t + 2 < NT) issue(t + 2);                                                        \
  }

// ---------------- GEMM: C[M,N] = A[M,K](bf16) * Bt[N,K](bf16)^T (+bias) ----------------
// N must be a multiple of 256. MODE 0: Cf = acc+bias  1: Cf += acc+bias  2: Cb = bf16.
template<int MODE>
__global__ __launch_bounds__(256, 2) void gemm_bt(
    const u16* __restrict__ A, const u16* __restrict__ Bt,
    const float* __restrict__ bias,
    float* __restrict__ Cf, u16* __restrict__ Cb,
    int Mact, int N, int Kin)
{
  __shared__ char smem[73728];
  G128_LOOP(Kin)

  const int ccol0 = (int)brow0 + wid * 64 + frow;
  const int rsub  = (lane >> 4) * 4;
  float bv[4];
#pragma unroll
  for (int ni = 0; ni < 4; ++ni) bv[ni] = bias ? bias[ccol0 + ni * 16] : 0.0f;
#pragma unroll
  for (int mi = 0; mi < 8; ++mi) {
#pragma unroll
    for (int r = 0; r < 4; ++r) {
      long row = arow0 + mi * 16 + rsub + r;
      if (row < Mact) {
#pragma unroll
        for (int ni = 0; ni < 4; ++ni) {
          float v = acc[mi][ni][r] + bv[ni];
          long idx = row * (long)N + ccol0 + ni * 16;
          if (MODE == 0)      Cf[idx] = v;
          else if (MODE == 1) Cf[idx] += v;
          else                Cb[idx] = f2b(v);
        }
      }
    }
  }
}

// ---------------- FFN1 fused: H = XN @ PW1^T + b1 (permuted), HACT = a * gelu(g) --------
// Permuted chunks: np block q of 128 = [a(q*64..+63) | g(4096+q*64..+63)].
// Block covers chunks 2c,2c+1. Wave pair p=wid>>1; wid even = a-half, odd = g-half.
// g exchanged via dead staging LDS (gx stride 68 f32; 2 pairs x 128 x 68 x 4B = 69.6KB).
__global__ __launch_bounds__(256, 2) void gemm_w1_fused(
    const u16* __restrict__ A, const u16* __restrict__ Bt,
    const float* __restrict__ bias, u16* __restrict__ HACT, int Mact)
{
  __shared__ char smem[73728];
  G128_LOOP(1024)

  float* gx = (float*)smem;
  const int p     = wid >> 1;
  const int cbase = blockIdx.x * 128 + p * 64;    // HACT column base for this pair
  const int rsub  = (lane >> 4) * 4;
  float bv[4];
#pragma unroll
  for (int ni = 0; ni < 4; ++ni)
    bv[ni] = bias[((wid & 1) ? 4096 : 0) + cbase + ni * 16 + frow];

  __syncthreads();                   // all MFMA reads landed; staging LDS dead
  if (wid & 1) {                     // g-wave: write g+bias to LDS
#pragma unroll
    for (int mi = 0; mi < 8; ++mi)
#pragma unroll
      for (int r = 0; r < 4; ++r) {
        int rl = mi * 16 + rsub + r;
#pragma unroll
        for (int ni = 0; ni < 4; ++ni)
          gx[(p * 128 + rl) * 68 + ni * 16 + frow] = acc[mi][ni][r] + bv[ni];
      }
  }
  __syncthreads();
  if (!(wid & 1)) {                  // a-wave: fuse a*gelu(g), store
#pragma unroll
    for (int mi = 0; mi < 8; ++mi)
#pragma unroll
      for (int r = 0; r < 4; ++r) {
        int rl = mi * 16 + rsub + r;
        long row = arow0 + rl;
        if (row < Mact) {
#pragma unroll
          for (int ni = 0; ni < 4; ++ni) {
            float a = acc[mi][ni][r] + bv[ni];
            float g = gx[(p * 128 + rl) * 68 + ni * 16 + frow];
            HACT[row * 4096L + cbase + ni * 16 + frow] = f2b(a * gelu_f(g));
          }
        }
      }
  }
}

// ---------------- transpose + f32->bf16 convert ----------------
__global__ __launch_bounds__(256) void transpose_cvt(
    const float* __restrict__ src, u16* __restrict__ dst,
    int R, int C, long sstride, long dstride)
{
  src += (long)blockIdx.z * sstride;
  dst += (long)blockIdx.z * dstride;
  __shared__ float tile[32][33];
  const int r0 = blockIdx.y * 32, c0 = blockIdx.x * 32;
  const int tx = threadIdx.x & 31, ty = threadIdx.x >> 5;
#pragma unroll
  for (int i = 0; i < 32; i += 8) {
    int r = r0 + ty + i, c = c0 + tx;
    if (r < R && c < C) tile[ty + i][tx] = src[(long)r * C + c];
  }
  __syncthreads();
#pragma unroll
  for (int i = 0; i < 32; i += 8) {
    int c = c0 + ty + i, r = r0 + tx;
    if (c < C && r < R) dst[(long)c * R + r] = f2b(tile[tx][ty + i]);
  }
}

// ---------------- w1 permuted transpose ----------------
__global__ __launch_bounds__(256) void transpose_w1(
    const float* __restrict__ src, u16* __restrict__ dst)
{
  __shared__ float tile[32][33];
  const int r0 = blockIdx.y * 32, c0 = blockIdx.x * 32;
  const int tx = threadIdx.x & 31, ty = threadIdx.x >> 5;
#pragma unroll
  for (int i = 0; i < 32; i += 8)
    tile[ty + i][tx] = src[(long)(r0 + ty + i) * 8192 + c0 + tx];
  __syncthreads();
#pragma unroll
  for (int i = 0; i < 32; i += 8) {
    int n = c0 + ty + i;
    int np = (n < 4096) ? ((n >> 6) * 128 + (n & 63))
                        : (((n - 4096) >> 6) * 128 + 64 + ((n - 4096) & 63));
    dst[(long)np * 1024 + r0 + tx] = f2b(tile[tx][ty + i]);
  }
}

// ---------------- build XT = concat(cls, tokens) + pos ----------------
__global__ __launch_bounds__(256) void build_xt(
    const float* __restrict__ TOK, const float* __restrict__ cls,
    const float* __restrict__ pos, float* __restrict__ XT)
{
  const int row = blockIdx.x, tid = threadIdx.x;
  const int b = row / SEQ, s = row % SEQ;
  float4 p = ((const float4*)(pos + (long)s * 1024))[tid];
  float4 t;
  if (s == 0) t = ((const float4*)cls)[tid];
  else        t = ((const float4*)(TOK + ((long)b * 3136 + (s - 1)) * 1024))[tid];
  float4 r; r.x = t.x + p.x; r.y = t.y + p.y; r.z = t.z + p.z; r.w = t.w + p.w;
  ((float4*)(XT + (long)row * 1024))[tid] = r;
}

// ---------------- LayerNorm (f32 in) -> bf16 out ----------------
__global__ __launch_bounds__(256) void ln_rows(
    const float* __restrict__ X, const float* __restrict__ g,
    const float* __restrict__ b, u16* __restrict__ Y)
{
  const int row = blockIdx.x, tid = threadIdx.x;
  const int lane = tid & 63, wid = tid >> 6;
  float4 x = ((const float4*)(X + (long)row * 1024))[tid];
  float s = x.x + x.y + x.z + x.w;
  float q = x.x * x.x + x.y * x.y + x.z * x.z + x.w * x.w;
#pragma unroll
  for (int o = 32; o; o >>= 1) { s += __shfl_xor(s, o); q += __shfl_xor(q, o); }
  __shared__ float ls[4], lq[4];
  if (lane == 0) { ls[wid] = s; lq[wid] = q; }
  __syncthreads();
  s = ls[0] + ls[1] + ls[2] + ls[3];
  q = lq[0] + lq[1] + lq[2] + lq[3];
  const float mean = s * (1.0f / 1024.0f);
  const float rstd = rsqrtf(q * (1.0f / 1024.0f) - mean * mean + 1e-5f);
  float4 gg = ((const float4*)g)[tid];
  float4 bb = ((const float4*)b)[tid];
  ushort4 o4;
  o4.x = f2b((x.x - mean) * rstd * gg.x + bb.x);
  o4.y = f2b((x.y - mean) * rstd * gg.y + bb.y);
  o4.z = f2b((x.z - mean) * rstd * gg.z + bb.z);
  o4.w = f2b((x.w - mean) * rstd * gg.w + bb.w);
  ((ushort4*)(Y + (long)row * 1024))[tid] = o4;
}

// ---------------- cls attention, split-K partial ----------------
__global__ __launch_bounds__(256) void attn_cls_part(
    const u16* __restrict__ QKV, float* __restrict__ PART, const void* __restrict__ maskp)
{
  const int c = blockIdx.x, bh = blockIdx.y;
  const int b = bh >> 4, h = bh & 15;
  const long rowbase = (long)b * SEQ;
  const int tid = threadIdx.x, lane = tid & 63, w = tid >> 6;
  const int rs = lane >> 3, c8 = lane & 7;
  const int start = c * CHK;
  const int end = (start + CHK < SEQ) ? start + CHK : SEQ;

  float qf[8];
  {
    u16x8 qv = *(const u16x8*)(QKV + rowbase * 3072 + h * 64 + c8 * 8);
#pragma unroll
    for (int i = 0; i < 8; ++i) qf[i] = b2f(qv[i]) * 0.125f;
  }

  float m_run = -3.4e38f, s_run = 0.f;
  float acc[8] = {};

  for (int j8 = start + w * 8; j8 < end; j8 += 32) {
    int j = j8 + rs;
    bool valid = (j < end);
    int jc = valid ? j : (end - 1);
    const u16* kp = QKV + (rowbase + jc) * 3072 + 1024 + h * 64 + c8 * 8;
    u16x8 kv = *(const u16x8*)kp;
    u16x8 vv = *(const u16x8*)(kp + 1024);
    float sim = 0.f;
#pragma unroll
    for (int i = 0; i < 8; ++i) sim += b2f(kv[i]) * qf[i];
    sim += __shfl_xor(sim, 1); sim += __shfl_xor(sim, 2); sim += __shfl_xor(sim, 4);
    bool ok = valid && ((jc == 0) || read_bool(maskp, b * 16 + (jc - 1) / 196));
    float simv = ok ? sim : -3.4e38f;
    float mx = simv;
    mx = fmaxf(mx, __shfl_xor(mx, 8));
    mx = fmaxf(mx, __shfl_xor(mx, 16));
    mx = fmaxf(mx, __shfl_xor(mx, 32));
    float new_m = fmaxf(m_run, mx);
    float scale = __expf(m_run - new_m);
    float p = ok ? __expf(simv - new_m) : 0.f;
    m_run = new_m;
    s_run = s_run * scale + p;
#pragma unroll
    for (int i = 0; i < 8; ++i) acc[i] = acc[i] * scale + p * b2f(vv[i]);
  }
#pragma unroll
  for (int o = 8; o <= 32; o <<= 1) {
    s_run += __shfl_xor(s_run, o);
#pragma unroll
    for (int i = 0; i < 8; ++i) acc[i] += __shfl_xor(acc[i], o);
  }

  __shared__ float sm_m[4], sm_s[4], sm_a[4][64];
  if (lane == 0) { sm_m[w] = m_run; sm_s[w] = s_run; }
  if (rs == 0) {
#pragma unroll
    for (int i = 0; i < 8; ++i) sm_a[w][c8 * 8 + i] = acc[i];
  }
  __syncthreads();
  if (tid < 64) {
    float M = fmaxf(fmaxf(sm_m[0], sm_m[1]), fmaxf(sm_m[2], sm_m[3]));
    float S = 0.f, A = 0.f;
#pragma unroll
    for (int ww = 0; ww < 4; ++ww) {
      float e = __expf(sm_m[ww] - M);
      S += sm_s[ww] * e;
      A += sm_a[ww][tid] * e;
    }
    float* outp = PART + ((long)bh * NCC + c) * 72;
    outp[tid] = A;
    if (tid == 0) { outp[64] = M; outp[65] = S; }
  }
}

// ---------------- cls attention combine ----------------
__global__ __launch_bounds__(64) void attn_cls_comb(
    const float* __restrict__ PART, u16* __restrict__ ATT)
{
  const int bh = blockIdx.x, b = bh >> 4, h = bh & 15;
  const int d = threadIdx.x;
  float M = -3.4e38f;
#pragma unroll
  for (int c = 0; c < NCC; ++c) M = fmaxf(M, PART[((long)bh * NCC + c) * 72 + 64]);
  float S = 0.f, A = 0.f;
#pragma unroll
  for (int c = 0; c < NCC; ++c) {
    const float* p = PART + ((long)bh * NCC + c) * 72;
    float e = __expf(p[64] - M);
    S += p[65] * e;
    A += p[d] * e;
  }
  ATT[((long)b * SEQ) * 1024 + h * 64 + d] = f2b(A / S);
}

// ---------------- time attention: groups (b,h,n), 16 queries x 17 keys ----------------
__global__ __launch_bounds__(256) void attn_time(
    const u16* __restrict__ QKV, u16* __restrict__ ATT,
    const void* __restrict__ maskp, const void* __restrict__ idmp)
{
  const int g = blockIdx.x;
  const int n = g % 196;
  const int bh = g / 196;
  const int h = bh & 15, b = bh >> 4;
  const long rowbase = (long)b * SEQ;
  const int tid = threadIdx.x;
  __shared__ float q_s[16][65], k_s[17][65], v_s[17][65], p_s[16][18];
  for (int idx = tid; idx < 16 * 64; idx += 256) {
    int i = idx >> 6, d = idx & 63;
    q_s[i][d] = b2f(QKV[(rowbase + 1 + i * 196 + n) * 3072 + h * 64 + d]) * 0.125f;
  }
  for (int idx = tid; idx < 17 * 64; idx += 256) {
    int j = idx >> 6, d = idx & 63;
    long kr = (j == 0) ? rowbase : (rowbase + 1 + (long)(j - 1) * 196 + n);
    k_s[j][d] = b2f(QKV[kr * 3072 + 1024 + h * 64 + d]);
    v_s[j][d] = b2f(QKV[kr * 3072 + 2048 + h * 64 + d]);
  }
  __syncthreads();
#pragma unroll
  for (int pp = 0; pp < 2; ++pp) {
    int idx = tid + pp * 256;
    if (idx < 272) {
      int i = idx / 17, j = idx % 17;
      float s = 0.f;
      for (int d = 0; d < 64; ++d) s += q_s[i][d] * k_s[j][d];
      bool ok = (j == 0) ||
                (read_bool(maskp, b * 16 + (j - 1)) && read_bool(idmp, (b * 16 + i) * 16 + (j - 1)));
      p_s[i][j] = ok ? s : -3.4e38f;
    }
  }
  __syncthreads();
  if (tid < 16) {
    float m = -3.4e38f;
    for (int j = 0; j < 17; ++j) m = fmaxf(m, p_s[tid][j]);
    float su = 0.f;
    for (int j = 0; j < 17; ++j) { float e = __expf(p_s[tid][j] - m); p_s[tid][j] = e; su += e; }
    float inv = 1.0f / su;
    for (int j = 0; j < 17; ++j) p_s[tid][j] *= inv;
  }
  __syncthreads();
  for (int idx = tid; idx < 1024; idx += 256) {
    int i = idx >> 6, d = idx & 63;
    float o = 0.f;
#pragma unroll
    for (int j = 0; j < 17; ++j) o += p_s[i][j] * v_s[j][d];
    ATT[(rowbase + 1 + i * 196 + n) * 1024 + h * 64 + d] = f2b(o);
  }
}

// ---------------- space attention (MFMA): one block per (b,h,f) ----------------
__global__ __launch_bounds__(256) void attn_space(
    const u16* __restrict__ QKV, u16* __restrict__ ATT)
{
  const int g = blockIdx.x;             // bh*16 + f
  const int fr = g & 15, bh = g >> 4;
  const int h = bh & 15, b = bh >> 4;
  const long rowbase = (long)b * SEQ;
  const long qbase = rowbase + 1 + (long)fr * 196;
  const int tid = threadIdx.x, lane = tid & 63, wid = tid >> 6;

  __shared__ u16 Ks[208][72];
  __shared__ u16 Vt[64][232];
  __shared__ u16 Ps[4][16][232];

  for (int c = tid; c < 197 * 8; c += 256) {
    int row = c >> 3, k8 = c & 7;
    long kr = (row == 0) ? rowbase : (qbase + row - 1);
    *(u16x8*)&Ks[row][k8 * 8] = *(const u16x8*)(QKV + kr * 3072 + 1024 + h * 64 + k8 * 8);
  }
  for (int c = tid; c < 64 * 35; c += 256) {
    int d = c / 35, k = 197 + c % 35;
    Vt[d][k] = 0;
  }
  for (int c = tid; c < 4 * 16 * 24; c += 256) {
    int w = c / (16 * 24), rem = c % (16 * 24);
    Ps[w][rem / 24][208 + rem % 24] = 0;
  }
  for (int c = tid; c < 197 * 64; c += 256) {
    int k = c >> 6, d = c & 63;
    long vr = (k == 0) ? rowbase : (qbase + k - 1);
    Vt[d][k] = QKV[vr * 3072 + 2048 + h * 64 + d];
  }
  __syncthreads();

  const int cl = lane & 15, hi = lane >> 4;
  for (int mt = wid; mt < 13; mt += 4) {
    int qi0 = mt * 16 + cl;
    long qrow = qbase + (qi0 < 196 ? qi0 : 0);
    const u16* qp = QKV + qrow * 3072 + h * 64 + hi * 8;
    bf16x8 af0 = *(const bf16x8*)qp;
    bf16x8 af1 = *(const bf16x8*)(qp + 32);

    f32x4 acc[13];
#pragma unroll
    for (int nt = 0; nt < 13; ++nt) {
      acc[nt] = (f32x4){0.f, 0.f, 0.f, 0.f};
      bf16x8 b0 = *(const bf16x8*)&Ks[nt * 16 + cl][hi * 8];
      acc[nt] = __builtin_amdgcn_mfma_f32_16x16x32_bf16(af0, b0, acc[nt], 0, 0, 0);
      bf16x8 b1 = *(const bf16x8*)&Ks[nt * 16 + cl][32 + hi * 8];
      acc[nt] = __builtin_amdgcn_mfma_f32_16x16x32_bf16(af1, b1, acc[nt], 0, 0, 0);
    }
    float mx[4] = {-3.4e38f, -3.4e38f, -3.4e38f, -3.4e38f};
#pragma unroll
    for (int nt = 0; nt < 13; ++nt) {
      int col = nt * 16 + cl;
#pragma unroll
      for (int r = 0; r < 4; ++r) {
        float s = acc[nt][r] * 0.125f;
        if (col >= 197) s = -3.4e38f;
        acc[nt][r] = s;
        mx[r] = fmaxf(mx[r], s);
      }
    }
#pragma unroll
    for (int r = 0; r < 4; ++r) {
#pragma unroll
      for (int o = 8; o; o >>= 1) mx[r] = fmaxf(mx[r], __shfl_xor(mx[r], o));
    }
    float sum[4] = {0.f, 0.f, 0.f, 0.f};
#pragma unroll
    for (int nt = 0; nt < 13; ++nt) {
      int col = nt * 16 + cl;
#pragma unroll
      for (int r = 0; r < 4; ++r) {
        float p = __expf(acc[nt][r] - mx[r]);
        sum[r] += p;
        Ps[wid][hi * 4 + r][col] = f2b(p);
      }
    }
    float inv[4];
#pragma unroll
    for (int r = 0; r < 4; ++r) {
#pragma unroll
      for (int o = 8; o; o >>= 1) sum[r] += __shfl_xor(sum[r], o);
      inv[r] = 1.0f / sum[r];
    }
    f32x4 ov[4];
#pragma unroll
    for (int dt = 0; dt < 4; ++dt) ov[dt] = (f32x4){0.f, 0.f, 0.f, 0.f};
#pragma unroll
    for (int ks = 0; ks < 7; ++ks) {
      bf16x8 pa = *(const bf16x8*)&Ps[wid][cl][ks * 32 + hi * 8];
#pragma unroll
      for (int dt = 0; dt < 4; ++dt) {
        bf16x8 vb = *(const bf16x8*)&Vt[dt * 16 + cl][ks * 32 + hi * 8];
        ov[dt] = __builtin_amdgcn_mfma_f32_16x16x32_bf16(pa, vb, ov[dt], 0, 0, 0);
      }
    }
#pragma unroll
    for (int r = 0; r < 4; ++r) {
      int qi = mt * 16 + hi * 4 + r;
      if (qi < 196) {
        long orow = (qbase + qi) * 1024 + h * 64;
#pragma unroll
        for (int dt = 0; dt < 4; ++dt)
          ATT[orow + dt * 16 + cl] = f2b(ov[dt][r] * inv[r]);
      }
    }
  }
}

// ---------------- final head: LN(cls) @ o_w + o_b ----------------
__global__ __launch_bounds__(256) void final_head(
    const float* __restrict__ XT, const float* __restrict__ g,
    const float* __restrict__ b, const float* __restrict__ ow,
    const float* __restrict__ ob, float* __restrict__ out)
{
  const int bb = blockIdx.x, tid = threadIdx.x;
  const int lane = tid & 63, wid = tid >> 6;
  float4 x = ((const float4*)(XT + (long)bb * SEQ * 1024))[tid];
  float s = x.x + x.y + x.z + x.w;
  float q = x.x * x.x + x.y * x.y + x.z * x.z + x.w * x.w;
#pragma unroll
  for (int o = 32; o; o >>= 1) { s += __shfl_xor(s, o); q += __shfl_xor(q, o); }
  __shared__ float ls[4], lq[4], lt[4];
  if (lane == 0) { ls[wid] = s; lq[wid] = q; }
  __syncthreads();
  s = ls[0] + ls[1] + ls[2] + ls[3];
  q = lq[0] + lq[1] + lq[2] + lq[3];
  const float mean = s * (1.0f / 1024.0f);
  const float rstd = rsqrtf(q * (1.0f / 1024.0f) - mean * mean + 1e-5f);
  float4 gg = ((const float4*)g)[tid];
  float4 bv = ((const float4*)b)[tid];
  float4 wv = ((const float4*)ow)[tid];
  float t = ((x.x - mean) * rstd * gg.x + bv.x) * wv.x
          + ((x.y - mean) * rstd * gg.y + bv.y) * wv.y
          + ((x.z - mean) * rstd * gg.z + bv.z) * wv.z
          + ((x.w - mean) * rstd * gg.w + bv.w) * wv.w;
#pragma unroll
  for (int o = 32; o; o >>= 1) t += __shfl_xor(t, o);
  if (lane == 0) lt[wid] = t;
  __syncthreads();
  if (tid == 0) out[bb] = lt[0] + lt[1] + lt[2] + lt[3] + ob[0];
}

// ==========================================================================
extern "C" void kernel_launch(void* const* d_in, const int* in_sizes, int n_in,
                              void* d_out, int out_size, void* d_ws, size_t ws_size,
                              hipStream_t stream) {
  const float* x       = (const float*)d_in[0];
  const void*  maskp   = d_in[1];
  const void*  idmp    = d_in[2];
  const float* patch_w = (const float*)d_in[3];
  const float* patch_b = (const float*)d_in[4];
  const float* cls_tok = (const float*)d_in[5];
  const float* pos_emb = (const float*)d_in[6];
  const float* t_ng = (const float*)d_in[7];
  const float* t_nb = (const float*)d_in[8];
  const float* t_qkv = (const float*)d_in[9];
  const float* t_ow = (const float*)d_in[10];
  const float* t_ob = (const float*)d_in[11];
  const float* s_ng = (const float*)d_in[12];
  const float* s_nb = (const float*)d_in[13];
  const float* s_qkv = (const float*)d_in[14];
  const float* s_ow = (const float*)d_in[15];
  const float* s_ob = (const float*)d_in[16];
  const float* f_ng = (const float*)d_in[17];
  const float* f_nb = (const float*)d_in[18];
  const float* f_w1 = (const float*)d_in[19];
  const float* f_b1 = (const float*)d_in[20];
  const float* f_w2 = (const float*)d_in[21];
  const float* f_b2 = (const float*)d_in[22];
  const float* o_ng = (const float*)d_in[23];
  const float* o_nb = (const float*)d_in[24];
  const float* o_w  = (const float*)d_in[25];
  const float* o_b  = (const float*)d_in[26];
  float* out = (float*)d_out;

  // ---- workspace layout (~199 MB) ----
  const size_t szXT   = (size_t)ROWS * 1024 * 4;
  const size_t szXNA  = (size_t)MPADA * 1024 * 2;
  const size_t szBIG  = (size_t)MPAD * 4096 * 2;
  const size_t szWBUF = (size_t)8192 * 1024 * 2;
  size_t off = 0;
  auto take = [&](size_t b) { size_t o = off; off += (b + 255) & ~(size_t)255; return o; };
  char* base = (char*)d_ws;
  float* XT  = (float*)(base + take(szXT));
  u16*  XNA  = (u16*)(base + take(szXNA));
  char* BIG  = base + take(szBIG);
  u16*  WBUF = (u16*)(base + take(szWBUF));
  if (off > ws_size) return;                              // ws too small: fail clean

  u16*   QKV  = (u16*)BIG;
  u16*   HACT = (u16*)BIG;
  u16*   Xtr  = (u16*)BIG;
  float* TOK  = (float*)(BIG + (size_t)40 * 1024 * 1024);
  float* PART = (float*)(BIG + (size_t)MPAD * 3072 * 2);  // after QKV extent

  auto tr = [&](const float* s, u16* d, int R, int C) {
    dim3 gr((C + 31) / 32, (R + 31) / 32, 1);
    transpose_cvt<<<gr, 256, 0, stream>>>(s, d, R, C, 0, 0);
  };

  // ---- patch embedding ----
  {
    dim3 gr((196 + 31) / 32, (1280 + 31) / 32, 64);
    transpose_cvt<<<gr, 256, 0, stream>>>(x, Xtr, 1280, 196, 1280L * 196, 196L * 1280);
  }
  tr(patch_w, WBUF, 1280, 1024);
  gemm_bt<0><<<dim3(4, 98), 256, 0, stream>>>(Xtr, WBUF, patch_b, TOK, nullptr, NTOK, 1024, 1280);
  build_xt<<<ROWS, 256, 0, stream>>>(TOK, cls_tok, pos_emb, XT);

  for (int L = 0; L < 2; ++L) {
    // ---- time attention block ----
    tr(t_qkv + (size_t)L * 1024 * 3072, WBUF, 1024, 3072);
    ln_rows<<<ROWS, 256, 0, stream>>>(XT, t_ng + L * 1024, t_nb + L * 1024, XNA);
    gemm_bt<2><<<dim3(12, 99), 256, 0, stream>>>(XNA, WBUF, nullptr, nullptr, QKV, MPAD, 3072, 1024);
    tr(t_ow + (size_t)L * 1024 * 1024, WBUF, 1024, 1024);
    attn_cls_part<<<dim3(NCC, 64), 256, 0, stream>>>(QKV, PART, maskp);
    attn_cls_comb<<<64, 64, 0, stream>>>(PART, XNA);
    attn_time<<<NTOK, 256, 0, stream>>>(QKV, XNA, maskp, idmp);
    gemm_bt<1><<<dim3(4, 99), 256, 0, stream>>>(XNA, WBUF, t_ob + L * 1024, XT, nullptr, ROWS, 1024, 1024);
    // ---- space attention block ----
    tr(s_qkv + (size_t)L * 1024 * 3072, WBUF, 1024, 3072);
    ln_rows<<<ROWS, 256, 0, stream>>>(XT, s_ng + L * 1024, s_nb + L * 1024, XNA);
    gemm_bt<2><<<dim3(12, 99), 256, 0, stream>>>(XNA, WBUF, nullptr, nullptr, QKV, MPAD, 3072, 1024);
    tr(s_ow + (size_t)L * 1024 * 1024, WBUF, 1024, 1024);
    attn_cls_part<<<dim3(NCC, 64), 256, 0, stream>>>(QKV, PART, maskp);
    attn_cls_comb<<<64, 64, 0, stream>>>(PART, XNA);
    attn_space<<<1024, 256, 0, stream>>>(QKV, XNA);
    gemm_bt<1><<<dim3(4, 99), 256, 0, stream>>>(XNA, WBUF, s_ob + L * 1024, XT, nullptr, ROWS, 1024, 1024);
    // ---- FFN (gate fused into GEMM1 epilogue) ----
    transpose_w1<<<dim3(256, 32), 256, 0, stream>>>(f_w1 + (size_t)L * 1024 * 8192, WBUF);
    ln_rows<<<ROWS, 256, 0, stream>>>(XT, f_ng + L * 1024, f_nb + L * 1024, XNA);
    gemm_w1_fused<<<dim3(32, 99), 256, 0, stream>>>(XNA, WBUF, f_b1 + L * 8192, HACT, ROWS);
    tr(f_w2 + (size_t)L * 4096 * 1024, WBUF, 4096, 1024);
    gemm_bt<1><<<dim3(4, 99), 256, 0, stream>>>(HACT, WBUF, f_b2 + L * 1024, XT, nullptr, ROWS, 1024, 4096);
  }
  final_head<<<4, 256, 0, stream>>>(XT, o_ng, o_nb, o_w, o_b, out);
}

// Round 13
// 1984.426 us; speedup vs baseline: 1.1692x; 1.0480x over previous
//
#include <hip/hip_runtime.h>

// SizeInvariantTimeSformer forward on MI355X (gfx950).
// fp32 residual stream. GEMM routing by measurement:
//   - gemm_bt (QKV/out-proj/FFN2/patch): 128x256 tile, 4 waves, BK=32, 3-buf ring,
//     vmcnt(6), 72KB LDS (r12-proven best for these shapes).
//   - gemm_w1_fused: 128x128 tile, BK=32, 3-buf ring, vmcnt(4), 48KB LDS ->
//     3 blocks/CU (r11-proven 765 TF, best for w1).
// attn_space MFMA; attn_cls split-K flash.

typedef unsigned short u16;
typedef __bf16 bf16x8 __attribute__((ext_vector_type(8)));
typedef float f32x4 __attribute__((ext_vector_type(4)));
typedef u16 u16x8 __attribute__((ext_vector_type(8)));

#define SEQ   3137
#define ROWS  12548   // B * SEQ
#define MPAD  12672   // 99 * 128
#define MPADA 12800   // XNA row allocation (superset)
#define NTOK  12544   // B * F * 196
#define NCC   16      // cls split-K chunks
#define CHK   197     // ceil(SEQ/NCC)

__device__ __forceinline__ u16 f2b(float f) {
  union { float f; unsigned u; } v; v.f = f;
  unsigned r = v.u + 0x7FFFu + ((v.u >> 16) & 1u);   // RNE
  return (u16)(r >> 16);
}
__device__ __forceinline__ float b2f(u16 u) {
  union { unsigned u; float f; } v; v.u = ((unsigned)u) << 16;
  return v.f;
}
__device__ __forceinline__ float gelu_f(float g) {
  return 0.5f * g * (1.0f + erff(g * 0.70710678118654752f));
}
// bool inputs may arrive as uint8 bytes, int32 words, or float32 words.
__device__ __forceinline__ bool read_bool(const void* p, int idx) {
  const unsigned* w = (const unsigned*)p;
  unsigned w0 = w[0];
  if (w0 == 1u || w0 == 0u) return ((const int*)p)[idx] != 0;   // int32-encoded
  if (w0 == 0x3F800000u) return w[idx] != 0;                    // float32-encoded
  return ((const unsigned char*)p)[idx] != 0;                   // uint8-encoded
}

typedef const __attribute__((address_space(1))) void GVOID;
typedef __attribute__((address_space(3))) void LVOID;
__device__ __forceinline__ void gload_lds16(const void* g, void* l) {
  __builtin_amdgcn_global_load_lds((GVOID*)g, (LVOID*)l, 16, 0, 0);
}

// ---- WIDE: 3-buffer BK=32 loop, 128(M)x256(N) tile, 4 waves (r12) ----
#define GLOOP_WIDE(KVAL)                                                                 \
  const int K = (KVAL);                                                                  \
  const int NT = K >> 5;                                                                 \
  const int tid  = threadIdx.x;                                                          \
  const int lane = tid & 63, wid = tid >> 6;       /* wid = n-stripe 0..3 */             \
  const long arow0 = (long)blockIdx.y * 128;                                             \
  const long brow0 = (long)blockIdx.x * 256;                                             \
  const int  s_row = tid >> 2;                     /* 0..63 */                           \
  const int  s_swz = (((tid & 3) ^ ((tid >> 3) & 3)) << 4);                              \
  const char* Ag = (const char*)A + (arow0 + s_row) * (long)K * 2 + s_swz;               \
  const char* Bg = (const char*)Bt + (brow0 + s_row) * (long)K * 2 + s_swz;              \
  auto issue = [&](int t) {                                                              \
    char* d = smem + (t % 3) * 24576 + tid * 16;                                         \
    const long kb = (long)t * 64;                                                        \
    gload_lds16(Ag + kb,                     d);                                         \
    gload_lds16(Ag + kb + (long)64  * K * 2, d + 4096);                                  \
    gload_lds16(Bg + kb,                     d + 8192);                                  \
    gload_lds16(Bg + kb + (long)64  * K * 2, d + 12288);                                 \
    gload_lds16(Bg + kb + (long)128 * K * 2, d + 16384);                                 \
    gload_lds16(Bg + kb + (long)192 * K * 2, d + 20480);                                 \
  };                                                                                     \
  f32x4 acc[8][4] = {};                                                                  \
  const int frow  = lane & 15;                                                           \
  const int rd_kb = (lane >> 4) << 4;                                                    \
  const int rxor  = ((lane >> 1) & 3) << 4;                                              \
  issue(0); issue(1);                                                                    \
  for (int t = 0; t < NT; ++t) {                                                         \
    if (t + 1 < NT) asm volatile("s_waitcnt vmcnt(6)" ::: "memory");                     \
    else            asm volatile("s_waitcnt vmcnt(0)" ::: "memory");                     \
    __builtin_amdgcn_sched_barrier(0);                                                   \
    __builtin_amdgcn_s_barrier();                                                        \
    __builtin_amdgcn_sched_barrier(0);                                                   \
    const char* Ab = smem + (t % 3) * 24576;                                             \
    const char* Bb = Ab + 8192;                                                          \
    bf16x8 af[8], bfr[4];                                                                \
    _Pragma("unroll")                                                                    \
    for (int mi = 0; mi < 8; ++mi)                                                       \
      af[mi] = *(const bf16x8*)(Ab + (mi * 16 + frow) * 64 + (rd_kb ^ rxor));            \
    _Pragma("unroll")                                                                    \
    for (int ni = 0; ni < 4; ++ni)                                                       \
      bfr[ni] = *(const bf16x8*)(Bb + (wid * 64 + ni * 16 + frow) * 64 + (rd_kb ^ rxor));\
    __builtin_amdgcn_s_setprio(1);                                                       \
    _Pragma("unroll")                                                                    \
    for (int mi = 0; mi < 8; ++mi)                                                       \
      _Pragma("unroll")                                                                  \
      for (int ni = 0; ni < 4; ++ni)                                                     \
        acc[mi][ni] = __builtin_amdgcn_mfma_f32_16x16x32_bf16(af[mi], bfr[ni],           \
                                                              acc[mi][ni], 0, 0, 0);     \
    __builtin_amdgcn_s_setprio(0);                                                       \
    if (t + 2 < NT) issue(t + 2);                                                        \
  }

// ---- SQ: 3-buffer BK=32 loop, 128x128 tile, 4 waves 2x2 (r11, 765 TF) ----
#define GLOOP_SQ(KVAL)                                                                   \
  const int K = (KVAL);                                                                  \
  const int NT = K >> 5;                                                                 \
  const int tid  = threadIdx.x;                                                          \
  const int lane = tid & 63, wid = tid >> 6;                                             \
  const int wm = wid >> 1, wn = wid & 1;                                                 \
  const long arow0 = (long)blockIdx.y * 128;                                             \
  const long brow0 = (long)blockIdx.x * 128;                                             \
  const int  s_row = tid >> 2;                                                           \
  const int  s_swz = (((tid & 3) ^ ((tid >> 3) & 3)) << 4);                              \
  const char* Ag = (const char*)A + (arow0 + s_row) * (long)K * 2 + s_swz;               \
  const char* Bg = (const char*)Bt + (brow0 + s_row) * (long)K * 2 + s_swz;              \
  auto issue = [&](int t) {                                                              \
    char* d = smem + (t % 3) * 16384 + tid * 16;                                         \
    const long kb = (long)t * 64;                                                        \
    gload_lds16(Ag + kb,                    d);                                          \
    gload_lds16(Ag + kb + (long)64 * K * 2, d + 4096);                                   \
    gload_lds16(Bg + kb,                    d + 8192);                                   \
    gload_lds16(Bg + kb + (long)64 * K * 2, d + 12288);                                  \
  };                                                                                     \
  f32x4 acc[4][4] = {};                                                                  \
  const int rd_row_a = wm * 64 + (lane & 15);                                            \
  const int rd_row_b = wn * 64 + (lane & 15);                                            \
  const int rd_kb    = (lane >> 4) << 4;                                                 \
  const int rxor     = ((lane >> 1) & 3) << 4;                                           \
  issue(0); issue(1);                                                                    \
  for (int t = 0; t < NT; ++t) {                                                         \
    if (t + 1 < NT) asm volatile("s_waitcnt vmcnt(4)" ::: "memory");                     \
    else            asm volatile("s_waitcnt vmcnt(0)" ::: "memory");                     \
    __builtin_amdgcn_sched_barrier(0);                                                   \
    __builtin_amdgcn_s_barrier();                                                        \
    __builtin_amdgcn_sched_barrier(0);                                                   \
    const char* Ab = smem + (t % 3) * 16384;                                             \
    const char* Bb = Ab + 8192;                                                          \
    bf16x8 af[4], bfr[4];                                                                \
    _Pragma("unroll")                                                                    \
    for (int mi = 0; mi < 4; ++mi)                                                       \
      af[mi] = *(const bf16x8*)(Ab + (rd_row_a + mi * 16) * 64 + (rd_kb ^ rxor));        \
    _Pragma("unroll")                                                                    \
    for (int ni = 0; ni < 4; ++ni)                                                       \
      bfr[ni] = *(const bf16x8*)(Bb + (rd_row_b + ni * 16) * 64 + (rd_kb ^ rxor));       \
    __builtin_amdgcn_s_setprio(1);                                                       \
    _Pragma("unroll")                                                                    \
    for (int mi = 0; mi < 4; ++mi)                                                       \
      _Pragma("unroll")                                                                  \
      for (int ni = 0; ni < 4; ++ni)                                                     \
        acc[mi][ni] = __builtin_amdgcn_mfma_f32_16x16x32_bf16(af[mi], bfr[ni],           \
                                                              acc[mi][ni], 0, 0, 0);     \
    __builtin_amdgcn_s_setprio(0);                                                       \
    if (t + 2 < NT) issue(t + 2);                                                        \
  }

// ---------------- GEMM (wide): C[M,N] = A * Bt^T (+bias), N % 256 == 0 ----------------
// MODE 0: Cf = acc+bias   1: Cf += acc+bias   2: Cb = bf16(acc+bias)
template<int MODE>
__global__ __launch_bounds__(256, 2) void gemm_bt(
    const u16* __restrict__ A, const u16* __restrict__ Bt,
    const float* __restrict__ bias,
    float* __restrict__ Cf, u16* __restrict__ Cb,
    int Mact, int N, int Kin)
{
  __shared__ char smem[73728];
  GLOOP_WIDE(Kin)

  const int ccol0 = (int)brow0 + wid * 64 + frow;
  const int rsub  = (lane >> 4) * 4;
  float bv[4];
#pragma unroll
  for (int ni = 0; ni < 4; ++ni) bv[ni] = bias ? bias[ccol0 + ni * 16] : 0.0f;
#pragma unroll
  for (int mi = 0; mi < 8; ++mi) {
#pragma unroll
    for (int r = 0; r < 4; ++r) {
      long row = arow0 + mi * 16 + rsub + r;
      if (row < Mact) {
#pragma unroll
        for (int ni = 0; ni < 4; ++ni) {
          float v = acc[mi][ni][r] + bv[ni];
          long idx = row * (long)N + ccol0 + ni * 16;
          if (MODE == 0)      Cf[idx] = v;
          else if (MODE == 1) Cf[idx] += v;
          else                Cb[idx] = f2b(v);
        }
      }
    }
  }
}

// ---------------- FFN1 fused (sq, r11): H = XN @ PW1^T + b1, HACT = a * gelu(g) --------
// PW1 rows: block c (128 rows) = [a-cols c*64..+63 | g-cols 4096+c*64..+63].
// Waves wn=0 hold a, wn=1 hold g; g exchanged via LDS reuse (gx stride 68).
__global__ __launch_bounds__(256) void gemm_w1_fused(
    const u16* __restrict__ A, const u16* __restrict__ Bt,
    const float* __restrict__ bias, u16* __restrict__ HACT, int Mact)
{
  __shared__ char smem[49152];
  GLOOP_SQ(1024)

  float* gx = (float*)smem;          // reuse: 2*64*68*4 = 34.8KB <= 48KB
  const int colb  = lane & 15;
  const int rsub  = (lane >> 4) * 4;
  const int cbase = blockIdx.x * 64;
  float bv[4];
#pragma unroll
  for (int ni = 0; ni < 4; ++ni)
    bv[ni] = bias[(wn ? 4096 : 0) + cbase + ni * 16 + colb];

  __syncthreads();                   // staging LDS dead (vmcnt(0) at last tile)
  if (wn == 1) {
#pragma unroll
    for (int mi = 0; mi < 4; ++mi)
#pragma unroll
      for (int r = 0; r < 4; ++r) {
        int rl = mi * 16 + rsub + r;
#pragma unroll
        for (int ni = 0; ni < 4; ++ni)
          gx[(wm * 64 + rl) * 68 + ni * 16 + colb] = acc[mi][ni][r] + bv[ni];
      }
  }
  __syncthreads();
  if (wn == 0) {
#pragma unroll
    for (int mi = 0; mi < 4; ++mi)
#pragma unroll
      for (int r = 0; r < 4; ++r) {
        int rl = mi * 16 + rsub + r;
        long row = arow0 + wm * 64 + rl;
        if (row < Mact) {
#pragma unroll
          for (int ni = 0; ni < 4; ++ni) {
            float a = acc[mi][ni][r] + bv[ni];
            float g = gx[(wm * 64 + rl) * 68 + ni * 16 + colb];
            HACT[row * 4096L + cbase + ni * 16 + colb] = f2b(a * gelu_f(g));
          }
        }
      }
  }
}

// ---------------- transpose + f32->bf16 convert ----------------
__global__ __launch_bounds__(256) void transpose_cvt(
    const float* __restrict__ src, u16* __restrict__ dst,
    int R, int C, long sstride, long dstride)
{
  src += (long)blockIdx.z * sstride;
  dst += (long)blockIdx.z * dstride;
  __shared__ float tile[32][33];
  const int r0 = blockIdx.y * 32, c0 = blockIdx.x * 32;
  const int tx = threadIdx.x & 31, ty = threadIdx.x >> 5;
#pragma unroll
  for (int i = 0; i < 32; i += 8) {
    int r = r0 + ty + i, c = c0 + tx;
    if (r < R && c < C) tile[ty + i][tx] = src[(long)r * C + c];
  }
  __syncthreads();
#pragma unroll
  for (int i = 0; i < 32; i += 8) {
    int c = c0 + ty + i, r = r0 + tx;
    if (c < C && r < R) dst[(long)c * R + r] = f2b(tile[tx][ty + i]);
  }
}

// ---------------- w1 permuted transpose ----------------
__global__ __launch_bounds__(256) void transpose_w1(
    const float* __restrict__ src, u16* __restrict__ dst)
{
  __shared__ float tile[32][33];
  const int r0 = blockIdx.y * 32, c0 = blockIdx.x * 32;
  const int tx = threadIdx.x & 31, ty = threadIdx.x >> 5;
#pragma unroll
  for (int i = 0; i < 32; i += 8)
    tile[ty + i][tx] = src[(long)(r0 + ty + i) * 8192 + c0 + tx];
  __syncthreads();
#pragma unroll
  for (int i = 0; i < 32; i += 8) {
    int n = c0 + ty + i;
    int np = (n < 4096) ? ((n >> 6) * 128 + (n & 63))
                        : (((n - 4096) >> 6) * 128 + 64 + ((n - 4096) & 63));
    dst[(long)np * 1024 + r0 + tx] = f2b(tile[tx][ty + i]);
  }
}

// ---------------- build XT = concat(cls, tokens) + pos ----------------
__global__ __launch_bounds__(256) void build_xt(
    const float* __restrict__ TOK, const float* __restrict__ cls,
    const float* __restrict__ pos, float* __restrict__ XT)
{
  const int row = blockIdx.x, tid = threadIdx.x;
  const int b = row / SEQ, s = row % SEQ;
  float4 p = ((const float4*)(pos + (long)s * 1024))[tid];
  float4 t;
  if (s == 0) t = ((const float4*)cls)[tid];
  else        t = ((const float4*)(TOK + ((long)b * 3136 + (s - 1)) * 1024))[tid];
  float4 r; r.x = t.x + p.x; r.y = t.y + p.y; r.z = t.z + p.z; r.w = t.w + p.w;
  ((float4*)(XT + (long)row * 1024))[tid] = r;
}

// ---------------- LayerNorm (f32 in) -> bf16 out ----------------
__global__ __launch_bounds__(256) void ln_rows(
    const float* __restrict__ X, const float* __restrict__ g,
    const float* __restrict__ b, u16* __restrict__ Y)
{
  const int row = blockIdx.x, tid = threadIdx.x;
  const int lane = tid & 63, wid = tid >> 6;
  float4 x = ((const float4*)(X + (long)row * 1024))[tid];
  float s = x.x + x.y + x.z + x.w;
  float q = x.x * x.x + x.y * x.y + x.z * x.z + x.w * x.w;
#pragma unroll
  for (int o = 32; o; o >>= 1) { s += __shfl_xor(s, o); q += __shfl_xor(q, o); }
  __shared__ float ls[4], lq[4];
  if (lane == 0) { ls[wid] = s; lq[wid] = q; }
  __syncthreads();
  s = ls[0] + ls[1] + ls[2] + ls[3];
  q = lq[0] + lq[1] + lq[2] + lq[3];
  const float mean = s * (1.0f / 1024.0f);
  const float rstd = rsqrtf(q * (1.0f / 1024.0f) - mean * mean + 1e-5f);
  float4 gg = ((const float4*)g)[tid];
  float4 bb = ((const float4*)b)[tid];
  ushort4 o4;
  o4.x = f2b((x.x - mean) * rstd * gg.x + bb.x);
  o4.y = f2b((x.y - mean) * rstd * gg.y + bb.y);
  o4.z = f2b((x.z - mean) * rstd * gg.z + bb.z);
  o4.w = f2b((x.w - mean) * rstd * gg.w + bb.w);
  ((ushort4*)(Y + (long)row * 1024))[tid] = o4;
}

// ---------------- cls attention, split-K partial ----------------
__global__ __launch_bounds__(256) void attn_cls_part(
    const u16* __restrict__ QKV, float* __restrict__ PART, const void* __restrict__ maskp)
{
  const int c = blockIdx.x, bh = blockIdx.y;
  const int b = bh >> 4, h = bh & 15;
  const long rowbase = (long)b * SEQ;
  const int tid = threadIdx.x, lane = tid & 63, w = tid >> 6;
  const int rs = lane >> 3, c8 = lane & 7;
  const int start = c * CHK;
  const int end = (start + CHK < SEQ) ? start + CHK : SEQ;

  float qf[8];
  {
    u16x8 qv = *(const u16x8*)(QKV + rowbase * 3072 + h * 64 + c8 * 8);
#pragma unroll
    for (int i = 0; i < 8; ++i) qf[i] = b2f(qv[i]) * 0.125f;
  }

  float m_run = -3.4e38f, s_run = 0.f;
  float acc[8] = {};

  for (int j8 = start + w * 8; j8 < end; j8 += 32) {
    int j = j8 + rs;
    bool valid = (j < end);
    int jc = valid ? j : (end - 1);
    const u16* kp = QKV + (rowbase + jc) * 3072 + 1024 + h * 64 + c8 * 8;
    u16x8 kv = *(const u16x8*)kp;
    u16x8 vv = *(const u16x8*)(kp + 1024);
    float sim = 0.f;
#pragma unroll
    for (int i = 0; i < 8; ++i) sim += b2f(kv[i]) * qf[i];
    sim += __shfl_xor(sim, 1); sim += __shfl_xor(sim, 2); sim += __shfl_xor(sim, 4);
    bool ok = valid && ((jc == 0) || read_bool(maskp, b * 16 + (jc - 1) / 196));
    float simv = ok ? sim : -3.4e38f;
    float mx = simv;
    mx = fmaxf(mx, __shfl_xor(mx, 8));
    mx = fmaxf(mx, __shfl_xor(mx, 16));
    mx = fmaxf(mx, __shfl_xor(mx, 32));
    float new_m = fmaxf(m_run, mx);
    float scale = __expf(m_run - new_m);
    float p = ok ? __expf(simv - new_m) : 0.f;
    m_run = new_m;
    s_run = s_run * scale + p;
#pragma unroll
    for (int i = 0; i < 8; ++i) acc[i] = acc[i] * scale + p * b2f(vv[i]);
  }
#pragma unroll
  for (int o = 8; o <= 32; o <<= 1) {
    s_run += __shfl_xor(s_run, o);
#pragma unroll
    for (int i = 0; i < 8; ++i) acc[i] += __shfl_xor(acc[i], o);
  }

  __shared__ float sm_m[4], sm_s[4], sm_a[4][64];
  if (lane == 0) { sm_m[w] = m_run; sm_s[w] = s_run; }
  if (rs == 0) {
#pragma unroll
    for (int i = 0; i < 8; ++i) sm_a[w][c8 * 8 + i] = acc[i];
  }
  __syncthreads();
  if (tid < 64) {
    float M = fmaxf(fmaxf(sm_m[0], sm_m[1]), fmaxf(sm_m[2], sm_m[3]));
    float S = 0.f, A = 0.f;
#pragma unroll
    for (int ww = 0; ww < 4; ++ww) {
      float e = __expf(sm_m[ww] - M);
      S += sm_s[ww] * e;
      A += sm_a[ww][tid] * e;
    }
    float* outp = PART + ((long)bh * NCC + c) * 72;
    outp[tid] = A;
    if (tid == 0) { outp[64] = M; outp[65] = S; }
  }
}

// ---------------- cls attention combine ----------------
__global__ __launch_bounds__(64) void attn_cls_comb(
    const float* __restrict__ PART, u16* __restrict__ ATT)
{
  const int bh = blockIdx.x, b = bh >> 4, h = bh & 15;
  const int d = threadIdx.x;
  float M = -3.4e38f;
#pragma unroll
  for (int c = 0; c < NCC; ++c) M = fmaxf(M, PART[((long)bh * NCC + c) * 72 + 64]);
  float S = 0.f, A = 0.f;
#pragma unroll
  for (int c = 0; c < NCC; ++c) {
    const float* p = PART + ((long)bh * NCC + c) * 72;
    float e = __expf(p[64] - M);
    S += p[65] * e;
    A += p[d] * e;
  }
  ATT[((long)b * SEQ) * 1024 + h * 64 + d] = f2b(A / S);
}

// ---------------- time attention: groups (b,h,n), 16 queries x 17 keys ----------------
__global__ __launch_bounds__(256) void attn_time(
    const u16* __restrict__ QKV, u16* __restrict__ ATT,
    const void* __restrict__ maskp, const void* __restrict__ idmp)
{
  const int g = blockIdx.x;
  const int n = g % 196;
  const int bh = g / 196;
  const int h = bh & 15, b = bh >> 4;
  const long rowbase = (long)b * SEQ;
  const int tid = threadIdx.x;
  __shared__ float q_s[16][65], k_s[17][65], v_s[17][65], p_s[16][18];
  for (int idx = tid; idx < 16 * 64; idx += 256) {
    int i = idx >> 6, d = idx & 63;
    q_s[i][d] = b2f(QKV[(rowbase + 1 + i * 196 + n) * 3072 + h * 64 + d]) * 0.125f;
  }
  for (int idx = tid; idx < 17 * 64; idx += 256) {
    int j = idx >> 6, d = idx & 63;
    long kr = (j == 0) ? rowbase : (rowbase + 1 + (long)(j - 1) * 196 + n);
    k_s[j][d] = b2f(QKV[kr * 3072 + 1024 + h * 64 + d]);
    v_s[j][d] = b2f(QKV[kr * 3072 + 2048 + h * 64 + d]);
  }
  __syncthreads();
#pragma unroll
  for (int pp = 0; pp < 2; ++pp) {
    int idx = tid + pp * 256;
    if (idx < 272) {
      int i = idx / 17, j = idx % 17;
      float s = 0.f;
      for (int d = 0; d < 64; ++d) s += q_s[i][d] * k_s[j][d];
      bool ok = (j == 0) ||
                (read_bool(maskp, b * 16 + (j - 1)) && read_bool(idmp, (b * 16 + i) * 16 + (j - 1)));
      p_s[i][j] = ok ? s : -3.4e38f;
    }
  }
  __syncthreads();
  if (tid < 16) {
    float m = -3.4e38f;
    for (int j = 0; j < 17; ++j) m = fmaxf(m, p_s[tid][j]);
    float su = 0.f;
    for (int j = 0; j < 17; ++j) { float e = __expf(p_s[tid][j] - m); p_s[tid][j] = e; su += e; }
    float inv = 1.0f / su;
    for (int j = 0; j < 17; ++j) p_s[tid][j] *= inv;
  }
  __syncthreads();
  for (int idx = tid; idx < 1024; idx += 256) {
    int i = idx >> 6, d = idx & 63;
    float o = 0.f;
#pragma unroll
    for (int j = 0; j < 17; ++j) o += p_s[i][j] * v_s[j][d];
    ATT[(rowbase + 1 + i * 196 + n) * 1024 + h * 64 + d] = f2b(o);
  }
}

// ---------------- space attention (MFMA): one block per (b,h,f) ----------------
__global__ __launch_bounds__(256) void attn_space(
    const u16* __restrict__ QKV, u16* __restrict__ ATT)
{
  const int g = blockIdx.x;             // bh*16 + f
  const int fr = g & 15, bh = g >> 4;
  const int h = bh & 15, b = bh >> 4;
  const long rowbase = (long)b * SEQ;
  const long qbase = rowbase + 1 + (long)fr * 196;
  const int tid = threadIdx.x, lane = tid & 63, wid = tid >> 6;

  __shared__ u16 Ks[208][72];
  __shared__ u16 Vt[64][232];
  __shared__ u16 Ps[4][16][232];

  for (int c = tid; c < 197 * 8; c += 256) {
    int row = c >> 3, k8 = c & 7;
    long kr = (row == 0) ? rowbase : (qbase + row - 1);
    *(u16x8*)&Ks[row][k8 * 8] = *(const u16x8*)(QKV + kr * 3072 + 1024 + h * 64 + k8 * 8);
  }
  for (int c = tid; c < 64 * 35; c += 256) {
    int d = c / 35, k = 197 + c % 35;
    Vt[d][k] = 0;
  }
  for (int c = tid; c < 4 * 16 * 24; c += 256) {
    int w = c / (16 * 24), rem = c % (16 * 24);
    Ps[w][rem / 24][208 + rem % 24] = 0;
  }
  for (int c = tid; c < 197 * 64; c += 256) {
    int k = c >> 6, d = c & 63;
    long vr = (k == 0) ? rowbase : (qbase + k - 1);
    Vt[d][k] = QKV[vr * 3072 + 2048 + h * 64 + d];
  }
  __syncthreads();

  const int cl = lane & 15, hi = lane >> 4;
  for (int mt = wid; mt < 13; mt += 4) {
    int qi0 = mt * 16 + cl;
    long qrow = qbase + (qi0 < 196 ? qi0 : 0);
    const u16* qp = QKV + qrow * 3072 + h * 64 + hi * 8;
    bf16x8 af0 = *(const bf16x8*)qp;
    bf16x8 af1 = *(const bf16x8*)(qp + 32);

    f32x4 acc[13];
#pragma unroll
    for (int nt = 0; nt < 13; ++nt) {
      acc[nt] = (f32x4){0.f, 0.f, 0.f, 0.f};
      bf16x8 b0 = *(const bf16x8*)&Ks[nt * 16 + cl][hi * 8];
      acc[nt] = __builtin_amdgcn_mfma_f32_16x16x32_bf16(af0, b0, acc[nt], 0, 0, 0);
      bf16x8 b1 = *(const bf16x8*)&Ks[nt * 16 + cl][32 + hi * 8];
      acc[nt] = __builtin_amdgcn_mfma_f32_16x16x32_bf16(af1, b1, acc[nt], 0, 0, 0);
    }
    float mx[4] = {-3.4e38f, -3.4e38f, -3.4e38f, -3.4e38f};
#pragma unroll
    for (int nt = 0; nt < 13; ++nt) {
      int col = nt * 16 + cl;
#pragma unroll
      for (int r = 0; r < 4; ++r) {
        float s = acc[nt][r] * 0.125f;
        if (col >= 197) s = -3.4e38f;
        acc[nt][r] = s;
        mx[r] = fmaxf(mx[r], s);
      }
    }
#pragma unroll
    for (int r = 0; r < 4; ++r) {
#pragma unroll
      for (int o = 8; o; o >>= 1) mx[r] = fmaxf(mx[r], __shfl_xor(mx[r], o));
    }
    float sum[4] = {0.f, 0.f, 0.f, 0.f};
#pragma unroll
    for (int nt = 0; nt < 13; ++nt) {
      int col = nt * 16 + cl;
#pragma unroll
      for (int r = 0; r < 4; ++r) {
        float p = __expf(acc[nt][r] - mx[r]);
        sum[r] += p;
        Ps[wid][hi * 4 + r][col] = f2b(p);
      }
    }
    float inv[4];
#pragma unroll
    for (int r = 0; r < 4; ++r) {
#pragma unroll
      for (int o = 8; o; o >>= 1) sum[r] += __shfl_xor(sum[r], o);
      inv[r] = 1.0f / sum[r];
    }
    f32x4 ov[4];
#pragma unroll
    for (int dt = 0; dt < 4; ++dt) ov[dt] = (f32x4){0.f, 0.f, 0.f, 0.f};
#pragma unroll
    for (int ks = 0; ks < 7; ++ks) {
      bf16x8 pa = *(const bf16x8*)&Ps[wid][cl][ks * 32 + hi * 8];
#pragma unroll
      for (int dt = 0; dt < 4; ++dt) {
        bf16x8 vb = *(const bf16x8*)&Vt[dt * 16 + cl][ks * 32 + hi * 8];
        ov[dt] = __builtin_amdgcn_mfma_f32_16x16x32_bf16(pa, vb, ov[dt], 0, 0, 0);
      }
    }
#pragma unroll
    for (int r = 0; r < 4; ++r) {
      int qi = mt * 16 + hi * 4 + r;
      if (qi < 196) {
        long orow = (qbase + qi) * 1024 + h * 64;
#pragma unroll
        for (int dt = 0; dt < 4; ++dt)
          ATT[orow + dt * 16 + cl] = f2b(ov[dt][r] * inv[r]);
      }
    }
  }
}

// ---------------- final head: LN(cls) @ o_w + o_b ----------------
__global__ __launch_bounds__(256) void final_head(
    const float* __restrict__ XT, const float* __restrict__ g,
    const float* __restrict__ b, const float* __restrict__ ow,
    const float* __restrict__ ob, float* __restrict__ out)
{
  const int bb = blockIdx.x, tid = threadIdx.x;
  const int lane = tid & 63, wid = tid >> 6;
  float4 x = ((const float4*)(XT + (long)bb * SEQ * 1024))[tid];
  float s = x.x + x.y + x.z + x.w;
  float q = x.x * x.x + x.y * x.y + x.z * x.z + x.w * x.w;
#pragma unroll
  for (int o = 32; o; o >>= 1) { s += __shfl_xor(s, o); q += __shfl_xor(q, o); }
  __shared__ float ls[4], lq[4], lt[4];
  if (lane == 0) { ls[wid] = s; lq[wid] = q; }
  __syncthreads();
  s = ls[0] + ls[1] + ls[2] + ls[3];
  q = lq[0] + lq[1] + lq[2] + lq[3];
  const float mean = s * (1.0f / 1024.0f);
  const float rstd = rsqrtf(q * (1.0f / 1024.0f) - mean * mean + 1e-5f);
  float4 gg = ((const float4*)g)[tid];
  float4 bv = ((const float4*)b)[tid];
  float4 wv = ((const float4*)ow)[tid];
  float t = ((x.x - mean) * rstd * gg.x + bv.x) * wv.x
          + ((x.y - mean) * rstd * gg.y + bv.y) * wv.y
          + ((x.z - mean) * rstd * gg.z + bv.z) * wv.z
          + ((x.w - mean) * rstd * gg.w + bv.w) * wv.w;
#pragma unroll
  for (int o = 32; o; o >>= 1) t += __shfl_xor(t, o);
  if (lane == 0) lt[wid] = t;
  __syncthreads();
  if (tid == 0) out[bb] = lt[0] + lt[1] + lt[2] + lt[3] + ob[0];
}

// ==========================================================================
extern "C" void kernel_launch(void* const* d_in, const int* in_sizes, int n_in,
                              void* d_out, int out_size, void* d_ws, size_t ws_size,
                              hipStream_t stream) {
  const float* x       = (const float*)d_in[0];
  const void*  maskp   = d_in[1];
  const void*  idmp    = d_in[2];
  const float* patch_w = (const float*)d_in[3];
  const float* patch_b = (const float*)d_in[4];
  const float* cls_tok = (const float*)d_in[5];
  const float* pos_emb = (const float*)d_in[6];
  const float* t_ng = (const float*)d_in[7];
  const float* t_nb = (const float*)d_in[8];
  const float* t_qkv = (const float*)d_in[9];
  const float* t_ow = (const float*)d_in[10];
  const float* t_ob = (const float*)d_in[11];
  const float* s_ng = (const float*)d_in[12];
  const float* s_nb = (const float*)d_in[13];
  const float* s_qkv = (const float*)d_in[14];
  const float* s_ow = (const float*)d_in[15];
  const float* s_ob = (const float*)d_in[16];
  const float* f_ng = (const float*)d_in[17];
  const float* f_nb = (const float*)d_in[18];
  const float* f_w1 = (const float*)d_in[19];
  const float* f_b1 = (const float*)d_in[20];
  const float* f_w2 = (const float*)d_in[21];
  const float* f_b2 = (const float*)d_in[22];
  const float* o_ng = (const float*)d_in[23];
  const float* o_nb = (const float*)d_in[24];
  const float* o_w  = (const float*)d_in[25];
  const float* o_b  = (const float*)d_in[26];
  float* out = (float*)d_out;

  // ---- workspace layout (~199 MB) ----
  const size_t szXT   = (size_t)ROWS * 1024 * 4;
  const size_t szXNA  = (size_t)MPADA * 1024 * 2;
  const size_t szBIG  = (size_t)MPAD * 4096 * 2;
  const size_t szWBUF = (size_t)8192 * 1024 * 2;
  size_t off = 0;
  auto take = [&](size_t b) { size_t o = off; off += (b + 255) & ~(size_t)255; return o; };
  char* base = (char*)d_ws;
  float* XT  = (float*)(base + take(szXT));
  u16*  XNA  = (u16*)(base + take(szXNA));
  char* BIG  = base + take(szBIG);
  u16*  WBUF = (u16*)(base + take(szWBUF));
  if (off > ws_size) return;                              // ws too small: fail clean

  u16*   QKV  = (u16*)BIG;
  u16*   HACT = (u16*)BIG;
  u16*   Xtr  = (u16*)BIG;
  float* TOK  = (float*)(BIG + (size_t)40 * 1024 * 1024);
  float* PART = (float*)(BIG + (size_t)MPAD * 3072 * 2);  // after QKV extent

  auto tr = [&](const float* s, u16* d, int R, int C) {
    dim3 gr((C + 31) / 32, (R + 31) / 32, 1);
    transpose_cvt<<<gr, 256, 0, stream>>>(s, d, R, C, 0, 0);
  };

  // ---- patch embedding ----
  {
    dim3 gr((196 + 31) / 32, (1280 + 31) / 32, 64);
    transpose_cvt<<<gr, 256, 0, stream>>>(x, Xtr, 1280, 196, 1280L * 196, 196L * 1280);
  }
  tr(patch_w, WBUF, 1280, 1024);
  gemm_bt<0><<<dim3(4, 98), 256, 0, stream>>>(Xtr, WBUF, patch_b, TOK, nullptr, NTOK, 1024, 1280);
  build_xt<<<ROWS, 256, 0, stream>>>(TOK, cls_tok, pos_emb, XT);

  for (int L = 0; L < 2; ++L) {
    // ---- time attention block ----
    tr(t_qkv + (size_t)L * 1024 * 3072, WBUF, 1024, 3072);
    ln_rows<<<ROWS, 256, 0, stream>>>(XT, t_ng + L * 1024, t_nb + L * 1024, XNA);
    gemm_bt<2><<<dim3(12, 99), 256, 0, stream>>>(XNA, WBUF, nullptr, nullptr, QKV, MPAD, 3072, 1024);
    tr(t_ow + (size_t)L * 1024 * 1024, WBUF, 1024, 1024);
    attn_cls_part<<<dim3(NCC, 64), 256, 0, stream>>>(QKV, PART, maskp);
    attn_cls_comb<<<64, 64, 0, stream>>>(PART, XNA);
    attn_time<<<NTOK, 256, 0, stream>>>(QKV, XNA, maskp, idmp);
    gemm_bt<1><<<dim3(4, 99), 256, 0, stream>>>(XNA, WBUF, t_ob + L * 1024, XT, nullptr, ROWS, 1024, 1024);
    // ---- space attention block ----
    tr(s_qkv + (size_t)L * 1024 * 3072, WBUF, 1024, 3072);
    ln_rows<<<ROWS, 256, 0, stream>>>(XT, s_ng + L * 1024, s_nb + L * 1024, XNA);
    gemm_bt<2><<<dim3(12, 99), 256, 0, stream>>>(XNA, WBUF, nullptr, nullptr, QKV, MPAD, 3072, 1024);
    tr(s_ow + (size_t)L * 1024 * 1024, WBUF, 1024, 1024);
    attn_cls_part<<<dim3(NCC, 64), 256, 0, stream>>>(QKV, PART, maskp);
    attn_cls_comb<<<64, 64, 0, stream>>>(PART, XNA);
    attn_space<<<1024, 256, 0, stream>>>(QKV, XNA);
    gemm_bt<1><<<dim3(4, 99), 256, 0, stream>>>(XNA, WBUF, s_ob + L * 1024, XT, nullptr, ROWS, 1024, 1024);
    // ---- FFN (gate fused into GEMM1 epilogue; r11 sq kernel) ----
    transpose_w1<<<dim3(256, 32), 256, 0, stream>>>(f_w1 + (size_t)L * 1024 * 8192, WBUF);
    ln_rows<<<ROWS, 256, 0, stream>>>(XT, f_ng + L * 1024, f_nb + L * 1024, XNA);
    gemm_w1_fused<<<dim3(64, 99), 256, 0, stream>>>(XNA, WBUF, f_b1 + L * 8192, HACT, ROWS);
    tr(f_w2 + (size_t)L * 4096 * 1024, WBUF, 4096, 1024);
    gemm_bt<1><<<dim3(4, 99), 256, 0, stream>>>(HACT, WBUF, f_b2 + L * 1024, XT, nullptr, ROWS, 1024, 4096);
  }
  final_head<<<4, 256, 0, stream>>>(XT, o_ng, o_nb, o_w, o_b, out);
}

// Round 14
// 1970.773 us; speedup vs baseline: 1.1773x; 1.0069x over previous
//
#include <hip/hip_runtime.h>

// SizeInvariantTimeSformer forward on MI355X (gfx950).
// fp32 residual stream. GEMM routing by measurement:
//   - gemm_bt (QKV/out-proj/FFN2/patch): 128x256 tile, 4 waves, BK=32, 3-buf ring, vmcnt(6).
//   - gemm_w1_fused: 128x128 tile, BK=32, 3-buf ring, vmcnt(4), 48KB LDS (3 blocks/CU).
// Both rings: issue-before-compute (T3 template) + m204 bijective XCD block swizzle.
// attn_space MFMA; attn_cls split-K flash.

typedef unsigned short u16;
typedef __bf16 bf16x8 __attribute__((ext_vector_type(8)));
typedef float f32x4 __attribute__((ext_vector_type(4)));
typedef u16 u16x8 __attribute__((ext_vector_type(8)));

#define SEQ   3137
#define ROWS  12548   // B * SEQ
#define MPAD  12672   // 99 * 128
#define MPADA 12800   // XNA row allocation (superset)
#define NTOK  12544   // B * F * 196
#define NCC   16      // cls split-K chunks
#define CHK   197     // ceil(SEQ/NCC)

__device__ __forceinline__ u16 f2b(float f) {
  union { float f; unsigned u; } v; v.f = f;
  unsigned r = v.u + 0x7FFFu + ((v.u >> 16) & 1u);   // RNE
  return (u16)(r >> 16);
}
__device__ __forceinline__ float b2f(u16 u) {
  union { unsigned u; float f; } v; v.u = ((unsigned)u) << 16;
  return v.f;
}
__device__ __forceinline__ float gelu_f(float g) {
  return 0.5f * g * (1.0f + erff(g * 0.70710678118654752f));
}
// bool inputs may arrive as uint8 bytes, int32 words, or float32 words.
__device__ __forceinline__ bool read_bool(const void* p, int idx) {
  const unsigned* w = (const unsigned*)p;
  unsigned w0 = w[0];
  if (w0 == 1u || w0 == 0u) return ((const int*)p)[idx] != 0;   // int32-encoded
  if (w0 == 0x3F800000u) return w[idx] != 0;                    // float32-encoded
  return ((const unsigned char*)p)[idx] != 0;                   // uint8-encoded
}

typedef const __attribute__((address_space(1))) void GVOID;
typedef __attribute__((address_space(3))) void LVOID;
__device__ __forceinline__ void gload_lds16(const void* g, void* l) {
  __builtin_amdgcn_global_load_lds((GVOID*)g, (LVOID*)l, 16, 0, 0);
}

// m204 bijective XCD swizzle: physical linear id -> logical tile id such that each
// XCD (p&7) owns a contiguous logical chunk (A-panel locality in its L2).
__device__ __forceinline__ void xcd_swz(int gx, int gy, int& bx, int& by) {
  const int nwg = gx * gy;
  const int p = (int)(blockIdx.y * gx + blockIdx.x);
  const int q = nwg >> 3, r = nwg & 7;
  const int xcd = p & 7, loc = p >> 3;
  const int logical = (xcd < r ? xcd * (q + 1) : r * (q + 1) + (xcd - r) * q) + loc;
  bx = logical % gx; by = logical / gx;
}

// ---- WIDE: 3-buffer BK=32 loop, 128(M)x256(N) tile, 4 waves, issue-early ----
#define GLOOP_WIDE(KVAL)                                                                 \
  const int K = (KVAL);                                                                  \
  const int NT = K >> 5;                                                                 \
  const int tid  = threadIdx.x;                                                          \
  const int lane = tid & 63, wid = tid >> 6;       /* wid = n-stripe 0..3 */             \
  int bx_, by_; xcd_swz(gridDim.x, gridDim.y, bx_, by_);                                 \
  const long arow0 = (long)by_ * 128;                                                    \
  const long brow0 = (long)bx_ * 256;                                                    \
  const int  s_row = tid >> 2;                     /* 0..63 */                           \
  const int  s_swz = (((tid & 3) ^ ((tid >> 3) & 3)) << 4);                              \
  const char* Ag = (const char*)A + (arow0 + s_row) * (long)K * 2 + s_swz;               \
  const char* Bg = (const char*)Bt + (brow0 + s_row) * (long)K * 2 + s_swz;              \
  auto issue = [&](int t) {                                                              \
    char* d = smem + (t % 3) * 24576 + tid * 16;                                         \
    const long kb = (long)t * 64;                                                        \
    gload_lds16(Ag + kb,                     d);                                         \
    gload_lds16(Ag + kb + (long)64  * K * 2, d + 4096);                                  \
    gload_lds16(Bg + kb,                     d + 8192);                                  \
    gload_lds16(Bg + kb + (long)64  * K * 2, d + 12288);                                 \
    gload_lds16(Bg + kb + (long)128 * K * 2, d + 16384);                                 \
    gload_lds16(Bg + kb + (long)192 * K * 2, d + 20480);                                 \
  };                                                                                     \
  f32x4 acc[8][4] = {};                                                                  \
  const int frow  = lane & 15;                                                           \
  const int rd_kb = (lane >> 4) << 4;                                                    \
  const int rxor  = ((lane >> 1) & 3) << 4;                                              \
  issue(0); issue(1);                                                                    \
  for (int t = 0; t < NT; ++t) {                                                         \
    if (t + 1 < NT) asm volatile("s_waitcnt vmcnt(6)" ::: "memory");                     \
    else            asm volatile("s_waitcnt vmcnt(0)" ::: "memory");                     \
    __builtin_amdgcn_sched_barrier(0);                                                   \
    __builtin_amdgcn_s_barrier();                                                        \
    __builtin_amdgcn_sched_barrier(0);                                                   \
    if (t + 2 < NT) issue(t + 2);                  /* issue BEFORE compute (T3) */       \
    const char* Ab = smem + (t % 3) * 24576;                                             \
    const char* Bb = Ab + 8192;                                                          \
    bf16x8 af[8], bfr[4];                                                                \
    _Pragma("unroll")                                                                    \
    for (int mi = 0; mi < 8; ++mi)                                                       \
      af[mi] = *(const bf16x8*)(Ab + (mi * 16 + frow) * 64 + (rd_kb ^ rxor));            \
    _Pragma("unroll")                                                                    \
    for (int ni = 0; ni < 4; ++ni)                                                       \
      bfr[ni] = *(const bf16x8*)(Bb + (wid * 64 + ni * 16 + frow) * 64 + (rd_kb ^ rxor));\
    __builtin_amdgcn_s_setprio(1);                                                       \
    _Pragma("unroll")                                                                    \
    for (int mi = 0; mi < 8; ++mi)                                                       \
      _Pragma("unroll")                                                                  \
      for (int ni = 0; ni < 4; ++ni)                                                     \
        acc[mi][ni] = __builtin_amdgcn_mfma_f32_16x16x32_bf16(af[mi], bfr[ni],           \
                                                              acc[mi][ni], 0, 0, 0);     \
    __builtin_amdgcn_s_setprio(0);                                                       \
  }

// ---- SQ: 3-buffer BK=32 loop, 128x128 tile, 4 waves 2x2, issue-early ----
#define GLOOP_SQ(KVAL)                                                                   \
  const int K = (KVAL);                                                                  \
  const int NT = K >> 5;                                                                 \
  const int tid  = threadIdx.x;                                                          \
  const int lane = tid & 63, wid = tid >> 6;                                             \
  const int wm = wid >> 1, wn = wid & 1;                                                 \
  int bx_, by_; xcd_swz(gridDim.x, gridDim.y, bx_, by_);                                 \
  const long arow0 = (long)by_ * 128;                                                    \
  const long brow0 = (long)bx_ * 128;                                                    \
  const int  s_row = tid >> 2;                                                           \
  const int  s_swz = (((tid & 3) ^ ((tid >> 3) & 3)) << 4);                              \
  const char* Ag = (const char*)A + (arow0 + s_row) * (long)K * 2 + s_swz;               \
  const char* Bg = (const char*)Bt + (brow0 + s_row) * (long)K * 2 + s_swz;              \
  auto issue = [&](int t) {                                                              \
    char* d = smem + (t % 3) * 16384 + tid * 16;                                         \
    const long kb = (long)t * 64;                                                        \
    gload_lds16(Ag + kb,                    d);                                          \
    gload_lds16(Ag + kb + (long)64 * K * 2, d + 4096);                                   \
    gload_lds16(Bg + kb,                    d + 8192);                                   \
    gload_lds16(Bg + kb + (long)64 * K * 2, d + 12288);                                  \
  };                                                                                     \
  f32x4 acc[4][4] = {};                                                                  \
  const int rd_row_a = wm * 64 + (lane & 15);                                            \
  const int rd_row_b = wn * 64 + (lane & 15);                                            \
  const int rd_kb    = (lane >> 4) << 4;                                                 \
  const int rxor     = ((lane >> 1) & 3) << 4;                                           \
  issue(0); issue(1);                                                                    \
  for (int t = 0; t < NT; ++t) {                                                         \
    if (t + 1 < NT) asm volatile("s_waitcnt vmcnt(4)" ::: "memory");                     \
    else            asm volatile("s_waitcnt vmcnt(0)" ::: "memory");                     \
    __builtin_amdgcn_sched_barrier(0);                                                   \
    __builtin_amdgcn_s_barrier();                                                        \
    __builtin_amdgcn_sched_barrier(0);                                                   \
    if (t + 2 < NT) issue(t + 2);                  /* issue BEFORE compute (T3) */       \
    const char* Ab = smem + (t % 3) * 16384;                                             \
    const char* Bb = Ab + 8192;                                                          \
    bf16x8 af[4], bfr[4];                                                                \
    _Pragma("unroll")                                                                    \
    for (int mi = 0; mi < 4; ++mi)                                                       \
      af[mi] = *(const bf16x8*)(Ab + (rd_row_a + mi * 16) * 64 + (rd_kb ^ rxor));        \
    _Pragma("unroll")                                                                    \
    for (int ni = 0; ni < 4; ++ni)                                                       \
      bfr[ni] = *(const bf16x8*)(Bb + (rd_row_b + ni * 16) * 64 + (rd_kb ^ rxor));       \
    __builtin_amdgcn_s_setprio(1);                                                       \
    _Pragma("unroll")                                                                    \
    for (int mi = 0; mi < 4; ++mi)                                                       \
      _Pragma("unroll")                                                                  \
      for (int ni = 0; ni < 4; ++ni)                                                     \
        acc[mi][ni] = __builtin_amdgcn_mfma_f32_16x16x32_bf16(af[mi], bfr[ni],           \
                                                              acc[mi][ni], 0, 0, 0);     \
    __builtin_amdgcn_s_setprio(0);                                                       \
  }

// ---------------- GEMM (wide): C[M,N] = A * Bt^T (+bias), N % 256 == 0 ----------------
// MODE 0: Cf = acc+bias   1: Cf += acc+bias   2: Cb = bf16(acc+bias)
template<int MODE>
__global__ __launch_bounds__(256, 2) void gemm_bt(
    const u16* __restrict__ A, const u16* __restrict__ Bt,
    const float* __restrict__ bias,
    float* __restrict__ Cf, u16* __restrict__ Cb,
    int Mact, int N, int Kin)
{
  __shared__ char smem[73728];
  GLOOP_WIDE(Kin)

  const int ccol0 = (int)brow0 + wid * 64 + frow;
  const int rsub  = (lane >> 4) * 4;
  float bv[4];
#pragma unroll
  for (int ni = 0; ni < 4; ++ni) bv[ni] = bias ? bias[ccol0 + ni * 16] : 0.0f;
#pragma unroll
  for (int mi = 0; mi < 8; ++mi) {
#pragma unroll
    for (int r = 0; r < 4; ++r) {
      long row = arow0 + mi * 16 + rsub + r;
      if (row < Mact) {
#pragma unroll
        for (int ni = 0; ni < 4; ++ni) {
          float v = acc[mi][ni][r] + bv[ni];
          long idx = row * (long)N + ccol0 + ni * 16;
          if (MODE == 0)      Cf[idx] = v;
          else if (MODE == 1) Cf[idx] += v;
          else                Cb[idx] = f2b(v);
        }
      }
    }
  }
}

// ---------------- FFN1 fused (sq): H = XN @ PW1^T + b1, HACT = a * gelu(g) --------
// PW1 rows: block c (128 rows) = [a-cols c*64..+63 | g-cols 4096+c*64..+63].
// Waves wn=0 hold a, wn=1 hold g; g exchanged via LDS reuse (gx stride 68).
__global__ __launch_bounds__(256) void gemm_w1_fused(
    const u16* __restrict__ A, const u16* __restrict__ Bt,
    const float* __restrict__ bias, u16* __restrict__ HACT, int Mact)
{
  __shared__ char smem[49152];
  GLOOP_SQ(1024)

  float* gx = (float*)smem;          // reuse: 2*64*68*4 = 34.8KB <= 48KB
  const int colb  = lane & 15;
  const int rsub  = (lane >> 4) * 4;
  const int cbase = bx_ * 64;
  float bv[4];
#pragma unroll
  for (int ni = 0; ni < 4; ++ni)
    bv[ni] = bias[(wn ? 4096 : 0) + cbase + ni * 16 + colb];

  __syncthreads();                   // staging LDS dead (vmcnt(0) at last tile)
  if (wn == 1) {
#pragma unroll
    for (int mi = 0; mi < 4; ++mi)
#pragma unroll
      for (int r = 0; r < 4; ++r) {
        int rl = mi * 16 + rsub + r;
#pragma unroll
        for (int ni = 0; ni < 4; ++ni)
          gx[(wm * 64 + rl) * 68 + ni * 16 + colb] = acc[mi][ni][r] + bv[ni];
      }
  }
  __syncthreads();
  if (wn == 0) {
#pragma unroll
    for (int mi = 0; mi < 4; ++mi)
#pragma unroll
      for (int r = 0; r < 4; ++r) {
        int rl = mi * 16 + rsub + r;
        long row = arow0 + wm * 64 + rl;
        if (row < Mact) {
#pragma unroll
          for (int ni = 0; ni < 4; ++ni) {
            float a = acc[mi][ni][r] + bv[ni];
            float g = gx[(wm * 64 + rl) * 68 + ni * 16 + colb];
            HACT[row * 4096L + cbase + ni * 16 + colb] = f2b(a * gelu_f(g));
          }
        }
      }
  }
}

// ---------------- transpose + f32->bf16 convert ----------------
__global__ __launch_bounds__(256) void transpose_cvt(
    const float* __restrict__ src, u16* __restrict__ dst,
    int R, int C, long sstride, long dstride)
{
  src += (long)blockIdx.z * sstride;
  dst += (long)blockIdx.z * dstride;
  __shared__ float tile[32][33];
  const int r0 = blockIdx.y * 32, c0 = blockIdx.x * 32;
  const int tx = threadIdx.x & 31, ty = threadIdx.x >> 5;
#pragma unroll
  for (int i = 0; i < 32; i += 8) {
    int r = r0 + ty + i, c = c0 + tx;
    if (r < R && c < C) tile[ty + i][tx] = src[(long)r * C + c];
  }
  __syncthreads();
#pragma unroll
  for (int i = 0; i < 32; i += 8) {
    int c = c0 + ty + i, r = r0 + tx;
    if (c < C && r < R) dst[(long)c * R + r] = f2b(tile[tx][ty + i]);
  }
}

// ---------------- w1 permuted transpose ----------------
__global__ __launch_bounds__(256) void transpose_w1(
    const float* __restrict__ src, u16* __restrict__ dst)
{
  __shared__ float tile[32][33];
  const int r0 = blockIdx.y * 32, c0 = blockIdx.x * 32;
  const int tx = threadIdx.x & 31, ty = threadIdx.x >> 5;
#pragma unroll
  for (int i = 0; i < 32; i += 8)
    tile[ty + i][tx] = src[(long)(r0 + ty + i) * 8192 + c0 + tx];
  __syncthreads();
#pragma unroll
  for (int i = 0; i < 32; i += 8) {
    int n = c0 + ty + i;
    int np = (n < 4096) ? ((n >> 6) * 128 + (n & 63))
                        : (((n - 4096) >> 6) * 128 + 64 + ((n - 4096) & 63));
    dst[(long)np * 1024 + r0 + tx] = f2b(tile[tx][ty + i]);
  }
}

// ---------------- build XT = concat(cls, tokens) + pos ----------------
__global__ __launch_bounds__(256) void build_xt(
    const float* __restrict__ TOK, const float* __restrict__ cls,
    const float* __restrict__ pos, float* __restrict__ XT)
{
  const int row = blockIdx.x, tid = threadIdx.x;
  const int b = row / SEQ, s = row % SEQ;
  float4 p = ((const float4*)(pos + (long)s * 1024))[tid];
  float4 t;
  if (s == 0) t = ((const float4*)cls)[tid];
  else        t = ((const float4*)(TOK + ((long)b * 3136 + (s - 1)) * 1024))[tid];
  float4 r; r.x = t.x + p.x; r.y = t.y + p.y; r.z = t.z + p.z; r.w = t.w + p.w;
  ((float4*)(XT + (long)row * 1024))[tid] = r;
}

// ---------------- LayerNorm (f32 in) -> bf16 out ----------------
__global__ __launch_bounds__(256) void ln_rows(
    const float* __restrict__ X, const float* __restrict__ g,
    const float* __restrict__ b, u16* __restrict__ Y)
{
  const int row = blockIdx.x, tid = threadIdx.x;
  const int lane = tid & 63, wid = tid >> 6;
  float4 x = ((const float4*)(X + (long)row * 1024))[tid];
  float s = x.x + x.y + x.z + x.w;
  float q = x.x * x.x + x.y * x.y + x.z * x.z + x.w * x.w;
#pragma unroll
  for (int o = 32; o; o >>= 1) { s += __shfl_xor(s, o); q += __shfl_xor(q, o); }
  __shared__ float ls[4], lq[4];
  if (lane == 0) { ls[wid] = s; lq[wid] = q; }
  __syncthreads();
  s = ls[0] + ls[1] + ls[2] + ls[3];
  q = lq[0] + lq[1] + lq[2] + lq[3];
  const float mean = s * (1.0f / 1024.0f);
  const float rstd = rsqrtf(q * (1.0f / 1024.0f) - mean * mean + 1e-5f);
  float4 gg = ((const float4*)g)[tid];
  float4 bb = ((const float4*)b)[tid];
  ushort4 o4;
  o4.x = f2b((x.x - mean) * rstd * gg.x + bb.x);
  o4.y = f2b((x.y - mean) * rstd * gg.y + bb.y);
  o4.z = f2b((x.z - mean) * rstd * gg.z + bb.z);
  o4.w = f2b((x.w - mean) * rstd * gg.w + bb.w);
  ((ushort4*)(Y + (long)row * 1024))[tid] = o4;
}

// ---------------- cls attention, split-K partial ----------------
__global__ __launch_bounds__(256) void attn_cls_part(
    const u16* __restrict__ QKV, float* __restrict__ PART, const void* __restrict__ maskp)
{
  const int c = blockIdx.x, bh = blockIdx.y;
  const int b = bh >> 4, h = bh & 15;
  const long rowbase = (long)b * SEQ;
  const int tid = threadIdx.x, lane = tid & 63, w = tid >> 6;
  const int rs = lane >> 3, c8 = lane & 7;
  const int start = c * CHK;
  const int end = (start + CHK < SEQ) ? start + CHK : SEQ;

  float qf[8];
  {
    u16x8 qv = *(const u16x8*)(QKV + rowbase * 3072 + h * 64 + c8 * 8);
#pragma unroll
    for (int i = 0; i < 8; ++i) qf[i] = b2f(qv[i]) * 0.125f;
  }

  float m_run = -3.4e38f, s_run = 0.f;
  float acc[8] = {};

  for (int j8 = start + w * 8; j8 < end; j8 += 32) {
    int j = j8 + rs;
    bool valid = (j < end);
    int jc = valid ? j : (end - 1);
    const u16* kp = QKV + (rowbase + jc) * 3072 + 1024 + h * 64 + c8 * 8;
    u16x8 kv = *(const u16x8*)kp;
    u16x8 vv = *(const u16x8*)(kp + 1024);
    float sim = 0.f;
#pragma unroll
    for (int i = 0; i < 8; ++i) sim += b2f(kv[i]) * qf[i];
    sim += __shfl_xor(sim, 1); sim += __shfl_xor(sim, 2); sim += __shfl_xor(sim, 4);
    bool ok = valid && ((jc == 0) || read_bool(maskp, b * 16 + (jc - 1) / 196));
    float simv = ok ? sim : -3.4e38f;
    float mx = simv;
    mx = fmaxf(mx, __shfl_xor(mx, 8));
    mx = fmaxf(mx, __shfl_xor(mx, 16));
    mx = fmaxf(mx, __shfl_xor(mx, 32));
    float new_m = fmaxf(m_run, mx);
    float scale = __expf(m_run - new_m);
    float p = ok ? __expf(simv - new_m) : 0.f;
    m_run = new_m;
    s_run = s_run * scale + p;
#pragma unroll
    for (int i = 0; i < 8; ++i) acc[i] = acc[i] * scale + p * b2f(vv[i]);
  }
#pragma unroll
  for (int o = 8; o <= 32; o <<= 1) {
    s_run += __shfl_xor(s_run, o);
#pragma unroll
    for (int i = 0; i < 8; ++i) acc[i] += __shfl_xor(acc[i], o);
  }

  __shared__ float sm_m[4], sm_s[4], sm_a[4][64];
  if (lane == 0) { sm_m[w] = m_run; sm_s[w] = s_run; }
  if (rs == 0) {
#pragma unroll
    for (int i = 0; i < 8; ++i) sm_a[w][c8 * 8 + i] = acc[i];
  }
  __syncthreads();
  if (tid < 64) {
    float M = fmaxf(fmaxf(sm_m[0], sm_m[1]), fmaxf(sm_m[2], sm_m[3]));
    float S = 0.f, A = 0.f;
#pragma unroll
    for (int ww = 0; ww < 4; ++ww) {
      float e = __expf(sm_m[ww] - M);
      S += sm_s[ww] * e;
      A += sm_a[ww][tid] * e;
    }
    float* outp = PART + ((long)bh * NCC + c) * 72;
    outp[tid] = A;
    if (tid == 0) { outp[64] = M; outp[65] = S; }
  }
}

// ---------------- cls attention combine ----------------
__global__ __launch_bounds__(64) void attn_cls_comb(
    const float* __restrict__ PART, u16* __restrict__ ATT)
{
  const int bh = blockIdx.x, b = bh >> 4, h = bh & 15;
  const int d = threadIdx.x;
  float M = -3.4e38f;
#pragma unroll
  for (int c = 0; c < NCC; ++c) M = fmaxf(M, PART[((long)bh * NCC + c) * 72 + 64]);
  float S = 0.f, A = 0.f;
#pragma unroll
  for (int c = 0; c < NCC; ++c) {
    const float* p = PART + ((long)bh * NCC + c) * 72;
    float e = __expf(p[64] - M);
    S += p[65] * e;
    A += p[d] * e;
  }
  ATT[((long)b * SEQ) * 1024 + h * 64 + d] = f2b(A / S);
}

// ---------------- time attention: groups (b,h,n), 16 queries x 17 keys ----------------
__global__ __launch_bounds__(256) void attn_time(
    const u16* __restrict__ QKV, u16* __restrict__ ATT,
    const void* __restrict__ maskp, const void* __restrict__ idmp)
{
  const int g = blockIdx.x;
  const int n = g % 196;
  const int bh = g / 196;
  const int h = bh & 15, b = bh >> 4;
  const long rowbase = (long)b * SEQ;
  const int tid = threadIdx.x;
  __shared__ float q_s[16][65], k_s[17][65], v_s[17][65], p_s[16][18];
  for (int idx = tid; idx < 16 * 64; idx += 256) {
    int i = idx >> 6, d = idx & 63;
    q_s[i][d] = b2f(QKV[(rowbase + 1 + i * 196 + n) * 3072 + h * 64 + d]) * 0.125f;
  }
  for (int idx = tid; idx < 17 * 64; idx += 256) {
    int j = idx >> 6, d = idx & 63;
    long kr = (j == 0) ? rowbase : (rowbase + 1 + (long)(j - 1) * 196 + n);
    k_s[j][d] = b2f(QKV[kr * 3072 + 1024 + h * 64 + d]);
    v_s[j][d] = b2f(QKV[kr * 3072 + 2048 + h * 64 + d]);
  }
  __syncthreads();
#pragma unroll
  for (int pp = 0; pp < 2; ++pp) {
    int idx = tid + pp * 256;
    if (idx < 272) {
      int i = idx / 17, j = idx % 17;
      float s = 0.f;
      for (int d = 0; d < 64; ++d) s += q_s[i][d] * k_s[j][d];
      bool ok = (j == 0) ||
                (read_bool(maskp, b * 16 + (j - 1)) && read_bool(idmp, (b * 16 + i) * 16 + (j - 1)));
      p_s[i][j] = ok ? s : -3.4e38f;
    }
  }
  __syncthreads();
  if (tid < 16) {
    float m = -3.4e38f;
    for (int j = 0; j < 17; ++j) m = fmaxf(m, p_s[tid][j]);
    float su = 0.f;
    for (int j = 0; j < 17; ++j) { float e = __expf(p_s[tid][j] - m); p_s[tid][j] = e; su += e; }
    float inv = 1.0f / su;
    for (int j = 0; j < 17; ++j) p_s[tid][j] *= inv;
  }
  __syncthreads();
  for (int idx = tid; idx < 1024; idx += 256) {
    int i = idx >> 6, d = idx & 63;
    float o = 0.f;
#pragma unroll
    for (int j = 0; j < 17; ++j) o += p_s[i][j] * v_s[j][d];
    ATT[(rowbase + 1 + i * 196 + n) * 1024 + h * 64 + d] = f2b(o);
  }
}

// ---------------- space attention (MFMA): one block per (b,h,f) ----------------
__global__ __launch_bounds__(256) void attn_space(
    const u16* __restrict__ QKV, u16* __restrict__ ATT)
{
  const int g = blockIdx.x;             // bh*16 + f
  const int fr = g & 15, bh = g >> 4;
  const int h = bh & 15, b = bh >> 4;
  const long rowbase = (long)b * SEQ;
  const long qbase = rowbase + 1 + (long)fr * 196;
  const int tid = threadIdx.x, lane = tid & 63, wid = tid >> 6;

  __shared__ u16 Ks[208][72];
  __shared__ u16 Vt[64][232];
  __shared__ u16 Ps[4][16][232];

  for (int c = tid; c < 197 * 8; c += 256) {
    int row = c >> 3, k8 = c & 7;
    long kr = (row == 0) ? rowbase : (qbase + row - 1);
    *(u16x8*)&Ks[row][k8 * 8] = *(const u16x8*)(QKV + kr * 3072 + 1024 + h * 64 + k8 * 8);
  }
  for (int c = tid; c < 64 * 35; c += 256) {
    int d = c / 35, k = 197 + c % 35;
    Vt[d][k] = 0;
  }
  for (int c = tid; c < 4 * 16 * 24; c += 256) {
    int w = c / (16 * 24), rem = c % (16 * 24);
    Ps[w][rem / 24][208 + rem % 24] = 0;
  }
  for (int c = tid; c < 197 * 64; c += 256) {
    int k = c >> 6, d = c & 63;
    long vr = (k == 0) ? rowbase : (qbase + k - 1);
    Vt[d][k] = QKV[vr * 3072 + 2048 + h * 64 + d];
  }
  __syncthreads();

  const int cl = lane & 15, hi = lane >> 4;
  for (int mt = wid; mt < 13; mt += 4) {
    int qi0 = mt * 16 + cl;
    long qrow = qbase + (qi0 < 196 ? qi0 : 0);
    const u16* qp = QKV + qrow * 3072 + h * 64 + hi * 8;
    bf16x8 af0 = *(const bf16x8*)qp;
    bf16x8 af1 = *(const bf16x8*)(qp + 32);

    f32x4 acc[13];
#pragma unroll
    for (int nt = 0; nt < 13; ++nt) {
      acc[nt] = (f32x4){0.f, 0.f, 0.f, 0.f};
      bf16x8 b0 = *(const bf16x8*)&Ks[nt * 16 + cl][hi * 8];
      acc[nt] = __builtin_amdgcn_mfma_f32_16x16x32_bf16(af0, b0, acc[nt], 0, 0, 0);
      bf16x8 b1 = *(const bf16x8*)&Ks[nt * 16 + cl][32 + hi * 8];
      acc[nt] = __builtin_amdgcn_mfma_f32_16x16x32_bf16(af1, b1, acc[nt], 0, 0, 0);
    }
    float mx[4] = {-3.4e38f, -3.4e38f, -3.4e38f, -3.4e38f};
#pragma unroll
    for (int nt = 0; nt < 13; ++nt) {
      int col = nt * 16 + cl;
#pragma unroll
      for (int r = 0; r < 4; ++r) {
        float s = acc[nt][r] * 0.125f;
        if (col >= 197) s = -3.4e38f;
        acc[nt][r] = s;
        mx[r] = fmaxf(mx[r], s);
      }
    }
#pragma unroll
    for (int r = 0; r < 4; ++r) {
#pragma unroll
      for (int o = 8; o; o >>= 1) mx[r] = fmaxf(mx[r], __shfl_xor(mx[r], o));
    }
    float sum[4] = {0.f, 0.f, 0.f, 0.f};
#pragma unroll
    for (int nt = 0; nt < 13; ++nt) {
      int col = nt * 16 + cl;
#pragma unroll
      for (int r = 0; r < 4; ++r) {
        float p = __expf(acc[nt][r] - mx[r]);
        sum[r] += p;
        Ps[wid][hi * 4 + r][col] = f2b(p);
      }
    }
    float inv[4];
#pragma unroll
    for (int r = 0; r < 4; ++r) {
#pragma unroll
      for (int o = 8; o; o >>= 1) sum[r] += __shfl_xor(sum[r], o);
      inv[r] = 1.0f / sum[r];
    }
    f32x4 ov[4];
#pragma unroll
    for (int dt = 0; dt < 4; ++dt) ov[dt] = (f32x4){0.f, 0.f, 0.f, 0.f};
#pragma unroll
    for (int ks = 0; ks < 7; ++ks) {
      bf16x8 pa = *(const bf16x8*)&Ps[wid][cl][ks * 32 + hi * 8];
#pragma unroll
      for (int dt = 0; dt < 4; ++dt) {
        bf16x8 vb = *(const bf16x8*)&Vt[dt * 16 + cl][ks * 32 + hi * 8];
        ov[dt] = __builtin_amdgcn_mfma_f32_16x16x32_bf16(pa, vb, ov[dt], 0, 0, 0);
      }
    }
#pragma unroll
    for (int r = 0; r < 4; ++r) {
      int qi = mt * 16 + hi * 4 + r;
      if (qi < 196) {
        long orow = (qbase + qi) * 1024 + h * 64;
#pragma unroll
        for (int dt = 0; dt < 4; ++dt)
          ATT[orow + dt * 16 + cl] = f2b(ov[dt][r] * inv[r]);
      }
    }
  }
}

// ---------------- final head: LN(cls) @ o_w + o_b ----------------
__global__ __launch_bounds__(256) void final_head(
    const float* __restrict__ XT, const float* __restrict__ g,
    const float* __restrict__ b, const float* __restrict__ ow,
    const float* __restrict__ ob, float* __restrict__ out)
{
  const int bb = blockIdx.x, tid = threadIdx.x;
  const int lane = tid & 63, wid = tid >> 6;
  float4 x = ((const float4*)(XT + (long)bb * SEQ * 1024))[tid];
  float s = x.x + x.y + x.z + x.w;
  float q = x.x * x.x + x.y * x.y + x.z * x.z + x.w * x.w;
#pragma unroll
  for (int o = 32; o; o >>= 1) { s += __shfl_xor(s, o); q += __shfl_xor(q, o); }
  __shared__ float ls[4], lq[4], lt[4];
  if (lane == 0) { ls[wid] = s; lq[wid] = q; }
  __syncthreads();
  s = ls[0] + ls[1] + ls[2] + ls[3];
  q = lq[0] + lq[1] + lq[2] + lq[3];
  const float mean = s * (1.0f / 1024.0f);
  const float rstd = rsqrtf(q * (1.0f / 1024.0f) - mean * mean + 1e-5f);
  float4 gg = ((const float4*)g)[tid];
  float4 bv = ((const float4*)b)[tid];
  float4 wv = ((const float4*)ow)[tid];
  float t = ((x.x - mean) * rstd * gg.x + bv.x) * wv.x
          + ((x.y - mean) * rstd * gg.y + bv.y) * wv.y
          + ((x.z - mean) * rstd * gg.z + bv.z) * wv.z
          + ((x.w - mean) * rstd * gg.w + bv.w) * wv.w;
#pragma unroll
  for (int o = 32; o; o >>= 1) t += __shfl_xor(t, o);
  if (lane == 0) lt[wid] = t;
  __syncthreads();
  if (tid == 0) out[bb] = lt[0] + lt[1] + lt[2] + lt[3] + ob[0];
}

// ==========================================================================
extern "C" void kernel_launch(void* const* d_in, const int* in_sizes, int n_in,
                              void* d_out, int out_size, void* d_ws, size_t ws_size,
                              hipStream_t stream) {
  const float* x       = (const float*)d_in[0];
  const void*  maskp   = d_in[1];
  const void*  idmp    = d_in[2];
  const float* patch_w = (const float*)d_in[3];
  const float* patch_b = (const float*)d_in[4];
  const float* cls_tok = (const float*)d_in[5];
  const float* pos_emb = (const float*)d_in[6];
  const float* t_ng = (const float*)d_in[7];
  const float* t_nb = (const float*)d_in[8];
  const float* t_qkv = (const float*)d_in[9];
  const float* t_ow = (const float*)d_in[10];
  const float* t_ob = (const float*)d_in[11];
  const float* s_ng = (const float*)d_in[12];
  const float* s_nb = (const float*)d_in[13];
  const float* s_qkv = (const float*)d_in[14];
  const float* s_ow = (const float*)d_in[15];
  const float* s_ob = (const float*)d_in[16];
  const float* f_ng = (const float*)d_in[17];
  const float* f_nb = (const float*)d_in[18];
  const float* f_w1 = (const float*)d_in[19];
  const float* f_b1 = (const float*)d_in[20];
  const float* f_w2 = (const float*)d_in[21];
  const float* f_b2 = (const float*)d_in[22];
  const float* o_ng = (const float*)d_in[23];
  const float* o_nb = (const float*)d_in[24];
  const float* o_w  = (const float*)d_in[25];
  const float* o_b  = (const float*)d_in[26];
  float* out = (float*)d_out;

  // ---- workspace layout (~199 MB) ----
  const size_t szXT   = (size_t)ROWS * 1024 * 4;
  const size_t szXNA  = (size_t)MPADA * 1024 * 2;
  const size_t szBIG  = (size_t)MPAD * 4096 * 2;
  const size_t szWBUF = (size_t)8192 * 1024 * 2;
  size_t off = 0;
  auto take = [&](size_t b) { size_t o = off; off += (b + 255) & ~(size_t)255; return o; };
  char* base = (char*)d_ws;
  float* XT  = (float*)(base + take(szXT));
  u16*  XNA  = (u16*)(base + take(szXNA));
  char* BIG  = base + take(szBIG);
  u16*  WBUF = (u16*)(base + take(szWBUF));
  if (off > ws_size) return;                              // ws too small: fail clean

  u16*   QKV  = (u16*)BIG;
  u16*   HACT = (u16*)BIG;
  u16*   Xtr  = (u16*)BIG;
  float* TOK  = (float*)(BIG + (size_t)40 * 1024 * 1024);
  float* PART = (float*)(BIG + (size_t)MPAD * 3072 * 2);  // after QKV extent

  auto tr = [&](const float* s, u16* d, int R, int C) {
    dim3 gr((C + 31) / 32, (R + 31) / 32, 1);
    transpose_cvt<<<gr, 256, 0, stream>>>(s, d, R, C, 0, 0);
  };

  // ---- patch embedding ----
  {
    dim3 gr((196 + 31) / 32, (1280 + 31) / 32, 64);
    transpose_cvt<<<gr, 256, 0, stream>>>(x, Xtr, 1280, 196, 1280L * 196, 196L * 1280);
  }
  tr(patch_w, WBUF, 1280, 1024);
  gemm_bt<0><<<dim3(4, 98), 256, 0, stream>>>(Xtr, WBUF, patch_b, TOK, nullptr, NTOK, 1024, 1280);
  build_xt<<<ROWS, 256, 0, stream>>>(TOK, cls_tok, pos_emb, XT);

  for (int L = 0; L < 2; ++L) {
    // ---- time attention block ----
    tr(t_qkv + (size_t)L * 1024 * 3072, WBUF, 1024, 3072);
    ln_rows<<<ROWS, 256, 0, stream>>>(XT, t_ng + L * 1024, t_nb + L * 1024, XNA);
    gemm_bt<2><<<dim3(12, 99), 256, 0, stream>>>(XNA, WBUF, nullptr, nullptr, QKV, MPAD, 3072, 1024);
    tr(t_ow + (size_t)L * 1024 * 1024, WBUF, 1024, 1024);
    attn_cls_part<<<dim3(NCC, 64), 256, 0, stream>>>(QKV, PART, maskp);
    attn_cls_comb<<<64, 64, 0, stream>>>(PART, XNA);
    attn_time<<<NTOK, 256, 0, stream>>>(QKV, XNA, maskp, idmp);
    gemm_bt<1><<<dim3(4, 99), 256, 0, stream>>>(XNA, WBUF, t_ob + L * 1024, XT, nullptr, ROWS, 1024, 1024);
    // ---- space attention block ----
    tr(s_qkv + (size_t)L * 1024 * 3072, WBUF, 1024, 3072);
    ln_rows<<<ROWS, 256, 0, stream>>>(XT, s_ng + L * 1024, s_nb + L * 1024, XNA);
    gemm_bt<2><<<dim3(12, 99), 256, 0, stream>>>(XNA, WBUF, nullptr, nullptr, QKV, MPAD, 3072, 1024);
    tr(s_ow + (size_t)L * 1024 * 1024, WBUF, 1024, 1024);
    attn_cls_part<<<dim3(NCC, 64), 256, 0, stream>>>(QKV, PART, maskp);
    attn_cls_comb<<<64, 64, 0, stream>>>(PART, XNA);
    attn_space<<<1024, 256, 0, stream>>>(QKV, XNA);
    gemm_bt<1><<<dim3(4, 99), 256, 0, stream>>>(XNA, WBUF, s_ob + L * 1024, XT, nullptr, ROWS, 1024, 1024);
    // ---- FFN (gate fused into GEMM1 epilogue; sq kernel) ----
    transpose_w1<<<dim3(256, 32), 256, 0, stream>>>(f_w1 + (size_t)L * 1024 * 8192, WBUF);
    ln_rows<<<ROWS, 256, 0, stream>>>(XT, f_ng + L * 1024, f_nb + L * 1024, XNA);
    gemm_w1_fused<<<dim3(64, 99), 256, 0, stream>>>(XNA, WBUF, f_b1 + L * 8192, HACT, ROWS);
    tr(f_w2 + (size_t)L * 4096 * 1024, WBUF, 4096, 1024);
    gemm_bt<1><<<dim3(4, 99), 256, 0, stream>>>(HACT, WBUF, f_b2 + L * 1024, XT, nullptr, ROWS, 1024, 4096);
  }
  final_head<<<4, 256, 0, stream>>>(XT, o_ng, o_nb, o_w, o_b, out);
}